// Round 13
// baseline (5887.746 us; speedup 1.0000x reference)
//
#include <hip/hip_runtime.h>
#include <math.h>

// Problem constants
#define NPTS 8192
#define MNODE 2048

// ---------------- ws layout (float element offsets) ----------------
#define WS_XT1  0L          // xt1_ [4][128][8192] (x1 ch0-63, x2 ch64-127) — live whole pass
#define WS_A    4194304L    // x34 [4][512][2048] (x3 ch0-255, x4 ch256-511); sort scratch EARLY
#define WS_B    8388608L    // scores [4][8][8192] early; s8 [4][128][8192] later
#define WS_C    12582912L   // h [4][256][2048] early; s6/s7 [4][128][2048] later
#define WS_D    14680064L   // sup [4][128][8192]; s9 later
#define WS_TOPV 18874368L   // [4][2048]
#define WS_TOPI 18882560L   // int [4][2048]
#define WS_NODE 18890752L   // [4][3][2048]
#define WS_MAXP 18915328L   // [4][1024]
#define WS_VEC  18919424L   // [4][2048]
#define WS_C1   18927616L   // [4][512]
#define WS_C2   18929664L   // [4][256]
#define WS_B6   18930688L   // [4][128]
#define WS_K20  18931200L   // int [4][2048][20]; ALSO convmax partial-max scratch (disjoint lifetime)
#define WS_K3I  19095040L   // int [4][8192][3]
#define WS_K3W  19193344L   // [4][8192][3]
// end = 19291648 floats = 73.6 MB

// ---------------- conv1: x[4,3,8192] -> xt1_ ch0-63 ----------------
__global__ __launch_bounds__(256) void k_conv1(const float* __restrict__ x,
                                               const float* __restrict__ W,
                                               const float* __restrict__ sc,
                                               const float* __restrict__ bi,
                                               float* __restrict__ out) {
    int t = blockIdx.x * 256 + threadIdx.x;           // 4*64*8192
    int n = t & 8191, o = (t >> 13) & 63, b = t >> 19;
    const float* xb = x + (long)b * 3 * NPTS;
    float a = W[o * 3 + 0] * xb[n] + W[o * 3 + 1] * xb[NPTS + n] + W[o * 3 + 2] * xb[2 * NPTS + n];
    a = fmaxf(a * sc[o] + bi[o], 0.f);
    out[((long)b * 128 + o) * NPTS + n] = a;
}

// ---------------- conv2: xt1_ ch0-63 -> xt1_ ch64-127 ----------------
__global__ __launch_bounds__(256) void k_conv2(const float* __restrict__ in,
                                               const float* __restrict__ W,
                                               const float* __restrict__ sc,
                                               const float* __restrict__ bi,
                                               float* __restrict__ out) {
    int t = blockIdx.x * 256 + threadIdx.x;
    int n = t & 8191, o = (t >> 13) & 63, b = t >> 19;
    const float* ip = in + (long)b * 128 * NPTS + n;
    const float* wp = W + o * 64;
    float a = 0.f;
#pragma unroll 8
    for (int c = 0; c < 64; ++c) a = fmaf(wp[c], ip[(long)c * NPTS], a);
    out[((long)b * 128 + 64 + o) * NPTS + n] = fmaxf(a * sc[o] + bi[o], 0.f);
}

// 16-output-tile FMA block: reads 4x float4 broadcast from Wl at row c16, FMAs into acc[16]
#define CMAX_FMA16()                                                        \
    {                                                                       \
        const float4* wp4 = reinterpret_cast<const float4*>(Wl + c16);      \
        _Pragma("unroll")                                                   \
        for (int g = 0; g < 4; ++g) {                                       \
            float4 w = wp4[g];                                              \
            acc[4 * g + 0].x = fmaf(w.x, v.x, acc[4 * g + 0].x);            \
            acc[4 * g + 0].y = fmaf(w.x, v.y, acc[4 * g + 0].y);            \
            acc[4 * g + 0].z = fmaf(w.x, v.z, acc[4 * g + 0].z);            \
            acc[4 * g + 0].w = fmaf(w.x, v.w, acc[4 * g + 0].w);            \
            acc[4 * g + 1].x = fmaf(w.y, v.x, acc[4 * g + 1].x);            \
            acc[4 * g + 1].y = fmaf(w.y, v.y, acc[4 * g + 1].y);            \
            acc[4 * g + 1].z = fmaf(w.y, v.z, acc[4 * g + 1].z);            \
            acc[4 * g + 1].w = fmaf(w.y, v.w, acc[4 * g + 1].w);            \
            acc[4 * g + 2].x = fmaf(w.z, v.x, acc[4 * g + 2].x);            \
            acc[4 * g + 2].y = fmaf(w.z, v.y, acc[4 * g + 2].y);            \
            acc[4 * g + 2].z = fmaf(w.z, v.z, acc[4 * g + 2].z);            \
            acc[4 * g + 2].w = fmaf(w.z, v.w, acc[4 * g + 2].w);            \
            acc[4 * g + 3].x = fmaf(w.w, v.x, acc[4 * g + 3].x);            \
            acc[4 * g + 3].y = fmaf(w.w, v.y, acc[4 * g + 3].y);            \
            acc[4 * g + 3].z = fmaf(w.w, v.z, acc[4 * g + 3].z);            \
            acc[4 * g + 3].w = fmaf(w.w, v.w, acc[4 * g + 3].w);            \
        }                                                                   \
    }

// ---------------- fused conv(+cbias)(+bn)(+relu) + partial max, DUAL param set ----------------
// 16-wide O-tile, Wl transposed [C][16], 1-deep prefetch.
// LDS alias: red[16][257] reuses Wl (disjoint lifetime, barrier-guarded).
// __launch_bounds__(256, 8): request 8 blocks/CU (VGPR cap 64; currently 52 fits).
__global__ __launch_bounds__(256, 8) void k_convmax(
        const float* __restrict__ in, int C, long ibs,
        const float* __restrict__ W1, const float* __restrict__ cb1,
        const float* __restrict__ sc1, const float* __restrict__ bi1, int relu1,
        float* __restrict__ pmax1,
        const float* __restrict__ W2, const float* __restrict__ cb2,
        const float* __restrict__ sc2, const float* __restrict__ bi2, int relu2,
        float* __restrict__ pmax2,
        int wpitch, int O, int Nn) {
    extern __shared__ float sm_[];
    float* Wl = sm_;              // [C][16]
    float* red = sm_;             // [16][257] — ALIASES Wl (disjoint lifetime)
    int b = blockIdx.z;
    int ns = blockIdx.x;
    int oblocks = O >> 4;
    int setid = (int)blockIdx.y / oblocks;          // uniform per block
    int og0 = ((int)blockIdx.y - setid * oblocks) * 16;
    const float* W  = setid ? W2 : W1;
    const float* cb = setid ? cb2 : cb1;
    const float* sc = setid ? sc2 : sc1;
    const float* bi = setid ? bi2 : bi1;
    int do_relu     = setid ? relu2 : relu1;
    float* pmax     = setid ? pmax2 : pmax1;
    for (int t = threadIdx.x; t < 16 * C; t += 256) {
        int c = t >> 4, o = t & 15;
        Wl[t] = W[(long)(og0 + o) * wpitch + c];
    }
    __syncthreads();
    int n0 = ns * 1024 + threadIdx.x * 4;
    float4 acc[16];
#pragma unroll
    for (int o = 0; o < 16; ++o) acc[o] = make_float4(0.f, 0.f, 0.f, 0.f);
    const float* p = in + (long)b * ibs + n0;
    float4 v = *reinterpret_cast<const float4*>(p);
    for (int c = 0; c < C - 1; ++c) {
        float4 vn = *reinterpret_cast<const float4*>(p + (long)(c + 1) * Nn);  // prefetch
        int c16 = c * 16;
        CMAX_FMA16();
        v = vn;
    }
    {
        int c16 = (C - 1) * 16;
        CMAX_FMA16();
    }
    // bn/relu + horizontal max4 into registers, THEN barrier (Wl dead), stage, tree-reduce
    float h2[16];
#pragma unroll
    for (int o = 0; o < 16; ++o) {
        float cbv = cb ? cb[og0 + o] : 0.f;
        float scv = sc ? sc[og0 + o] : 1.f;
        float biv = bi ? bi[og0 + o] : 0.f;
        float4 a = acc[o];
        float vx = (a.x + cbv) * scv + biv;
        float vy = (a.y + cbv) * scv + biv;
        float vz = (a.z + cbv) * scv + biv;
        float vw = (a.w + cbv) * scv + biv;
        if (do_relu) {
            vx = fmaxf(vx, 0.f); vy = fmaxf(vy, 0.f);
            vz = fmaxf(vz, 0.f); vw = fmaxf(vw, 0.f);
        }
        h2[o] = fmaxf(fmaxf(vx, vy), fmaxf(vz, vw));
    }
    __syncthreads();   // all Wl reads complete before red overwrites it
#pragma unroll
    for (int o = 0; o < 16; ++o) red[o * 257 + threadIdx.x] = h2[o];
    __syncthreads();
    for (int ls = 7; ls >= 0; --ls) {
        int s = 1 << ls;
        for (int w = threadIdx.x; w < 16 * s; w += 256) {
            int o = w >> ls, i = w & (s - 1);
            float* r = red + o * 257;
            r[i] = fmaxf(r[i], r[i + s]);
        }
        __syncthreads();
    }
    if (threadIdx.x < 16)
        pmax[((long)ns * 4 + b) * O + og0 + threadIdx.x] = red[threadIdx.x * 257];
}

// finalize: out[b*obs + o] = max over nsplit partials. Dual-set variant (one launch).
__global__ __launch_bounds__(256) void k_maxred2(const float* __restrict__ pA, int nsA, int OA,
                                                 float* __restrict__ outA, long obsA,
                                                 const float* __restrict__ pB, int nsB, int OB,
                                                 float* __restrict__ outB, long obsB,
                                                 int blocksA) {
    const float* pm; int ns, O; float* out; long obs; int bid = blockIdx.x;
    if (bid < blocksA) { pm = pA; ns = nsA; O = OA; out = outA; obs = obsA; }
    else { pm = pB; ns = nsB; O = OB; out = outB; obs = obsB; bid -= blocksA; }
    int t = bid * 256 + threadIdx.x;
    if (t >= 4 * O) return;
    int o = t % O, b = t / O;
    float m = -3.0e38f;
    for (int s = 0; s < ns; ++s) m = fmaxf(m, pm[((long)s * 4 + b) * O + o]);
    out[(long)b * obs + o] = m;
}

__global__ __launch_bounds__(256) void k_maxred(const float* __restrict__ pmax, int nsplit,
                                                int O, float* __restrict__ out, long obs) {
    int t = blockIdx.x * 256 + threadIdx.x;
    if (t >= 4 * O) return;
    int o = t % O, b = t / O;
    float m = -3.0e38f;
    for (int s = 0; s < nsplit; ++s) m = fmaxf(m, pmax[((long)s * 4 + b) * O + o]);
    out[(long)b * obs + o] = m;
}

// ---------------- generic conv(+extra)(+bn)(+relu), up to 2 concat inputs ----------------
// block 256, grid (Nn/1024, ceil(O/8), B). 8-wide o-tile, Wl transposed [Ct][8]
// zero-padded, 2x float4 weight reads per c, 1-deep prefetch.
#define CONV_FMA8()                                                         \
    {                                                                       \
        const float4* wp4 = reinterpret_cast<const float4*>(Wl + c8);       \
        _Pragma("unroll")                                                   \
        for (int g = 0; g < 2; ++g) {                                       \
            float4 w = wp4[g];                                              \
            acc[4 * g + 0].x = fmaf(w.x, v.x, acc[4 * g + 0].x);            \
            acc[4 * g + 0].y = fmaf(w.x, v.y, acc[4 * g + 0].y);            \
            acc[4 * g + 0].z = fmaf(w.x, v.z, acc[4 * g + 0].z);            \
            acc[4 * g + 0].w = fmaf(w.x, v.w, acc[4 * g + 0].w);            \
            acc[4 * g + 1].x = fmaf(w.y, v.x, acc[4 * g + 1].x);            \
            acc[4 * g + 1].y = fmaf(w.y, v.y, acc[4 * g + 1].y);            \
            acc[4 * g + 1].z = fmaf(w.y, v.z, acc[4 * g + 1].z);            \
            acc[4 * g + 1].w = fmaf(w.y, v.w, acc[4 * g + 1].w);            \
            acc[4 * g + 2].x = fmaf(w.z, v.x, acc[4 * g + 2].x);            \
            acc[4 * g + 2].y = fmaf(w.z, v.y, acc[4 * g + 2].y);            \
            acc[4 * g + 2].z = fmaf(w.z, v.z, acc[4 * g + 2].z);            \
            acc[4 * g + 2].w = fmaf(w.z, v.w, acc[4 * g + 2].w);            \
            acc[4 * g + 3].x = fmaf(w.w, v.x, acc[4 * g + 3].x);            \
            acc[4 * g + 3].y = fmaf(w.w, v.y, acc[4 * g + 3].y);            \
            acc[4 * g + 3].z = fmaf(w.w, v.z, acc[4 * g + 3].z);            \
            acc[4 * g + 3].w = fmaf(w.w, v.w, acc[4 * g + 3].w);            \
        }                                                                   \
    }

__global__ __launch_bounds__(256) void k_conv(const float* __restrict__ in1, int C1, long ibs1,
                                              const float* __restrict__ in2, int C2, long ibs2,
                                              const float* __restrict__ W, int wpitch,
                                              const float* __restrict__ extra,
                                              const float* __restrict__ sc,
                                              const float* __restrict__ bi, int do_relu,
                                              float* __restrict__ out, long obs, int O, int Nn) {
    __shared__ float Wl[384 * 8];
    int b = blockIdx.z;
    int og0 = blockIdx.y * 8;
    int on = O - og0; if (on > 8) on = 8;
    int Ct = C1 + C2;
    for (int t = threadIdx.x; t < Ct * 8; t += 256) {
        int c = t >> 3, o = t & 7;
        Wl[t] = (o < on) ? W[(long)(og0 + o) * wpitch + c] : 0.f;
    }
    __syncthreads();
    int n0 = blockIdx.x * 1024 + threadIdx.x * 4;
    float4 acc[8];
#pragma unroll
    for (int o = 0; o < 8; ++o) acc[o] = make_float4(0.f, 0.f, 0.f, 0.f);
    const float* p1 = in1 + (long)b * ibs1 + n0;
    {
        float4 v = *reinterpret_cast<const float4*>(p1);
        for (int c = 0; c < C1 - 1; ++c) {
            float4 vn = *reinterpret_cast<const float4*>(p1 + (long)(c + 1) * Nn);
            int c8 = c * 8;
            CONV_FMA8();
            v = vn;
        }
        int c8 = (C1 - 1) * 8;
        CONV_FMA8();
    }
    if (in2) {
        const float* p2 = in2 + (long)b * ibs2 + n0;
        float4 v = *reinterpret_cast<const float4*>(p2);
        for (int c = 0; c < C2 - 1; ++c) {
            float4 vn = *reinterpret_cast<const float4*>(p2 + (long)(c + 1) * Nn);
            int c8 = (C1 + c) * 8;
            CONV_FMA8();
            v = vn;
        }
        int c8 = (Ct - 1) * 8;
        CONV_FMA8();
    }
#pragma unroll
    for (int o = 0; o < 8; ++o) {
        if (o < on) {
            float e = extra ? extra[(long)b * O + og0 + o] : 0.f;
            float s = sc ? sc[og0 + o] : 1.f;
            float bv = bi ? bi[og0 + o] : 0.f;
            float4 a = acc[o];
            a.x = (a.x + e) * s + bv;
            a.y = (a.y + e) * s + bv;
            a.z = (a.z + e) * s + bv;
            a.w = (a.w + e) * s + bv;
            if (do_relu) {
                a.x = fmaxf(a.x, 0.f); a.y = fmaxf(a.y, 0.f);
                a.z = fmaxf(a.z, 0.f); a.w = fmaxf(a.w, 0.f);
            }
            *reinterpret_cast<float4*>(out + (long)b * obs + (long)(og0 + o) * Nn + n0) = a;
        }
    }
}

// ---------------- scores[b][e][n] = sigmoid(sum_c feat*vec), all 8 e per block ----------------
__global__ __launch_bounds__(256) void k_scores(const float* __restrict__ feat,
                                                const float* __restrict__ maxp,
                                                float* __restrict__ scores) {
    __shared__ float vl[1024];
    int b = blockIdx.z;
    for (int t = threadIdx.x; t < 1024; t += 256) vl[t] = maxp[b * 1024 + t];
    __syncthreads();
    int n0 = blockIdx.x * 1024 + threadIdx.x * 4;
    float4 acc[8];
#pragma unroll
    for (int e = 0; e < 8; ++e) acc[e] = make_float4(0.f, 0.f, 0.f, 0.f);
    const float* p = feat + (long)b * 128 * NPTS + n0;
    for (int c = 0; c < 128; ++c) {
        float4 v = *reinterpret_cast<const float4*>(p + (long)c * NPTS);
#pragma unroll
        for (int e = 0; e < 8; ++e) {
            float w = vl[c * 8 + e];
            acc[e].x = fmaf(w, v.x, acc[e].x);
            acc[e].y = fmaf(w, v.y, acc[e].y);
            acc[e].z = fmaf(w, v.z, acc[e].z);
            acc[e].w = fmaf(w, v.w, acc[e].w);
        }
    }
#pragma unroll
    for (int e = 0; e < 8; ++e) {
        float4 a = acc[e];
        a.x = 1.f / (1.f + expf(-a.x));
        a.y = 1.f / (1.f + expf(-a.y));
        a.z = 1.f / (1.f + expf(-a.z));
        a.w = 1.f / (1.f + expf(-a.w));
        *reinterpret_cast<float4*>(scores + ((long)b * 8 + e) * NPTS + n0) = a;
    }
}

// ---------------- hierarchical exact sorted top-256 per (b,e) ----------------
__global__ __launch_bounds__(256) void k_sorta(const float* __restrict__ scores,
                                               unsigned int* __restrict__ kout,
                                               unsigned short* __restrict__ iout) {
    __shared__ unsigned int kv[1024];
    __shared__ unsigned short ki[1024];
    int ch = blockIdx.x & 7;
    const float* sp = scores + (long)(blockIdx.x >> 3) * NPTS + ch * 1024;
    for (int t = threadIdx.x; t < 1024; t += 256) {
        kv[t] = __float_as_uint(sp[t]) ^ 0xFFFFFFFFu;
        ki[t] = (unsigned short)(ch * 1024 + t);
    }
    __syncthreads();
    for (int k = 2; k <= 1024; k <<= 1) {
        for (int j = k >> 1; j > 0; j >>= 1) {
            for (int t = threadIdx.x; t < 1024; t += 256) {
                int ixj = t ^ j;
                if (ixj > t) {
                    unsigned int va = kv[t], vb = kv[ixj];
                    unsigned short ia = ki[t], ib = ki[ixj];
                    bool up = ((t & k) == 0);
                    bool gt = (va > vb) || (va == vb && ia > ib);
                    if (gt == up) { kv[t] = vb; kv[ixj] = va; ki[t] = ib; ki[ixj] = ia; }
                }
            }
            __syncthreads();
        }
    }
    if (threadIdx.x < 256) {
        kout[blockIdx.x * 256 + threadIdx.x] = kv[threadIdx.x];
        iout[blockIdx.x * 256 + threadIdx.x] = ki[threadIdx.x];
    }
}

__global__ __launch_bounds__(512) void k_sortb(const unsigned int* __restrict__ kin,
                                               const unsigned short* __restrict__ iin,
                                               float* __restrict__ topv,
                                               int* __restrict__ topi) {
    __shared__ unsigned int kv[2048];
    __shared__ unsigned short ki[2048];
    int be = blockIdx.x, b = be >> 3, e = be & 7;
    for (int t = threadIdx.x; t < 2048; t += 512) {
        kv[t] = kin[be * 2048 + t];
        ki[t] = iin[be * 2048 + t];
    }
    __syncthreads();
    for (int k = 2; k <= 2048; k <<= 1) {
        for (int j = k >> 1; j > 0; j >>= 1) {
            for (int t = threadIdx.x; t < 2048; t += 512) {
                int ixj = t ^ j;
                if (ixj > t) {
                    unsigned int va = kv[t], vb = kv[ixj];
                    unsigned short ia = ki[t], ib = ki[ixj];
                    bool up = ((t & k) == 0);
                    bool gt = (va > vb) || (va == vb && ia > ib);
                    if (gt == up) { kv[t] = vb; kv[ixj] = va; ki[t] = ib; ki[ixj] = ia; }
                }
            }
            __syncthreads();
        }
    }
    for (int r = threadIdx.x; r < 256; r += 512) {
        int j = r * 8 + e;  // torch-order reshape: values[b, r*8+e] = v[b,e,r]
        topv[b * 2048 + j] = __uint_as_float(kv[r] ^ 0xFFFFFFFFu);
        topi[b * 2048 + j] = (int)ki[r];
    }
}

// ---------------- pool gather: node, node_static (coords) ----------------
__global__ __launch_bounds__(256) void k_poolgather(const float* __restrict__ xyz,
                                                    const float* __restrict__ topv,
                                                    const int* __restrict__ topi,
                                                    float* __restrict__ node_ws,
                                                    float* __restrict__ out_node,
                                                    float* __restrict__ out_nstat) {
    int t = blockIdx.x * 256 + threadIdx.x;  // 4*2048
    int j = t & 2047, b = t >> 11;
    int i = topi[b * 2048 + j];
    float v = topv[b * 2048 + j];
#pragma unroll
    for (int k = 0; k < 3; ++k) {
        float sx = xyz[((long)b * 3 + k) * NPTS + i];
        float nd = sx * v;
        out_nstat[((long)b * 3 + k) * MNODE + j] = sx;
        out_node[((long)b * 3 + k) * MNODE + j] = nd;
        node_ws[((long)b * 3 + k) * MNODE + j] = nd;
    }
}

// ---------------- nf1: h ch0-127 = feat gathered * values ----------------
__global__ __launch_bounds__(256) void k_nf1(const float* __restrict__ feat,
                                             const float* __restrict__ topv,
                                             const int* __restrict__ topi,
                                             float* __restrict__ h) {
    int t = blockIdx.x * 256 + threadIdx.x;  // 4*128*2048
    int j = t & 2047, c = (t >> 11) & 127, b = t >> 18;
    int i = topi[b * 2048 + j];
    float v = topv[b * 2048 + j];
    h[((long)b * 256 + c) * MNODE + j] = feat[((long)b * 128 + c) * NPTS + i] * v;
}

// ---------------- knn20 (block-per-node): exact stable top-20 ----------------
__device__ __forceinline__ unsigned int fsortbits(float f) {
    unsigned int u = __float_as_uint(f);
    return u ^ ((unsigned int)((int)u >> 31) | 0x80000000u);
}

__global__ __launch_bounds__(256) void k_knn20(const float* __restrict__ xyz,
                                               const float* __restrict__ node,
                                               int* __restrict__ k20) {
    __shared__ unsigned int s1[256];
    __shared__ int s2[256];
    __shared__ int lcnt;
    int m = blockIdx.x & 2047, b = blockIdx.x >> 11;
    int t = threadIdx.x;
    float nx = node[((long)b * 3 + 0) * MNODE + m];
    float ny = node[((long)b * 3 + 1) * MNODE + m];
    float nz = node[((long)b * 3 + 2) * MNODE + m];
    float sm = nx * nx + ny * ny + nz * nz;
    const float* xb = xyz + (long)b * 3 * NPTS;
    unsigned int kmin = 0xFFFFFFFFu;
    for (int i = 0; i < 32; ++i) {
        int n = i * 256 + t;
        float px = xb[n], py = xb[NPTS + n], pz = xb[2 * NPTS + n];
        float d = (px * px + py * py + pz * pz) + sm - 2.f * (px * nx + py * ny + pz * nz);
        unsigned int key = fsortbits(d);
        kmin = key < kmin ? key : kmin;
    }
    s1[t] = kmin;
    if (t == 0) lcnt = 0;
    __syncthreads();
    for (int k = 2; k <= 256; k <<= 1) {
        for (int j = k >> 1; j > 0; j >>= 1) {
            int ixj = t ^ j;
            if (ixj > t) {
                unsigned int va = s1[t], vb = s1[ixj];
                bool up = ((t & k) == 0);
                if ((va > vb) == up) { s1[t] = vb; s1[ixj] = va; }
            }
            __syncthreads();
        }
    }
    unsigned int keyT = s1[19];
    __syncthreads();
    for (int i = 0; i < 32; ++i) {
        int n = i * 256 + t;
        float px = xb[n], py = xb[NPTS + n], pz = xb[2 * NPTS + n];
        float d = (px * px + py * py + pz * pz) + sm - 2.f * (px * nx + py * ny + pz * nz);
        unsigned int key = fsortbits(d);
        if (key <= keyT) {
            int p = atomicAdd(&lcnt, 1);
            if (p < 128) { s1[p] = key; s2[p] = n; }
        }
    }
    __syncthreads();
    int cnt = lcnt;  // uniform across block
    if (cnt <= 128) {
        if (t >= cnt && t < 128) { s1[t] = 0xFFFFFFFFu; s2[t] = 0x7FFFFFFF; }
        __syncthreads();
        for (int k = 2; k <= 128; k <<= 1) {
            for (int j = k >> 1; j > 0; j >>= 1) {
                if (t < 128) {
                    int ixj = t ^ j;
                    if (ixj > t) {
                        unsigned int va = s1[t], vb = s1[ixj];
                        int ia = s2[t], ib = s2[ixj];
                        bool up = ((t & k) == 0);
                        bool gt = (va > vb) || (va == vb && ia > ib);
                        if (gt == up) { s1[t] = vb; s1[ixj] = va; s2[t] = ib; s2[ixj] = ia; }
                    }
                }
                __syncthreads();
            }
        }
        if (t < 20) k20[((long)b * 2048 + m) * 20 + t] = s2[t];
    } else {
        unsigned int lastk = 0u; int lasti = -1;
        for (int r = 0; r < 20; ++r) {
            unsigned int bk = 0xFFFFFFFFu; int bi = 0x7FFFFFFF;
            for (int i = 0; i < 32; ++i) {
                int n = i * 256 + t;
                float px = xb[n], py = xb[NPTS + n], pz = xb[2 * NPTS + n];
                float d = (px * px + py * py + pz * pz) + sm - 2.f * (px * nx + py * ny + pz * nz);
                unsigned int key = fsortbits(d);
                bool gtlast = (key > lastk) || (key == lastk && n > lasti);
                bool ltbest = (key < bk) || (key == bk && n < bi);
                if (gtlast && ltbest) { bk = key; bi = n; }
            }
            s1[t] = bk; s2[t] = bi;
            __syncthreads();
            for (int s = 128; s > 0; s >>= 1) {
                if (t < s) {
                    unsigned int vo = s1[t + s]; int io = s2[t + s];
                    unsigned int vm = s1[t]; int im = s2[t];
                    if (vo < vm || (vo == vm && io < im)) { s1[t] = vo; s2[t] = io; }
                }
                __syncthreads();
            }
            if (t == 0) k20[((long)b * 2048 + m) * 20 + r] = s2[0];
            lastk = s1[0]; lasti = s2[0];
            __syncthreads();
        }
    }
}

// ---------------- aggregate: h ch128-255 = max over 20 gathered feats ----------------
__global__ __launch_bounds__(256) void k_agg(const float* __restrict__ feat,
                                             const int* __restrict__ k20,
                                             float* __restrict__ h) {
    int t = blockIdx.x * 256 + threadIdx.x;  // 4*128*2048
    int m = t & 2047, c = (t >> 11) & 127, b = t >> 18;
    const int* ip = k20 + ((long)b * 2048 + m) * 20;
    const float* fb = feat + ((long)b * 128 + c) * NPTS;
    float mx = -3.0e38f;
#pragma unroll
    for (int q = 0; q < 20; ++q) mx = fmaxf(mx, fb[ip[q] & 8191]);  // mask = fault isolation
    h[((long)b * 256 + 128 + c) * MNODE + m] = mx;
}

// ---------------- gemv: block per output o, all 4 batches; coalesced row read ----------------
__global__ __launch_bounds__(256) void k_gemv(const float* __restrict__ in, int C,
                                              const float* __restrict__ W, int wpitch,
                                              const float* __restrict__ lb,
                                              const float* __restrict__ sc,
                                              const float* __restrict__ bi, int do_relu,
                                              float* __restrict__ out, int O) {
    __shared__ float red[256];
    int o = blockIdx.x;
    int t = threadIdx.x;
    const float* wp = W + (long)o * wpitch;
    float a0 = 0.f, a1 = 0.f, a2 = 0.f, a3 = 0.f;
    for (int c = t * 4; c < C; c += 1024) {
        float4 w = *reinterpret_cast<const float4*>(wp + c);
        float4 v0 = *reinterpret_cast<const float4*>(in + 0L * C + c);
        float4 v1 = *reinterpret_cast<const float4*>(in + 1L * C + c);
        float4 v2 = *reinterpret_cast<const float4*>(in + 2L * C + c);
        float4 v3 = *reinterpret_cast<const float4*>(in + 3L * C + c);
        a0 += w.x * v0.x + w.y * v0.y + w.z * v0.z + w.w * v0.w;
        a1 += w.x * v1.x + w.y * v1.y + w.z * v1.z + w.w * v1.w;
        a2 += w.x * v2.x + w.y * v2.y + w.z * v2.z + w.w * v2.w;
        a3 += w.x * v3.x + w.y * v3.y + w.z * v3.z + w.w * v3.w;
    }
    float lbv = lb ? lb[o] : 0.f;
    float scv = sc ? sc[o] : 1.f;
    float biv = bi ? bi[o] : 0.f;
#pragma unroll
    for (int b = 0; b < 4; ++b) {
        float a = (b == 0) ? a0 : (b == 1) ? a1 : (b == 2) ? a2 : a3;
        __syncthreads();
        red[t] = a;
        __syncthreads();
        for (int s2 = 128; s2 > 0; s2 >>= 1) {
            if (t < s2) red[t] += red[t + s2];
            __syncthreads();
        }
        if (t == 0) {
            float r = (red[0] + lbv) * scv + biv;
            if (do_relu) r = fmaxf(r, 0.f);
            out[(long)b * O + o] = r;
        }
    }
}

// ---------------- unpool knn3: block = 32 points x 8 threads/point, nodes staged in LDS ----
__global__ __launch_bounds__(256) void k_knn3(const float* __restrict__ xyz,
                                              const float* __restrict__ node,
                                              int* __restrict__ k3i, float* __restrict__ k3w) {
    __shared__ float sx[2048], sy[2048], sz[2048], sn[2048];
    __shared__ float md[256][3];
    __shared__ int   mi[256][3];
    int b = blockIdx.x >> 8;                 // 256 blocks per batch
    int pbase = (blockIdx.x & 255) * 32;
    int t = threadIdx.x;
    const float* nb = node + (long)b * 3 * MNODE;
    for (int j = t; j < 2048; j += 256) {
        float qx = nb[j], qy = nb[MNODE + j], qz = nb[2 * MNODE + j];
        sx[j] = qx; sy[j] = qy; sz[j] = qz;
        sn[j] = qx * qx + qy * qy + qz * qz;   // reference computes |b|^2 once per node
    }
    __syncthreads();
    int i = t & 31, q = t >> 5;
    int n = pbase + i;
    float px = xyz[((long)b * 3 + 0) * NPTS + n];
    float py = xyz[((long)b * 3 + 1) * NPTS + n];
    float pz = xyz[((long)b * 3 + 2) * NPTS + n];
    float sp = px * px + py * py + pz * pz;
    float d0 = 3.0e38f, d1 = 3.0e38f, d2 = 3.0e38f;
    int i0 = 0, i1 = 0, i2 = 0;
    int m0 = q * 256;
#pragma unroll 4
    for (int k = 0; k < 256; ++k) {
        int m = m0 + k;
        float d = (sp + sn[m]) - 2.f * (px * sx[m] + py * sy[m] + pz * sz[m]);
        if (d < d2) {
            d2 = d; i2 = m;
            if (d2 < d1) { float td = d1; d1 = d2; d2 = td; int ti = i1; i1 = i2; i2 = ti; }
            if (d1 < d0) { float td = d0; d0 = d1; d1 = td; int ti = i0; i0 = i1; i1 = ti; }
        }
    }
    md[t][0] = d0; md[t][1] = d1; md[t][2] = d2;
    mi[t][0] = i0; mi[t][1] = i1; mi[t][2] = i2;
    __syncthreads();
    if (t < 32) {
        int p0 = 0, p1 = 0, p2 = 0, p3 = 0, p4 = 0, p5 = 0, p6 = 0, p7 = 0;
        float rd[3]; int ri[3];
#pragma unroll
        for (int r = 0; r < 3; ++r) {
            float bestd = 3.0e38f; int besti = 0x7FFFFFFF; int bestq = -1;
#define KNN3_HEAD(QQ, PV)                                                              \
            {                                                                          \
                float dd = md[(QQ) * 32 + t][PV]; int ii = mi[(QQ) * 32 + t][PV];      \
                if (dd < bestd || (dd == bestd && ii < besti)) {                       \
                    bestd = dd; besti = ii; bestq = (QQ);                              \
                }                                                                      \
            }
            KNN3_HEAD(0, p0) KNN3_HEAD(1, p1) KNN3_HEAD(2, p2) KNN3_HEAD(3, p3)
            KNN3_HEAD(4, p4) KNN3_HEAD(5, p5) KNN3_HEAD(6, p6) KNN3_HEAD(7, p7)
#undef KNN3_HEAD
            rd[r] = bestd; ri[r] = besti;
            p0 += (bestq == 0); p1 += (bestq == 1); p2 += (bestq == 2); p3 += (bestq == 3);
            p4 += (bestq == 4); p5 += (bestq == 5); p6 += (bestq == 6); p7 += (bestq == 7);
        }
        // reference: w = softmax(-negd) = softmax over the squared distances themselves
        float mxd = fmaxf(rd[0], fmaxf(rd[1], rd[2]));
        float e0 = expf(rd[0] - mxd), e1 = expf(rd[1] - mxd), e2 = expf(rd[2] - mxd);
        float inv = 1.f / (e0 + e1 + e2);
        long base = ((long)b * NPTS + pbase + t) * 3;
        k3i[base] = ri[0]; k3i[base + 1] = ri[1]; k3i[base + 2] = ri[2];
        k3w[base] = e0 * inv; k3w[base + 1] = e1 * inv; k3w[base + 2] = e2 * inv;
    }
}

__global__ __launch_bounds__(256) void k_unpool(const float* __restrict__ s7,
                                                const int* __restrict__ k3i,
                                                const float* __restrict__ k3w,
                                                float* __restrict__ sup) {
    int t = blockIdx.x * 256 + threadIdx.x;  // 4*128*8192
    int n = t & 8191, c = (t >> 13) & 127, b = t >> 20;
    long base = ((long)b * NPTS + n) * 3;
    const float* spp = s7 + ((long)b * 128 + c) * MNODE;
    float a = k3w[base] * spp[k3i[base]] + k3w[base + 1] * spp[k3i[base + 1]] +
              k3w[base + 2] * spp[k3i[base + 2]];
    sup[((long)b * 128 + c) * NPTS + n] = a;
}

extern "C" void kernel_launch(void* const* d_in, const int* in_sizes, int n_in,
                              void* d_out, int out_size, void* d_ws, size_t ws_size,
                              hipStream_t stream) {
    const float* x     = (const float*)d_in[0];
    const float* c1w   = (const float*)d_in[1];
    const float* c2w   = (const float*)d_in[2];
    const float* c2mw  = (const float*)d_in[3];
    const float* c3w   = (const float*)d_in[4];
    const float* c4w   = (const float*)d_in[5];
    const float* c5w   = (const float*)d_in[6];
    const float* c6w   = (const float*)d_in[7];
    const float* c7w   = (const float*)d_in[8];
    const float* c8w   = (const float*)d_in[9];
    const float* c9w   = (const float*)d_in[10];
    const float* c10w  = (const float*)d_in[11];
    const float* bn1s  = (const float*)d_in[12]; const float* bn1b  = (const float*)d_in[13];
    const float* bn2s  = (const float*)d_in[14]; const float* bn2b  = (const float*)d_in[15];
    const float* bn2ms = (const float*)d_in[16]; const float* bn2mb = (const float*)d_in[17];
    const float* bn3s  = (const float*)d_in[18]; const float* bn3b  = (const float*)d_in[19];
    const float* bn4s  = (const float*)d_in[20]; const float* bn4b  = (const float*)d_in[21];
    const float* bn5s  = (const float*)d_in[22]; const float* bn5b  = (const float*)d_in[23];
    const float* bn6cs = (const float*)d_in[24]; const float* bn6cb = (const float*)d_in[25];
    const float* bn7cs = (const float*)d_in[26]; const float* bn7cb = (const float*)d_in[27];
    const float* bn8s  = (const float*)d_in[28]; const float* bn8b  = (const float*)d_in[29];
    const float* bn9s  = (const float*)d_in[30]; const float* bn9b  = (const float*)d_in[31];
    const float* bn6hs = (const float*)d_in[32]; const float* bn6hb = (const float*)d_in[33];
    const float* bn7hs = (const float*)d_in[34]; const float* bn7hb = (const float*)d_in[35];
    const float* poolw = (const float*)d_in[36]; const float* poolb = (const float*)d_in[37];
    const float* l1w   = (const float*)d_in[38];
    const float* l2w   = (const float*)d_in[39]; const float* l2b   = (const float*)d_in[40];
    const float* l3w   = (const float*)d_in[41]; const float* l3b   = (const float*)d_in[42];

    float* ws   = (float*)d_ws;
    float* xt1  = ws + WS_XT1;
    float* x34  = ws + WS_A;
    float* scor = ws + WS_B;
    float* s8   = ws + WS_B;                 // aliases scores (dead by then)
    float* hbuf = ws + WS_C;
    float* s6   = ws + WS_C;                 // aliases h (dead after conv3)
    float* s7   = ws + WS_C + 1048576L;
    float* sup  = ws + WS_D;
    float* s9   = ws + WS_D;                 // aliases sup (dead after conv8)
    float* topv = ws + WS_TOPV;
    int*   topi = (int*)(ws + WS_TOPI);
    float* node = ws + WS_NODE;
    float* maxp = ws + WS_MAXP;
    float* vec  = ws + WS_VEC;
    float* c1b  = ws + WS_C1;
    float* c2b_ = ws + WS_C2;
    float* b6   = ws + WS_B6;
    int*   k20  = (int*)(ws + WS_K20);
    float* pmax1 = ws + WS_K20;              // convmax partial scratch (k20 lifetime-disjoint)
    float* pmax2 = ws + WS_K20 + 32768;      // second set (8 splits * 4 * 1024)
    int*   k3i  = (int*)(ws + WS_K3I);
    float* k3w  = ws + WS_K3W;
    // sort scratch aliases x34 region (dead until conv3)
    unsigned int*   sskeys = (unsigned int*)(ws + WS_A);
    unsigned short* ssidx  = (unsigned short*)(ws + WS_A + 65536);

    float* out       = (float*)d_out;
    float* out_cls   = out;                  // [4,15]
    float* out_seg   = out + 60;             // [4,2,8192]
    float* out_node  = out + 60 + 65536;     // [4,3,2048]
    float* out_nstat = out_node + 24576;     // [4,3,2048]

    // x1, x2 -> xt1_
    k_conv1<<<dim3(8192), dim3(256), 0, stream>>>(x, c1w, bn1s, bn1b, xt1);
    k_conv2<<<dim3(8192), dim3(256), 0, stream>>>(xt1, c2w, bn2s, bn2b, xt1);
    // FUSED conv2m + pool-proj: one launch, 2 param sets; LDS = max(16C,4112) floats
    k_convmax<<<dim3(8, 128, 4), dim3(256), 16 * 257 * 4, stream>>>(
        xt1, 128, 128L * NPTS,
        c2mw, nullptr, bn2ms, bn2mb, 1, pmax1,
        poolw, poolb, nullptr, nullptr, 0, pmax2,
        128, 1024, NPTS);
    // both maxreds in one launch (16 blocks each)
    k_maxred2<<<dim3(32), dim3(256), 0, stream>>>(pmax1, 8, 1024, vec, 2048,
                                                  pmax2, 8, 1024, maxp, 1024, 16);
    // scores
    k_scores<<<dim3(8, 1, 4), dim3(256), 0, stream>>>(xt1, maxp, scor);
    // exact top-256 per (b,e): hierarchical chunk-sort + merge-sort
    k_sorta<<<dim3(256), dim3(256), 0, stream>>>(scor, sskeys, ssidx);
    k_sortb<<<dim3(32), dim3(512), 0, stream>>>(sskeys, ssidx, topv, topi);
    // node / node_static / nf1
    k_poolgather<<<dim3(32), dim3(256), 0, stream>>>(x, topv, topi, node, out_node, out_nstat);
    k_nf1<<<dim3(4096), dim3(256), 0, stream>>>(xt1, topv, topi, hbuf);
    // aggregate (knn20 block-per-node + gather-max)
    k_knn20<<<dim3(8192), dim3(256), 0, stream>>>(x, node, k20);
    k_agg<<<dim3(4096), dim3(256), 0, stream>>>(xt1, k20, hbuf);
    // conv3 / conv4 -> x34 (8-wide o-tile)
    k_conv<<<dim3(2, 32, 4), dim3(256), 0, stream>>>(hbuf, 256, 256L * MNODE, nullptr, 0, 0,
                                                     c3w, 256, nullptr, bn3s, bn3b, 1,
                                                     x34, 512L * MNODE, 256, MNODE);
    k_conv<<<dim3(2, 32, 4), dim3(256), 0, stream>>>(x34, 256, 512L * MNODE, nullptr, 0, 0,
                                                     c4w, 256, nullptr, bn4s, bn4b, 1,
                                                     x34 + 256L * MNODE, 512L * MNODE, 256, MNODE);
    // conv5 fused max -> vector[:,1024:2048]; LDS = 16*512 floats (red aliases)
    k_convmax<<<dim3(2, 64, 4), dim3(256), 16 * 512 * 4, stream>>>(
        x34, 512, 512L * MNODE,
        c5w, nullptr, bn5s, bn5b, 1, pmax1,
        nullptr, nullptr, nullptr, nullptr, 0, nullptr,
        512, 1024, MNODE);
    k_maxred<<<dim3(16), dim3(256), 0, stream>>>(pmax1, 2, 1024, vec + 1024, 2048);
    // classification head (k_gemv: block per output, coalesced weight rows, 4-batch reuse)
    k_gemv<<<dim3(512), dim3(256), 0, stream>>>(vec, 2048, l1w, 2048, nullptr, bn6hs, bn6hb, 1, c1b, 512);
    k_gemv<<<dim3(256), dim3(256), 0, stream>>>(c1b, 512, l2w, 512, l2b, bn7hs, bn7hb, 1, c2b_, 256);
    k_gemv<<<dim3(15), dim3(256), 0, stream>>>(c2b_, 256, l3w, 256, l3b, nullptr, nullptr, 0, out_cls, 15);
    // conv6: vrep part is n-independent -> per-(b,o) base, then conv over x4
    k_gemv<<<dim3(128), dim3(256), 0, stream>>>(vec, 2048, c6w, 2304, nullptr, nullptr, nullptr, 0, b6, 128);
    k_conv<<<dim3(2, 16, 4), dim3(256), 0, stream>>>(x34 + 256L * MNODE, 256, 512L * MNODE,
                                                     nullptr, 0, 0, c6w + 2048, 2304, b6,
                                                     bn6cs, bn6cb, 1, s6, 128L * MNODE, 128, MNODE);
    k_conv<<<dim3(2, 16, 4), dim3(256), 0, stream>>>(s6, 128, 128L * MNODE, x34, 256, 512L * MNODE,
                                                     c7w, 384, nullptr, bn7cs, bn7cb, 1,
                                                     s7, 128L * MNODE, 128, MNODE);
    // unpool
    k_knn3<<<dim3(1024), dim3(256), 0, stream>>>(x, node, k3i, k3w);
    k_unpool<<<dim3(16384), dim3(256), 0, stream>>>(s7, k3i, k3w, sup);
    // conv8 / conv9 / conv10 (8-wide o-tile)
    k_conv<<<dim3(8, 16, 4), dim3(256), 0, stream>>>(sup, 128, 128L * NPTS, xt1 + 64L * NPTS, 64,
                                                     128L * NPTS, c8w, 192, nullptr, bn8s, bn8b, 1,
                                                     s8, 128L * NPTS, 128, NPTS);
    k_conv<<<dim3(8, 16, 4), dim3(256), 0, stream>>>(s8, 128, 128L * NPTS, xt1, 64, 128L * NPTS,
                                                     c9w, 192, nullptr, bn9s, bn9b, 1,
                                                     s9, 128L * NPTS, 128, NPTS);
    k_conv<<<dim3(8, 1, 4), dim3(256), 0, stream>>>(s9, 128, 128L * NPTS, nullptr, 0, 0,
                                                    c10w, 128, nullptr, nullptr, nullptr, 0,
                                                    out_seg, 2L * NPTS, 2, NPTS);
    (void)in_sizes; (void)n_in; (void)out_size; (void)ws_size;
}

// Round 14
// 1002.598 us; speedup vs baseline: 5.8725x; 5.8725x over previous
//
#include <hip/hip_runtime.h>
#include <math.h>

// Problem constants
#define NPTS 8192
#define MNODE 2048

// ---------------- ws layout (float element offsets) ----------------
#define WS_XT1  0L          // xt1_ [4][128][8192] (x1 ch0-63, x2 ch64-127) — live whole pass
#define WS_A    4194304L    // x34 [4][512][2048] (x3 ch0-255, x4 ch256-511); sort scratch EARLY
#define WS_B    8388608L    // scores [4][8][8192] early; s8 [4][128][8192] later
#define WS_C    12582912L   // h [4][256][2048] early; s6/s7 [4][128][2048] later
#define WS_D    14680064L   // sup [4][128][8192]; s9 later
#define WS_TOPV 18874368L   // [4][2048]
#define WS_TOPI 18882560L   // int [4][2048]
#define WS_NODE 18890752L   // [4][3][2048]
#define WS_MAXP 18915328L   // [4][1024]
#define WS_VEC  18919424L   // [4][2048]
#define WS_C1   18927616L   // [4][512]
#define WS_C2   18929664L   // [4][256]
#define WS_B6   18930688L   // [4][128]
#define WS_K20  18931200L   // int [4][2048][20]; ALSO convmax partial-max scratch (disjoint lifetime)
#define WS_K3I  19095040L   // int [4][8192][3]
#define WS_K3W  19193344L   // [4][8192][3]
// end = 19291648 floats = 73.6 MB

// ---------------- conv1: x[4,3,8192] -> xt1_ ch0-63 ----------------
__global__ __launch_bounds__(256) void k_conv1(const float* __restrict__ x,
                                               const float* __restrict__ W,
                                               const float* __restrict__ sc,
                                               const float* __restrict__ bi,
                                               float* __restrict__ out) {
    int t = blockIdx.x * 256 + threadIdx.x;           // 4*64*8192
    int n = t & 8191, o = (t >> 13) & 63, b = t >> 19;
    const float* xb = x + (long)b * 3 * NPTS;
    float a = W[o * 3 + 0] * xb[n] + W[o * 3 + 1] * xb[NPTS + n] + W[o * 3 + 2] * xb[2 * NPTS + n];
    a = fmaxf(a * sc[o] + bi[o], 0.f);
    out[((long)b * 128 + o) * NPTS + n] = a;
}

// ---------------- conv2: xt1_ ch0-63 -> xt1_ ch64-127 ----------------
__global__ __launch_bounds__(256) void k_conv2(const float* __restrict__ in,
                                               const float* __restrict__ W,
                                               const float* __restrict__ sc,
                                               const float* __restrict__ bi,
                                               float* __restrict__ out) {
    int t = blockIdx.x * 256 + threadIdx.x;
    int n = t & 8191, o = (t >> 13) & 63, b = t >> 19;
    const float* ip = in + (long)b * 128 * NPTS + n;
    const float* wp = W + o * 64;
    float a = 0.f;
#pragma unroll 8
    for (int c = 0; c < 64; ++c) a = fmaf(wp[c], ip[(long)c * NPTS], a);
    out[((long)b * 128 + 64 + o) * NPTS + n] = fmaxf(a * sc[o] + bi[o], 0.f);
}

// 16-output-tile FMA block: reads 4x float4 broadcast from Wl at row c16, FMAs into acc[16]
#define CMAX_FMA16()                                                        \
    {                                                                       \
        const float4* wp4 = reinterpret_cast<const float4*>(Wl + c16);      \
        _Pragma("unroll")                                                   \
        for (int g = 0; g < 4; ++g) {                                       \
            float4 w = wp4[g];                                              \
            acc[4 * g + 0].x = fmaf(w.x, v.x, acc[4 * g + 0].x);            \
            acc[4 * g + 0].y = fmaf(w.x, v.y, acc[4 * g + 0].y);            \
            acc[4 * g + 0].z = fmaf(w.x, v.z, acc[4 * g + 0].z);            \
            acc[4 * g + 0].w = fmaf(w.x, v.w, acc[4 * g + 0].w);            \
            acc[4 * g + 1].x = fmaf(w.y, v.x, acc[4 * g + 1].x);            \
            acc[4 * g + 1].y = fmaf(w.y, v.y, acc[4 * g + 1].y);            \
            acc[4 * g + 1].z = fmaf(w.y, v.z, acc[4 * g + 1].z);            \
            acc[4 * g + 1].w = fmaf(w.y, v.w, acc[4 * g + 1].w);            \
            acc[4 * g + 2].x = fmaf(w.z, v.x, acc[4 * g + 2].x);            \
            acc[4 * g + 2].y = fmaf(w.z, v.y, acc[4 * g + 2].y);            \
            acc[4 * g + 2].z = fmaf(w.z, v.z, acc[4 * g + 2].z);            \
            acc[4 * g + 2].w = fmaf(w.z, v.w, acc[4 * g + 2].w);            \
            acc[4 * g + 3].x = fmaf(w.w, v.x, acc[4 * g + 3].x);            \
            acc[4 * g + 3].y = fmaf(w.w, v.y, acc[4 * g + 3].y);            \
            acc[4 * g + 3].z = fmaf(w.w, v.z, acc[4 * g + 3].z);            \
            acc[4 * g + 3].w = fmaf(w.w, v.w, acc[4 * g + 3].w);            \
        }                                                                   \
    }

// ---------------- fused conv(+cbias)(+bn)(+relu) + partial max, DUAL param set ----------------
// 16-wide O-tile, Wl transposed [C][16], 1-deep prefetch.
// LDS alias: red[16][257] reuses Wl (disjoint lifetime, barrier-guarded).
// NOTE: NO min-waves launch bound — (256,8) forced VGPR 52->32 and spilled the
// 16 float4 accumulators (R13: 12.9GB scratch writes, 5.9x slowdown).
__global__ __launch_bounds__(256) void k_convmax(
        const float* __restrict__ in, int C, long ibs,
        const float* __restrict__ W1, const float* __restrict__ cb1,
        const float* __restrict__ sc1, const float* __restrict__ bi1, int relu1,
        float* __restrict__ pmax1,
        const float* __restrict__ W2, const float* __restrict__ cb2,
        const float* __restrict__ sc2, const float* __restrict__ bi2, int relu2,
        float* __restrict__ pmax2,
        int wpitch, int O, int Nn) {
    extern __shared__ float sm_[];
    float* Wl = sm_;              // [C][16]
    float* red = sm_;             // [16][257] — ALIASES Wl (disjoint lifetime)
    int b = blockIdx.z;
    int ns = blockIdx.x;
    int oblocks = O >> 4;
    int setid = (int)blockIdx.y / oblocks;          // uniform per block
    int og0 = ((int)blockIdx.y - setid * oblocks) * 16;
    const float* W  = setid ? W2 : W1;
    const float* cb = setid ? cb2 : cb1;
    const float* sc = setid ? sc2 : sc1;
    const float* bi = setid ? bi2 : bi1;
    int do_relu     = setid ? relu2 : relu1;
    float* pmax     = setid ? pmax2 : pmax1;
    for (int t = threadIdx.x; t < 16 * C; t += 256) {
        int c = t >> 4, o = t & 15;
        Wl[t] = W[(long)(og0 + o) * wpitch + c];
    }
    __syncthreads();
    int n0 = ns * 1024 + threadIdx.x * 4;
    float4 acc[16];
#pragma unroll
    for (int o = 0; o < 16; ++o) acc[o] = make_float4(0.f, 0.f, 0.f, 0.f);
    const float* p = in + (long)b * ibs + n0;
    float4 v = *reinterpret_cast<const float4*>(p);
    for (int c = 0; c < C - 1; ++c) {
        float4 vn = *reinterpret_cast<const float4*>(p + (long)(c + 1) * Nn);  // prefetch
        int c16 = c * 16;
        CMAX_FMA16();
        v = vn;
    }
    {
        int c16 = (C - 1) * 16;
        CMAX_FMA16();
    }
    // bn/relu + horizontal max4 into registers, THEN barrier (Wl dead), stage, tree-reduce
    float h2[16];
#pragma unroll
    for (int o = 0; o < 16; ++o) {
        float cbv = cb ? cb[og0 + o] : 0.f;
        float scv = sc ? sc[og0 + o] : 1.f;
        float biv = bi ? bi[og0 + o] : 0.f;
        float4 a = acc[o];
        float vx = (a.x + cbv) * scv + biv;
        float vy = (a.y + cbv) * scv + biv;
        float vz = (a.z + cbv) * scv + biv;
        float vw = (a.w + cbv) * scv + biv;
        if (do_relu) {
            vx = fmaxf(vx, 0.f); vy = fmaxf(vy, 0.f);
            vz = fmaxf(vz, 0.f); vw = fmaxf(vw, 0.f);
        }
        h2[o] = fmaxf(fmaxf(vx, vy), fmaxf(vz, vw));
    }
    __syncthreads();   // all Wl reads complete before red overwrites it
#pragma unroll
    for (int o = 0; o < 16; ++o) red[o * 257 + threadIdx.x] = h2[o];
    __syncthreads();
    for (int ls = 7; ls >= 0; --ls) {
        int s = 1 << ls;
        for (int w = threadIdx.x; w < 16 * s; w += 256) {
            int o = w >> ls, i = w & (s - 1);
            float* r = red + o * 257;
            r[i] = fmaxf(r[i], r[i + s]);
        }
        __syncthreads();
    }
    if (threadIdx.x < 16)
        pmax[((long)ns * 4 + b) * O + og0 + threadIdx.x] = red[threadIdx.x * 257];
}

// finalize: out[b*obs + o] = max over nsplit partials. Dual-set variant (one launch).
__global__ __launch_bounds__(256) void k_maxred2(const float* __restrict__ pA, int nsA, int OA,
                                                 float* __restrict__ outA, long obsA,
                                                 const float* __restrict__ pB, int nsB, int OB,
                                                 float* __restrict__ outB, long obsB,
                                                 int blocksA) {
    const float* pm; int ns, O; float* out; long obs; int bid = blockIdx.x;
    if (bid < blocksA) { pm = pA; ns = nsA; O = OA; out = outA; obs = obsA; }
    else { pm = pB; ns = nsB; O = OB; out = outB; obs = obsB; bid -= blocksA; }
    int t = bid * 256 + threadIdx.x;
    if (t >= 4 * O) return;
    int o = t % O, b = t / O;
    float m = -3.0e38f;
    for (int s = 0; s < ns; ++s) m = fmaxf(m, pm[((long)s * 4 + b) * O + o]);
    out[(long)b * obs + o] = m;
}

__global__ __launch_bounds__(256) void k_maxred(const float* __restrict__ pmax, int nsplit,
                                                int O, float* __restrict__ out, long obs) {
    int t = blockIdx.x * 256 + threadIdx.x;
    if (t >= 4 * O) return;
    int o = t % O, b = t / O;
    float m = -3.0e38f;
    for (int s = 0; s < nsplit; ++s) m = fmaxf(m, pmax[((long)s * 4 + b) * O + o]);
    out[(long)b * obs + o] = m;
}

// ---------------- generic conv(+extra)(+bn)(+relu), up to 2 concat inputs ----------------
// block 256, grid (Nn/1024, ceil(O/8), B). 8-wide o-tile, Wl transposed [Ct][8]
// zero-padded, 2x float4 weight reads per c, 1-deep prefetch.
#define CONV_FMA8()                                                         \
    {                                                                       \
        const float4* wp4 = reinterpret_cast<const float4*>(Wl + c8);       \
        _Pragma("unroll")                                                   \
        for (int g = 0; g < 2; ++g) {                                       \
            float4 w = wp4[g];                                              \
            acc[4 * g + 0].x = fmaf(w.x, v.x, acc[4 * g + 0].x);            \
            acc[4 * g + 0].y = fmaf(w.x, v.y, acc[4 * g + 0].y);            \
            acc[4 * g + 0].z = fmaf(w.x, v.z, acc[4 * g + 0].z);            \
            acc[4 * g + 0].w = fmaf(w.x, v.w, acc[4 * g + 0].w);            \
            acc[4 * g + 1].x = fmaf(w.y, v.x, acc[4 * g + 1].x);            \
            acc[4 * g + 1].y = fmaf(w.y, v.y, acc[4 * g + 1].y);            \
            acc[4 * g + 1].z = fmaf(w.y, v.z, acc[4 * g + 1].z);            \
            acc[4 * g + 1].w = fmaf(w.y, v.w, acc[4 * g + 1].w);            \
            acc[4 * g + 2].x = fmaf(w.z, v.x, acc[4 * g + 2].x);            \
            acc[4 * g + 2].y = fmaf(w.z, v.y, acc[4 * g + 2].y);            \
            acc[4 * g + 2].z = fmaf(w.z, v.z, acc[4 * g + 2].z);            \
            acc[4 * g + 2].w = fmaf(w.z, v.w, acc[4 * g + 2].w);            \
            acc[4 * g + 3].x = fmaf(w.w, v.x, acc[4 * g + 3].x);            \
            acc[4 * g + 3].y = fmaf(w.w, v.y, acc[4 * g + 3].y);            \
            acc[4 * g + 3].z = fmaf(w.w, v.z, acc[4 * g + 3].z);            \
            acc[4 * g + 3].w = fmaf(w.w, v.w, acc[4 * g + 3].w);            \
        }                                                                   \
    }

__global__ __launch_bounds__(256) void k_conv(const float* __restrict__ in1, int C1, long ibs1,
                                              const float* __restrict__ in2, int C2, long ibs2,
                                              const float* __restrict__ W, int wpitch,
                                              const float* __restrict__ extra,
                                              const float* __restrict__ sc,
                                              const float* __restrict__ bi, int do_relu,
                                              float* __restrict__ out, long obs, int O, int Nn) {
    __shared__ float Wl[384 * 8];
    int b = blockIdx.z;
    int og0 = blockIdx.y * 8;
    int on = O - og0; if (on > 8) on = 8;
    int Ct = C1 + C2;
    for (int t = threadIdx.x; t < Ct * 8; t += 256) {
        int c = t >> 3, o = t & 7;
        Wl[t] = (o < on) ? W[(long)(og0 + o) * wpitch + c] : 0.f;
    }
    __syncthreads();
    int n0 = blockIdx.x * 1024 + threadIdx.x * 4;
    float4 acc[8];
#pragma unroll
    for (int o = 0; o < 8; ++o) acc[o] = make_float4(0.f, 0.f, 0.f, 0.f);
    const float* p1 = in1 + (long)b * ibs1 + n0;
    {
        float4 v = *reinterpret_cast<const float4*>(p1);
        for (int c = 0; c < C1 - 1; ++c) {
            float4 vn = *reinterpret_cast<const float4*>(p1 + (long)(c + 1) * Nn);
            int c8 = c * 8;
            CONV_FMA8();
            v = vn;
        }
        int c8 = (C1 - 1) * 8;
        CONV_FMA8();
    }
    if (in2) {
        const float* p2 = in2 + (long)b * ibs2 + n0;
        float4 v = *reinterpret_cast<const float4*>(p2);
        for (int c = 0; c < C2 - 1; ++c) {
            float4 vn = *reinterpret_cast<const float4*>(p2 + (long)(c + 1) * Nn);
            int c8 = (C1 + c) * 8;
            CONV_FMA8();
            v = vn;
        }
        int c8 = (Ct - 1) * 8;
        CONV_FMA8();
    }
#pragma unroll
    for (int o = 0; o < 8; ++o) {
        if (o < on) {
            float e = extra ? extra[(long)b * O + og0 + o] : 0.f;
            float s = sc ? sc[og0 + o] : 1.f;
            float bv = bi ? bi[og0 + o] : 0.f;
            float4 a = acc[o];
            a.x = (a.x + e) * s + bv;
            a.y = (a.y + e) * s + bv;
            a.z = (a.z + e) * s + bv;
            a.w = (a.w + e) * s + bv;
            if (do_relu) {
                a.x = fmaxf(a.x, 0.f); a.y = fmaxf(a.y, 0.f);
                a.z = fmaxf(a.z, 0.f); a.w = fmaxf(a.w, 0.f);
            }
            *reinterpret_cast<float4*>(out + (long)b * obs + (long)(og0 + o) * Nn + n0) = a;
        }
    }
}

// ---------------- scores[b][e][n] = sigmoid(sum_c feat*vec), all 8 e per block ----------------
__global__ __launch_bounds__(256) void k_scores(const float* __restrict__ feat,
                                                const float* __restrict__ maxp,
                                                float* __restrict__ scores) {
    __shared__ float vl[1024];
    int b = blockIdx.z;
    for (int t = threadIdx.x; t < 1024; t += 256) vl[t] = maxp[b * 1024 + t];
    __syncthreads();
    int n0 = blockIdx.x * 1024 + threadIdx.x * 4;
    float4 acc[8];
#pragma unroll
    for (int e = 0; e < 8; ++e) acc[e] = make_float4(0.f, 0.f, 0.f, 0.f);
    const float* p = feat + (long)b * 128 * NPTS + n0;
    for (int c = 0; c < 128; ++c) {
        float4 v = *reinterpret_cast<const float4*>(p + (long)c * NPTS);
#pragma unroll
        for (int e = 0; e < 8; ++e) {
            float w = vl[c * 8 + e];
            acc[e].x = fmaf(w, v.x, acc[e].x);
            acc[e].y = fmaf(w, v.y, acc[e].y);
            acc[e].z = fmaf(w, v.z, acc[e].z);
            acc[e].w = fmaf(w, v.w, acc[e].w);
        }
    }
#pragma unroll
    for (int e = 0; e < 8; ++e) {
        float4 a = acc[e];
        a.x = 1.f / (1.f + expf(-a.x));
        a.y = 1.f / (1.f + expf(-a.y));
        a.z = 1.f / (1.f + expf(-a.z));
        a.w = 1.f / (1.f + expf(-a.w));
        *reinterpret_cast<float4*>(scores + ((long)b * 8 + e) * NPTS + n0) = a;
    }
}

// ---------------- hierarchical exact sorted top-256 per (b,e) ----------------
__global__ __launch_bounds__(256) void k_sorta(const float* __restrict__ scores,
                                               unsigned int* __restrict__ kout,
                                               unsigned short* __restrict__ iout) {
    __shared__ unsigned int kv[1024];
    __shared__ unsigned short ki[1024];
    int ch = blockIdx.x & 7;
    const float* sp = scores + (long)(blockIdx.x >> 3) * NPTS + ch * 1024;
    for (int t = threadIdx.x; t < 1024; t += 256) {
        kv[t] = __float_as_uint(sp[t]) ^ 0xFFFFFFFFu;
        ki[t] = (unsigned short)(ch * 1024 + t);
    }
    __syncthreads();
    for (int k = 2; k <= 1024; k <<= 1) {
        for (int j = k >> 1; j > 0; j >>= 1) {
            for (int t = threadIdx.x; t < 1024; t += 256) {
                int ixj = t ^ j;
                if (ixj > t) {
                    unsigned int va = kv[t], vb = kv[ixj];
                    unsigned short ia = ki[t], ib = ki[ixj];
                    bool up = ((t & k) == 0);
                    bool gt = (va > vb) || (va == vb && ia > ib);
                    if (gt == up) { kv[t] = vb; kv[ixj] = va; ki[t] = ib; ki[ixj] = ia; }
                }
            }
            __syncthreads();
        }
    }
    if (threadIdx.x < 256) {
        kout[blockIdx.x * 256 + threadIdx.x] = kv[threadIdx.x];
        iout[blockIdx.x * 256 + threadIdx.x] = ki[threadIdx.x];
    }
}

__global__ __launch_bounds__(512) void k_sortb(const unsigned int* __restrict__ kin,
                                               const unsigned short* __restrict__ iin,
                                               float* __restrict__ topv,
                                               int* __restrict__ topi) {
    __shared__ unsigned int kv[2048];
    __shared__ unsigned short ki[2048];
    int be = blockIdx.x, b = be >> 3, e = be & 7;
    for (int t = threadIdx.x; t < 2048; t += 512) {
        kv[t] = kin[be * 2048 + t];
        ki[t] = iin[be * 2048 + t];
    }
    __syncthreads();
    for (int k = 2; k <= 2048; k <<= 1) {
        for (int j = k >> 1; j > 0; j >>= 1) {
            for (int t = threadIdx.x; t < 2048; t += 512) {
                int ixj = t ^ j;
                if (ixj > t) {
                    unsigned int va = kv[t], vb = kv[ixj];
                    unsigned short ia = ki[t], ib = ki[ixj];
                    bool up = ((t & k) == 0);
                    bool gt = (va > vb) || (va == vb && ia > ib);
                    if (gt == up) { kv[t] = vb; kv[ixj] = va; ki[t] = ib; ki[ixj] = ia; }
                }
            }
            __syncthreads();
        }
    }
    for (int r = threadIdx.x; r < 256; r += 512) {
        int j = r * 8 + e;  // torch-order reshape: values[b, r*8+e] = v[b,e,r]
        topv[b * 2048 + j] = __uint_as_float(kv[r] ^ 0xFFFFFFFFu);
        topi[b * 2048 + j] = (int)ki[r];
    }
}

// ---------------- pool gather: node, node_static (coords) ----------------
__global__ __launch_bounds__(256) void k_poolgather(const float* __restrict__ xyz,
                                                    const float* __restrict__ topv,
                                                    const int* __restrict__ topi,
                                                    float* __restrict__ node_ws,
                                                    float* __restrict__ out_node,
                                                    float* __restrict__ out_nstat) {
    int t = blockIdx.x * 256 + threadIdx.x;  // 4*2048
    int j = t & 2047, b = t >> 11;
    int i = topi[b * 2048 + j];
    float v = topv[b * 2048 + j];
#pragma unroll
    for (int k = 0; k < 3; ++k) {
        float sx = xyz[((long)b * 3 + k) * NPTS + i];
        float nd = sx * v;
        out_nstat[((long)b * 3 + k) * MNODE + j] = sx;
        out_node[((long)b * 3 + k) * MNODE + j] = nd;
        node_ws[((long)b * 3 + k) * MNODE + j] = nd;
    }
}

// ---------------- nf1: h ch0-127 = feat gathered * values ----------------
__global__ __launch_bounds__(256) void k_nf1(const float* __restrict__ feat,
                                             const float* __restrict__ topv,
                                             const int* __restrict__ topi,
                                             float* __restrict__ h) {
    int t = blockIdx.x * 256 + threadIdx.x;  // 4*128*2048
    int j = t & 2047, c = (t >> 11) & 127, b = t >> 18;
    int i = topi[b * 2048 + j];
    float v = topv[b * 2048 + j];
    h[((long)b * 256 + c) * MNODE + j] = feat[((long)b * 128 + c) * NPTS + i] * v;
}

// ---------------- knn20 (block-per-node): exact stable top-20 ----------------
__device__ __forceinline__ unsigned int fsortbits(float f) {
    unsigned int u = __float_as_uint(f);
    return u ^ ((unsigned int)((int)u >> 31) | 0x80000000u);
}

__global__ __launch_bounds__(256) void k_knn20(const float* __restrict__ xyz,
                                               const float* __restrict__ node,
                                               int* __restrict__ k20) {
    __shared__ unsigned int s1[256];
    __shared__ int s2[256];
    __shared__ int lcnt;
    int m = blockIdx.x & 2047, b = blockIdx.x >> 11;
    int t = threadIdx.x;
    float nx = node[((long)b * 3 + 0) * MNODE + m];
    float ny = node[((long)b * 3 + 1) * MNODE + m];
    float nz = node[((long)b * 3 + 2) * MNODE + m];
    float sm = nx * nx + ny * ny + nz * nz;
    const float* xb = xyz + (long)b * 3 * NPTS;
    unsigned int kmin = 0xFFFFFFFFu;
    for (int i = 0; i < 32; ++i) {
        int n = i * 256 + t;
        float px = xb[n], py = xb[NPTS + n], pz = xb[2 * NPTS + n];
        float d = (px * px + py * py + pz * pz) + sm - 2.f * (px * nx + py * ny + pz * nz);
        unsigned int key = fsortbits(d);
        kmin = key < kmin ? key : kmin;
    }
    s1[t] = kmin;
    if (t == 0) lcnt = 0;
    __syncthreads();
    for (int k = 2; k <= 256; k <<= 1) {
        for (int j = k >> 1; j > 0; j >>= 1) {
            int ixj = t ^ j;
            if (ixj > t) {
                unsigned int va = s1[t], vb = s1[ixj];
                bool up = ((t & k) == 0);
                if ((va > vb) == up) { s1[t] = vb; s1[ixj] = va; }
            }
            __syncthreads();
        }
    }
    unsigned int keyT = s1[19];
    __syncthreads();
    for (int i = 0; i < 32; ++i) {
        int n = i * 256 + t;
        float px = xb[n], py = xb[NPTS + n], pz = xb[2 * NPTS + n];
        float d = (px * px + py * py + pz * pz) + sm - 2.f * (px * nx + py * ny + pz * nz);
        unsigned int key = fsortbits(d);
        if (key <= keyT) {
            int p = atomicAdd(&lcnt, 1);
            if (p < 128) { s1[p] = key; s2[p] = n; }
        }
    }
    __syncthreads();
    int cnt = lcnt;  // uniform across block
    if (cnt <= 128) {
        if (t >= cnt && t < 128) { s1[t] = 0xFFFFFFFFu; s2[t] = 0x7FFFFFFF; }
        __syncthreads();
        for (int k = 2; k <= 128; k <<= 1) {
            for (int j = k >> 1; j > 0; j >>= 1) {
                if (t < 128) {
                    int ixj = t ^ j;
                    if (ixj > t) {
                        unsigned int va = s1[t], vb = s1[ixj];
                        int ia = s2[t], ib = s2[ixj];
                        bool up = ((t & k) == 0);
                        bool gt = (va > vb) || (va == vb && ia > ib);
                        if (gt == up) { s1[t] = vb; s1[ixj] = va; s2[t] = ib; s2[ixj] = ia; }
                    }
                }
                __syncthreads();
            }
        }
        if (t < 20) k20[((long)b * 2048 + m) * 20 + t] = s2[t];
    } else {
        unsigned int lastk = 0u; int lasti = -1;
        for (int r = 0; r < 20; ++r) {
            unsigned int bk = 0xFFFFFFFFu; int bi = 0x7FFFFFFF;
            for (int i = 0; i < 32; ++i) {
                int n = i * 256 + t;
                float px = xb[n], py = xb[NPTS + n], pz = xb[2 * NPTS + n];
                float d = (px * px + py * py + pz * pz) + sm - 2.f * (px * nx + py * ny + pz * nz);
                unsigned int key = fsortbits(d);
                bool gtlast = (key > lastk) || (key == lastk && n > lasti);
                bool ltbest = (key < bk) || (key == bk && n < bi);
                if (gtlast && ltbest) { bk = key; bi = n; }
            }
            s1[t] = bk; s2[t] = bi;
            __syncthreads();
            for (int s = 128; s > 0; s >>= 1) {
                if (t < s) {
                    unsigned int vo = s1[t + s]; int io = s2[t + s];
                    unsigned int vm = s1[t]; int im = s2[t];
                    if (vo < vm || (vo == vm && io < im)) { s1[t] = vo; s2[t] = io; }
                }
                __syncthreads();
            }
            if (t == 0) k20[((long)b * 2048 + m) * 20 + r] = s2[0];
            lastk = s1[0]; lasti = s2[0];
            __syncthreads();
        }
    }
}

// ---------------- aggregate: h ch128-255 = max over 20 gathered feats ----------------
__global__ __launch_bounds__(256) void k_agg(const float* __restrict__ feat,
                                             const int* __restrict__ k20,
                                             float* __restrict__ h) {
    int t = blockIdx.x * 256 + threadIdx.x;  // 4*128*2048
    int m = t & 2047, c = (t >> 11) & 127, b = t >> 18;
    const int* ip = k20 + ((long)b * 2048 + m) * 20;
    const float* fb = feat + ((long)b * 128 + c) * NPTS;
    float mx = -3.0e38f;
#pragma unroll
    for (int q = 0; q < 20; ++q) mx = fmaxf(mx, fb[ip[q] & 8191]);  // mask = fault isolation
    h[((long)b * 256 + 128 + c) * MNODE + m] = mx;
}

// ---------------- gemv: block per output o, all 4 batches; coalesced row read ----------------
__global__ __launch_bounds__(256) void k_gemv(const float* __restrict__ in, int C,
                                              const float* __restrict__ W, int wpitch,
                                              const float* __restrict__ lb,
                                              const float* __restrict__ sc,
                                              const float* __restrict__ bi, int do_relu,
                                              float* __restrict__ out, int O) {
    __shared__ float red[256];
    int o = blockIdx.x;
    int t = threadIdx.x;
    const float* wp = W + (long)o * wpitch;
    float a0 = 0.f, a1 = 0.f, a2 = 0.f, a3 = 0.f;
    for (int c = t * 4; c < C; c += 1024) {
        float4 w = *reinterpret_cast<const float4*>(wp + c);
        float4 v0 = *reinterpret_cast<const float4*>(in + 0L * C + c);
        float4 v1 = *reinterpret_cast<const float4*>(in + 1L * C + c);
        float4 v2 = *reinterpret_cast<const float4*>(in + 2L * C + c);
        float4 v3 = *reinterpret_cast<const float4*>(in + 3L * C + c);
        a0 += w.x * v0.x + w.y * v0.y + w.z * v0.z + w.w * v0.w;
        a1 += w.x * v1.x + w.y * v1.y + w.z * v1.z + w.w * v1.w;
        a2 += w.x * v2.x + w.y * v2.y + w.z * v2.z + w.w * v2.w;
        a3 += w.x * v3.x + w.y * v3.y + w.z * v3.z + w.w * v3.w;
    }
    float lbv = lb ? lb[o] : 0.f;
    float scv = sc ? sc[o] : 1.f;
    float biv = bi ? bi[o] : 0.f;
#pragma unroll
    for (int b = 0; b < 4; ++b) {
        float a = (b == 0) ? a0 : (b == 1) ? a1 : (b == 2) ? a2 : a3;
        __syncthreads();
        red[t] = a;
        __syncthreads();
        for (int s2 = 128; s2 > 0; s2 >>= 1) {
            if (t < s2) red[t] += red[t + s2];
            __syncthreads();
        }
        if (t == 0) {
            float r = (red[0] + lbv) * scv + biv;
            if (do_relu) r = fmaxf(r, 0.f);
            out[(long)b * O + o] = r;
        }
    }
}

// ---------------- unpool knn3: block = 32 points x 8 threads/point, nodes staged in LDS ----
__global__ __launch_bounds__(256) void k_knn3(const float* __restrict__ xyz,
                                              const float* __restrict__ node,
                                              int* __restrict__ k3i, float* __restrict__ k3w) {
    __shared__ float sx[2048], sy[2048], sz[2048], sn[2048];
    __shared__ float md[256][3];
    __shared__ int   mi[256][3];
    int b = blockIdx.x >> 8;                 // 256 blocks per batch
    int pbase = (blockIdx.x & 255) * 32;
    int t = threadIdx.x;
    const float* nb = node + (long)b * 3 * MNODE;
    for (int j = t; j < 2048; j += 256) {
        float qx = nb[j], qy = nb[MNODE + j], qz = nb[2 * MNODE + j];
        sx[j] = qx; sy[j] = qy; sz[j] = qz;
        sn[j] = qx * qx + qy * qy + qz * qz;   // reference computes |b|^2 once per node
    }
    __syncthreads();
    int i = t & 31, q = t >> 5;
    int n = pbase + i;
    float px = xyz[((long)b * 3 + 0) * NPTS + n];
    float py = xyz[((long)b * 3 + 1) * NPTS + n];
    float pz = xyz[((long)b * 3 + 2) * NPTS + n];
    float sp = px * px + py * py + pz * pz;
    float d0 = 3.0e38f, d1 = 3.0e38f, d2 = 3.0e38f;
    int i0 = 0, i1 = 0, i2 = 0;
    int m0 = q * 256;
#pragma unroll 4
    for (int k = 0; k < 256; ++k) {
        int m = m0 + k;
        float d = (sp + sn[m]) - 2.f * (px * sx[m] + py * sy[m] + pz * sz[m]);
        if (d < d2) {
            d2 = d; i2 = m;
            if (d2 < d1) { float td = d1; d1 = d2; d2 = td; int ti = i1; i1 = i2; i2 = ti; }
            if (d1 < d0) { float td = d0; d0 = d1; d1 = td; int ti = i0; i0 = i1; i1 = ti; }
        }
    }
    md[t][0] = d0; md[t][1] = d1; md[t][2] = d2;
    mi[t][0] = i0; mi[t][1] = i1; mi[t][2] = i2;
    __syncthreads();
    if (t < 32) {
        int p0 = 0, p1 = 0, p2 = 0, p3 = 0, p4 = 0, p5 = 0, p6 = 0, p7 = 0;
        float rd[3]; int ri[3];
#pragma unroll
        for (int r = 0; r < 3; ++r) {
            float bestd = 3.0e38f; int besti = 0x7FFFFFFF; int bestq = -1;
#define KNN3_HEAD(QQ, PV)                                                              \
            {                                                                          \
                float dd = md[(QQ) * 32 + t][PV]; int ii = mi[(QQ) * 32 + t][PV];      \
                if (dd < bestd || (dd == bestd && ii < besti)) {                       \
                    bestd = dd; besti = ii; bestq = (QQ);                              \
                }                                                                      \
            }
            KNN3_HEAD(0, p0) KNN3_HEAD(1, p1) KNN3_HEAD(2, p2) KNN3_HEAD(3, p3)
            KNN3_HEAD(4, p4) KNN3_HEAD(5, p5) KNN3_HEAD(6, p6) KNN3_HEAD(7, p7)
#undef KNN3_HEAD
            rd[r] = bestd; ri[r] = besti;
            p0 += (bestq == 0); p1 += (bestq == 1); p2 += (bestq == 2); p3 += (bestq == 3);
            p4 += (bestq == 4); p5 += (bestq == 5); p6 += (bestq == 6); p7 += (bestq == 7);
        }
        // reference: w = softmax(-negd) = softmax over the squared distances themselves
        float mxd = fmaxf(rd[0], fmaxf(rd[1], rd[2]));
        float e0 = expf(rd[0] - mxd), e1 = expf(rd[1] - mxd), e2 = expf(rd[2] - mxd);
        float inv = 1.f / (e0 + e1 + e2);
        long base = ((long)b * NPTS + pbase + t) * 3;
        k3i[base] = ri[0]; k3i[base + 1] = ri[1]; k3i[base + 2] = ri[2];
        k3w[base] = e0 * inv; k3w[base + 1] = e1 * inv; k3w[base + 2] = e2 * inv;
    }
}

__global__ __launch_bounds__(256) void k_unpool(const float* __restrict__ s7,
                                                const int* __restrict__ k3i,
                                                const float* __restrict__ k3w,
                                                float* __restrict__ sup) {
    int t = blockIdx.x * 256 + threadIdx.x;  // 4*128*8192
    int n = t & 8191, c = (t >> 13) & 127, b = t >> 20;
    long base = ((long)b * NPTS + n) * 3;
    const float* spp = s7 + ((long)b * 128 + c) * MNODE;
    float a = k3w[base] * spp[k3i[base]] + k3w[base + 1] * spp[k3i[base + 1]] +
              k3w[base + 2] * spp[k3i[base + 2]];
    sup[((long)b * 128 + c) * NPTS + n] = a;
}

extern "C" void kernel_launch(void* const* d_in, const int* in_sizes, int n_in,
                              void* d_out, int out_size, void* d_ws, size_t ws_size,
                              hipStream_t stream) {
    const float* x     = (const float*)d_in[0];
    const float* c1w   = (const float*)d_in[1];
    const float* c2w   = (const float*)d_in[2];
    const float* c2mw  = (const float*)d_in[3];
    const float* c3w   = (const float*)d_in[4];
    const float* c4w   = (const float*)d_in[5];
    const float* c5w   = (const float*)d_in[6];
    const float* c6w   = (const float*)d_in[7];
    const float* c7w   = (const float*)d_in[8];
    const float* c8w   = (const float*)d_in[9];
    const float* c9w   = (const float*)d_in[10];
    const float* c10w  = (const float*)d_in[11];
    const float* bn1s  = (const float*)d_in[12]; const float* bn1b  = (const float*)d_in[13];
    const float* bn2s  = (const float*)d_in[14]; const float* bn2b  = (const float*)d_in[15];
    const float* bn2ms = (const float*)d_in[16]; const float* bn2mb = (const float*)d_in[17];
    const float* bn3s  = (const float*)d_in[18]; const float* bn3b  = (const float*)d_in[19];
    const float* bn4s  = (const float*)d_in[20]; const float* bn4b  = (const float*)d_in[21];
    const float* bn5s  = (const float*)d_in[22]; const float* bn5b  = (const float*)d_in[23];
    const float* bn6cs = (const float*)d_in[24]; const float* bn6cb = (const float*)d_in[25];
    const float* bn7cs = (const float*)d_in[26]; const float* bn7cb = (const float*)d_in[27];
    const float* bn8s  = (const float*)d_in[28]; const float* bn8b  = (const float*)d_in[29];
    const float* bn9s  = (const float*)d_in[30]; const float* bn9b  = (const float*)d_in[31];
    const float* bn6hs = (const float*)d_in[32]; const float* bn6hb = (const float*)d_in[33];
    const float* bn7hs = (const float*)d_in[34]; const float* bn7hb = (const float*)d_in[35];
    const float* poolw = (const float*)d_in[36]; const float* poolb = (const float*)d_in[37];
    const float* l1w   = (const float*)d_in[38];
    const float* l2w   = (const float*)d_in[39]; const float* l2b   = (const float*)d_in[40];
    const float* l3w   = (const float*)d_in[41]; const float* l3b   = (const float*)d_in[42];

    float* ws   = (float*)d_ws;
    float* xt1  = ws + WS_XT1;
    float* x34  = ws + WS_A;
    float* scor = ws + WS_B;
    float* s8   = ws + WS_B;                 // aliases scores (dead by then)
    float* hbuf = ws + WS_C;
    float* s6   = ws + WS_C;                 // aliases h (dead after conv3)
    float* s7   = ws + WS_C + 1048576L;
    float* sup  = ws + WS_D;
    float* s9   = ws + WS_D;                 // aliases sup (dead after conv8)
    float* topv = ws + WS_TOPV;
    int*   topi = (int*)(ws + WS_TOPI);
    float* node = ws + WS_NODE;
    float* maxp = ws + WS_MAXP;
    float* vec  = ws + WS_VEC;
    float* c1b  = ws + WS_C1;
    float* c2b_ = ws + WS_C2;
    float* b6   = ws + WS_B6;
    int*   k20  = (int*)(ws + WS_K20);
    float* pmax1 = ws + WS_K20;              // convmax partial scratch (k20 lifetime-disjoint)
    float* pmax2 = ws + WS_K20 + 32768;      // second set (8 splits * 4 * 1024)
    int*   k3i  = (int*)(ws + WS_K3I);
    float* k3w  = ws + WS_K3W;
    // sort scratch aliases x34 region (dead until conv3)
    unsigned int*   sskeys = (unsigned int*)(ws + WS_A);
    unsigned short* ssidx  = (unsigned short*)(ws + WS_A + 65536);

    float* out       = (float*)d_out;
    float* out_cls   = out;                  // [4,15]
    float* out_seg   = out + 60;             // [4,2,8192]
    float* out_node  = out + 60 + 65536;     // [4,3,2048]
    float* out_nstat = out_node + 24576;     // [4,3,2048]

    // x1, x2 -> xt1_
    k_conv1<<<dim3(8192), dim3(256), 0, stream>>>(x, c1w, bn1s, bn1b, xt1);
    k_conv2<<<dim3(8192), dim3(256), 0, stream>>>(xt1, c2w, bn2s, bn2b, xt1);
    // FUSED conv2m + pool-proj: one launch, 2 param sets; LDS = max(16C,4112) floats
    k_convmax<<<dim3(8, 128, 4), dim3(256), 16 * 257 * 4, stream>>>(
        xt1, 128, 128L * NPTS,
        c2mw, nullptr, bn2ms, bn2mb, 1, pmax1,
        poolw, poolb, nullptr, nullptr, 0, pmax2,
        128, 1024, NPTS);
    // both maxreds in one launch (16 blocks each)
    k_maxred2<<<dim3(32), dim3(256), 0, stream>>>(pmax1, 8, 1024, vec, 2048,
                                                  pmax2, 8, 1024, maxp, 1024, 16);
    // scores
    k_scores<<<dim3(8, 1, 4), dim3(256), 0, stream>>>(xt1, maxp, scor);
    // exact top-256 per (b,e): hierarchical chunk-sort + merge-sort
    k_sorta<<<dim3(256), dim3(256), 0, stream>>>(scor, sskeys, ssidx);
    k_sortb<<<dim3(32), dim3(512), 0, stream>>>(sskeys, ssidx, topv, topi);
    // node / node_static / nf1
    k_poolgather<<<dim3(32), dim3(256), 0, stream>>>(x, topv, topi, node, out_node, out_nstat);
    k_nf1<<<dim3(4096), dim3(256), 0, stream>>>(xt1, topv, topi, hbuf);
    // aggregate (knn20 block-per-node + gather-max)
    k_knn20<<<dim3(8192), dim3(256), 0, stream>>>(x, node, k20);
    k_agg<<<dim3(4096), dim3(256), 0, stream>>>(xt1, k20, hbuf);
    // conv3 / conv4 -> x34 (8-wide o-tile)
    k_conv<<<dim3(2, 32, 4), dim3(256), 0, stream>>>(hbuf, 256, 256L * MNODE, nullptr, 0, 0,
                                                     c3w, 256, nullptr, bn3s, bn3b, 1,
                                                     x34, 512L * MNODE, 256, MNODE);
    k_conv<<<dim3(2, 32, 4), dim3(256), 0, stream>>>(x34, 256, 512L * MNODE, nullptr, 0, 0,
                                                     c4w, 256, nullptr, bn4s, bn4b, 1,
                                                     x34 + 256L * MNODE, 512L * MNODE, 256, MNODE);
    // conv5 fused max -> vector[:,1024:2048]; LDS = 16*512 floats (red aliases)
    k_convmax<<<dim3(2, 64, 4), dim3(256), 16 * 512 * 4, stream>>>(
        x34, 512, 512L * MNODE,
        c5w, nullptr, bn5s, bn5b, 1, pmax1,
        nullptr, nullptr, nullptr, nullptr, 0, nullptr,
        512, 1024, MNODE);
    k_maxred<<<dim3(16), dim3(256), 0, stream>>>(pmax1, 2, 1024, vec + 1024, 2048);
    // classification head (k_gemv: block per output, coalesced weight rows, 4-batch reuse)
    k_gemv<<<dim3(512), dim3(256), 0, stream>>>(vec, 2048, l1w, 2048, nullptr, bn6hs, bn6hb, 1, c1b, 512);
    k_gemv<<<dim3(256), dim3(256), 0, stream>>>(c1b, 512, l2w, 512, l2b, bn7hs, bn7hb, 1, c2b_, 256);
    k_gemv<<<dim3(15), dim3(256), 0, stream>>>(c2b_, 256, l3w, 256, l3b, nullptr, nullptr, 0, out_cls, 15);
    // conv6: vrep part is n-independent -> per-(b,o) base, then conv over x4
    k_gemv<<<dim3(128), dim3(256), 0, stream>>>(vec, 2048, c6w, 2304, nullptr, nullptr, nullptr, 0, b6, 128);
    k_conv<<<dim3(2, 16, 4), dim3(256), 0, stream>>>(x34 + 256L * MNODE, 256, 512L * MNODE,
                                                     nullptr, 0, 0, c6w + 2048, 2304, b6,
                                                     bn6cs, bn6cb, 1, s6, 128L * MNODE, 128, MNODE);
    k_conv<<<dim3(2, 16, 4), dim3(256), 0, stream>>>(s6, 128, 128L * MNODE, x34, 256, 512L * MNODE,
                                                     c7w, 384, nullptr, bn7cs, bn7cb, 1,
                                                     s7, 128L * MNODE, 128, MNODE);
    // unpool
    k_knn3<<<dim3(1024), dim3(256), 0, stream>>>(x, node, k3i, k3w);
    k_unpool<<<dim3(16384), dim3(256), 0, stream>>>(s7, k3i, k3w, sup);
    // conv8 / conv9 / conv10 (8-wide o-tile)
    k_conv<<<dim3(8, 16, 4), dim3(256), 0, stream>>>(sup, 128, 128L * NPTS, xt1 + 64L * NPTS, 64,
                                                     128L * NPTS, c8w, 192, nullptr, bn8s, bn8b, 1,
                                                     s8, 128L * NPTS, 128, NPTS);
    k_conv<<<dim3(8, 16, 4), dim3(256), 0, stream>>>(s8, 128, 128L * NPTS, xt1, 64, 128L * NPTS,
                                                     c9w, 192, nullptr, bn9s, bn9b, 1,
                                                     s9, 128L * NPTS, 128, NPTS);
    k_conv<<<dim3(8, 1, 4), dim3(256), 0, stream>>>(s9, 128, 128L * NPTS, nullptr, 0, 0,
                                                    c10w, 128, nullptr, nullptr, nullptr, 0,
                                                    out_seg, 2L * NPTS, 2, NPTS);
    (void)in_sizes; (void)n_in; (void)out_size; (void)ws_size;
}

// Round 15
// 941.700 us; speedup vs baseline: 6.2523x; 1.0647x over previous
//
#include <hip/hip_runtime.h>
#include <math.h>

typedef unsigned short u16;
typedef short bf8 __attribute__((ext_vector_type(8)));   // 8 bf16 (4 VGPRs)
typedef float f4 __attribute__((ext_vector_type(4)));    // 4 fp32

// Problem constants
#define NPTS 8192
#define MNODE 2048

// ---------------- ws layout (float element offsets) ----------------
#define WS_XT1  0L          // xt1_ [4][128][8192] — live whole pass
#define WS_A    4194304L    // x34 [4][512][2048]; sort scratch EARLY
#define WS_B    8388608L    // scores early; x34b+c5wb mid; s8 late
#define WS_C    12582912L   // xtb early; h [4][256][2048]; s6/s7 later
#define WS_D    14680064L   // c2mwb early; sup [4][128][8192]; s9 later
#define WS_TOPV 18874368L
#define WS_TOPI 18882560L
#define WS_NODE 18890752L
#define WS_MAXP 18915328L
#define WS_VEC  18919424L
#define WS_C1   18927616L
#define WS_C2   18929664L
#define WS_B6   18930688L
#define WS_K20  18931200L   // int [4][2048][20]; ALSO pmax scratch (disjoint lifetime)
#define WS_K3I  19095040L
#define WS_K3W  19193344L
// end = 19291648 floats = 73.6 MB

__device__ __forceinline__ u16 bf16rne(float f) {
    unsigned u = __float_as_uint(f);
    unsigned r = u + 0x7FFFu + ((u >> 16) & 1u);
    return (u16)(r >> 16);
}

// ---------------- conv1: x[4,3,8192] -> xt1_ ch0-63 ----------------
__global__ __launch_bounds__(256) void k_conv1(const float* __restrict__ x,
                                               const float* __restrict__ W,
                                               const float* __restrict__ sc,
                                               const float* __restrict__ bi,
                                               float* __restrict__ out) {
    int t = blockIdx.x * 256 + threadIdx.x;
    int n = t & 8191, o = (t >> 13) & 63, b = t >> 19;
    const float* xb = x + (long)b * 3 * NPTS;
    float a = W[o * 3 + 0] * xb[n] + W[o * 3 + 1] * xb[NPTS + n] + W[o * 3 + 2] * xb[2 * NPTS + n];
    a = fmaxf(a * sc[o] + bi[o], 0.f);
    out[((long)b * 128 + o) * NPTS + n] = a;
}

// ---------------- conv2: xt1_ ch0-63 -> xt1_ ch64-127 ----------------
__global__ __launch_bounds__(256) void k_conv2(const float* __restrict__ in,
                                               const float* __restrict__ W,
                                               const float* __restrict__ sc,
                                               const float* __restrict__ bi,
                                               float* __restrict__ out) {
    int t = blockIdx.x * 256 + threadIdx.x;
    int n = t & 8191, o = (t >> 13) & 63, b = t >> 19;
    const float* ip = in + (long)b * 128 * NPTS + n;
    const float* wp = W + o * 64;
    float a = 0.f;
#pragma unroll 8
    for (int c = 0; c < 64; ++c) a = fmaf(wp[c], ip[(long)c * NPTS], a);
    out[((long)b * 128 + 64 + o) * NPTS + n] = fmaxf(a * sc[o] + bi[o], 0.f);
}

// ---------------- bf16 packing ----------------
// MFMA 16x16x32 bf16 A/B frag k-layout: element j of lane l covers
// k = (l>>4)*4 + (j&3) + 16*(j>>2)  (two K=16 halves; m162 tr_b16 evidence).
// We pre-permute k inside each 32-block so a lane's 8 frag elements are the
// 8 CONTIGUOUS packed entries at offset (l>>4)*8: packed[g*8+j] = orig[g*4+(j&3)+16*(j>>2)].

// weights: W f32 [O][wpitch] -> out bf16 [O][C] (k-permuted)
__global__ __launch_bounds__(256) void k_packw(const float* __restrict__ W, int wpitch,
                                               int C, int O, u16* __restrict__ out) {
    int t = blockIdx.x * 256 + threadIdx.x;
    if (t >= O * C) return;
    int o = t / C, p = t - o * C;
    int blk = p >> 5, pj = p & 31;
    int g = pj >> 3, j = pj & 7;
    int k = (blk << 5) + g * 4 + (j & 3) + 16 * (j >> 2);
    out[t] = bf16rne(W[(long)o * wpitch + k]);
}

// input: in f32 [B][C][Nn] -> out bf16 [B][Nn][C] (transpose + k-permute), LDS-tiled
__global__ __launch_bounds__(256) void k_packT(const float* __restrict__ in, int C, int Nn,
                                               u16* __restrict__ out) {
    __shared__ float tile[32][33];
    int b = blockIdx.z;
    int k0 = blockIdx.y * 32, n0 = blockIdx.x * 32;
    int tx = threadIdx.x & 31, ty = threadIdx.x >> 5;   // 32 x 8
    for (int r = 0; r < 32; r += 8)
        tile[ty + r][tx] = in[((long)b * C + k0 + ty + r) * Nn + n0 + tx];
    __syncthreads();
    for (int r = 0; r < 32; r += 8) {
        int n = n0 + ty + r;
        int p = tx;                      // packed pos within 32-block
        int g = p >> 3, j = p & 7;
        int kin = g * 4 + (j & 3) + 16 * (j >> 2);
        out[((long)b * Nn + n) * C + k0 + p] = bf16rne(tile[kin][ty + r]);
    }
}

// ---------------- bf16-MFMA conv + bn/relu + partial max over n ----------------
// in: bf16 [B][Nn][C] k-packed; wpk: bf16 [O][C] k-packed. grid (Nn/256, O/64, B),
// block 256 = 4 waves; wave w handles o-tile (y*4+w)*16 over 16 n-tiles of 16.
// C/D layout (m89): col(n)=lane&15, row(o)=(lane>>4)*4+j.
__global__ __launch_bounds__(256) void k_cvmx_bf(const u16* __restrict__ in,
                                                 const u16* __restrict__ wpk, int C,
                                                 const float* __restrict__ sc,
                                                 const float* __restrict__ bi, int do_relu,
                                                 float* __restrict__ pmax, int O, int Nn) {
    __shared__ float red[4][16][17];
    int b = blockIdx.z, nc = blockIdx.x;
    int lane = threadIdx.x & 63, w = threadIdx.x >> 6;
    int o0 = (blockIdx.y * 4 + w) * 16;
    const u16* wp = wpk + (long)(o0 + (lane & 15)) * C + ((lane >> 4) << 3);
    const u16* ip = in + ((long)b * Nn + nc * 256 + (lane & 15)) * C + ((lane >> 4) << 3);
    long nstride = 16L * C;              // 16 n rows
    f4 acc[16];
#pragma unroll
    for (int t = 0; t < 16; ++t) acc[t] = (f4)(0.f);
    for (int kk = 0; kk < C; kk += 32) {
        bf8 a = *(const bf8*)(wp + kk);
#pragma unroll
        for (int t = 0; t < 16; ++t) {
            bf8 bb = *(const bf8*)(ip + t * nstride + kk);
            acc[t] = __builtin_amdgcn_mfma_f32_16x16x32_bf16(a, bb, acc[t], 0, 0, 0);
        }
    }
#pragma unroll
    for (int j = 0; j < 4; ++j) {
        int ol = (lane >> 4) * 4 + j;
        int o = o0 + ol;
        float scv = sc ? sc[o] : 1.f;
        float biv = bi ? bi[o] : 0.f;
        float mm = -3.0e38f;
#pragma unroll
        for (int t = 0; t < 16; ++t) {
            float v = acc[t][j] * scv + biv;
            if (do_relu) v = fmaxf(v, 0.f);
            mm = fmaxf(mm, v);
        }
        red[w][ol][lane & 15] = mm;
    }
    __syncthreads();
    if (threadIdx.x < 64) {
        int ww = threadIdx.x >> 4, oo = threadIdx.x & 15;
        float mm = red[ww][oo][0];
#pragma unroll
        for (int i = 1; i < 16; ++i) mm = fmaxf(mm, red[ww][oo][i]);
        int og = (blockIdx.y * 4 + ww) * 16 + oo;
        pmax[((long)nc * 4 + b) * O + og] = mm;
    }
}

// 16-output-tile FMA block (fp32 path)
#define CMAX_FMA16()                                                        \
    {                                                                       \
        const float4* wp4 = reinterpret_cast<const float4*>(Wl + c16);      \
        _Pragma("unroll")                                                   \
        for (int g = 0; g < 4; ++g) {                                       \
            float4 w = wp4[g];                                              \
            acc[4 * g + 0].x = fmaf(w.x, v.x, acc[4 * g + 0].x);            \
            acc[4 * g + 0].y = fmaf(w.x, v.y, acc[4 * g + 0].y);            \
            acc[4 * g + 0].z = fmaf(w.x, v.z, acc[4 * g + 0].z);            \
            acc[4 * g + 0].w = fmaf(w.x, v.w, acc[4 * g + 0].w);            \
            acc[4 * g + 1].x = fmaf(w.y, v.x, acc[4 * g + 1].x);            \
            acc[4 * g + 1].y = fmaf(w.y, v.y, acc[4 * g + 1].y);            \
            acc[4 * g + 1].z = fmaf(w.y, v.z, acc[4 * g + 1].z);            \
            acc[4 * g + 1].w = fmaf(w.y, v.w, acc[4 * g + 1].w);            \
            acc[4 * g + 2].x = fmaf(w.z, v.x, acc[4 * g + 2].x);            \
            acc[4 * g + 2].y = fmaf(w.z, v.y, acc[4 * g + 2].y);            \
            acc[4 * g + 2].z = fmaf(w.z, v.z, acc[4 * g + 2].z);            \
            acc[4 * g + 2].w = fmaf(w.z, v.w, acc[4 * g + 2].w);            \
            acc[4 * g + 3].x = fmaf(w.w, v.x, acc[4 * g + 3].x);            \
            acc[4 * g + 3].y = fmaf(w.w, v.y, acc[4 * g + 3].y);            \
            acc[4 * g + 3].z = fmaf(w.w, v.z, acc[4 * g + 3].z);            \
            acc[4 * g + 3].w = fmaf(w.w, v.w, acc[4 * g + 3].w);            \
        }                                                                   \
    }

// ---------------- fp32 convmax (pool-proj only now), DUAL-capable ----------------
// NOTE: no min-waves bound (R13: (256,8) forced spill, 5.9x slowdown).
__global__ __launch_bounds__(256) void k_convmax(
        const float* __restrict__ in, int C, long ibs,
        const float* __restrict__ W1, const float* __restrict__ cb1,
        const float* __restrict__ sc1, const float* __restrict__ bi1, int relu1,
        float* __restrict__ pmax1,
        const float* __restrict__ W2, const float* __restrict__ cb2,
        const float* __restrict__ sc2, const float* __restrict__ bi2, int relu2,
        float* __restrict__ pmax2,
        int wpitch, int O, int Nn) {
    extern __shared__ float sm_[];
    float* Wl = sm_;              // [C][16]
    float* red = sm_;             // [16][257] — aliases Wl (disjoint lifetime)
    int b = blockIdx.z;
    int ns = blockIdx.x;
    int oblocks = O >> 4;
    int setid = (int)blockIdx.y / oblocks;
    int og0 = ((int)blockIdx.y - setid * oblocks) * 16;
    const float* W  = setid ? W2 : W1;
    const float* cb = setid ? cb2 : cb1;
    const float* sc = setid ? sc2 : sc1;
    const float* bi = setid ? bi2 : bi1;
    int do_relu     = setid ? relu2 : relu1;
    float* pmax     = setid ? pmax2 : pmax1;
    for (int t = threadIdx.x; t < 16 * C; t += 256) {
        int c = t >> 4, o = t & 15;
        Wl[t] = W[(long)(og0 + o) * wpitch + c];
    }
    __syncthreads();
    int n0 = ns * 1024 + threadIdx.x * 4;
    float4 acc[16];
#pragma unroll
    for (int o = 0; o < 16; ++o) acc[o] = make_float4(0.f, 0.f, 0.f, 0.f);
    const float* p = in + (long)b * ibs + n0;
    float4 v = *reinterpret_cast<const float4*>(p);
    for (int c = 0; c < C - 1; ++c) {
        float4 vn = *reinterpret_cast<const float4*>(p + (long)(c + 1) * Nn);
        int c16 = c * 16;
        CMAX_FMA16();
        v = vn;
    }
    {
        int c16 = (C - 1) * 16;
        CMAX_FMA16();
    }
    float h2[16];
#pragma unroll
    for (int o = 0; o < 16; ++o) {
        float cbv = cb ? cb[og0 + o] : 0.f;
        float scv = sc ? sc[og0 + o] : 1.f;
        float biv = bi ? bi[og0 + o] : 0.f;
        float4 a = acc[o];
        float vx = (a.x + cbv) * scv + biv;
        float vy = (a.y + cbv) * scv + biv;
        float vz = (a.z + cbv) * scv + biv;
        float vw = (a.w + cbv) * scv + biv;
        if (do_relu) {
            vx = fmaxf(vx, 0.f); vy = fmaxf(vy, 0.f);
            vz = fmaxf(vz, 0.f); vw = fmaxf(vw, 0.f);
        }
        h2[o] = fmaxf(fmaxf(vx, vy), fmaxf(vz, vw));
    }
    __syncthreads();
#pragma unroll
    for (int o = 0; o < 16; ++o) red[o * 257 + threadIdx.x] = h2[o];
    __syncthreads();
    for (int ls = 7; ls >= 0; --ls) {
        int s = 1 << ls;
        for (int w = threadIdx.x; w < 16 * s; w += 256) {
            int o = w >> ls, i = w & (s - 1);
            float* r = red + o * 257;
            r[i] = fmaxf(r[i], r[i + s]);
        }
        __syncthreads();
    }
    if (threadIdx.x < 16)
        pmax[((long)ns * 4 + b) * O + og0 + threadIdx.x] = red[threadIdx.x * 257];
}

// finalize: out[b*obs + o] = max over nsplit partials. Dual-set variant.
__global__ __launch_bounds__(256) void k_maxred2(const float* __restrict__ pA, int nsA, int OA,
                                                 float* __restrict__ outA, long obsA,
                                                 const float* __restrict__ pB, int nsB, int OB,
                                                 float* __restrict__ outB, long obsB,
                                                 int blocksA) {
    const float* pm; int ns, O; float* out; long obs; int bid = blockIdx.x;
    if (bid < blocksA) { pm = pA; ns = nsA; O = OA; out = outA; obs = obsA; }
    else { pm = pB; ns = nsB; O = OB; out = outB; obs = obsB; bid -= blocksA; }
    int t = bid * 256 + threadIdx.x;
    if (t >= 4 * O) return;
    int o = t % O, b = t / O;
    float m = -3.0e38f;
    for (int s = 0; s < ns; ++s) m = fmaxf(m, pm[((long)s * 4 + b) * O + o]);
    out[(long)b * obs + o] = m;
}

__global__ __launch_bounds__(256) void k_maxred(const float* __restrict__ pmax, int nsplit,
                                                int O, float* __restrict__ out, long obs) {
    int t = blockIdx.x * 256 + threadIdx.x;
    if (t >= 4 * O) return;
    int o = t % O, b = t / O;
    float m = -3.0e38f;
    for (int s = 0; s < nsplit; ++s) m = fmaxf(m, pmax[((long)s * 4 + b) * O + o]);
    out[(long)b * obs + o] = m;
}

// ---------------- generic conv(+extra)(+bn)(+relu), up to 2 concat inputs ----------------
#define CONV_FMA8()                                                         \
    {                                                                       \
        const float4* wp4 = reinterpret_cast<const float4*>(Wl + c8);       \
        _Pragma("unroll")                                                   \
        for (int g = 0; g < 2; ++g) {                                       \
            float4 w = wp4[g];                                              \
            acc[4 * g + 0].x = fmaf(w.x, v.x, acc[4 * g + 0].x);            \
            acc[4 * g + 0].y = fmaf(w.x, v.y, acc[4 * g + 0].y);            \
            acc[4 * g + 0].z = fmaf(w.x, v.z, acc[4 * g + 0].z);            \
            acc[4 * g + 0].w = fmaf(w.x, v.w, acc[4 * g + 0].w);            \
            acc[4 * g + 1].x = fmaf(w.y, v.x, acc[4 * g + 1].x);            \
            acc[4 * g + 1].y = fmaf(w.y, v.y, acc[4 * g + 1].y);            \
            acc[4 * g + 1].z = fmaf(w.y, v.z, acc[4 * g + 1].z);            \
            acc[4 * g + 1].w = fmaf(w.y, v.w, acc[4 * g + 1].w);            \
            acc[4 * g + 2].x = fmaf(w.z, v.x, acc[4 * g + 2].x);            \
            acc[4 * g + 2].y = fmaf(w.z, v.y, acc[4 * g + 2].y);            \
            acc[4 * g + 2].z = fmaf(w.z, v.z, acc[4 * g + 2].z);            \
            acc[4 * g + 2].w = fmaf(w.z, v.w, acc[4 * g + 2].w);            \
            acc[4 * g + 3].x = fmaf(w.w, v.x, acc[4 * g + 3].x);            \
            acc[4 * g + 3].y = fmaf(w.w, v.y, acc[4 * g + 3].y);            \
            acc[4 * g + 3].z = fmaf(w.w, v.z, acc[4 * g + 3].z);            \
            acc[4 * g + 3].w = fmaf(w.w, v.w, acc[4 * g + 3].w);            \
        }                                                                   \
    }

__global__ __launch_bounds__(256) void k_conv(const float* __restrict__ in1, int C1, long ibs1,
                                              const float* __restrict__ in2, int C2, long ibs2,
                                              const float* __restrict__ W, int wpitch,
                                              const float* __restrict__ extra,
                                              const float* __restrict__ sc,
                                              const float* __restrict__ bi, int do_relu,
                                              float* __restrict__ out, long obs, int O, int Nn) {
    __shared__ float Wl[384 * 8];
    int b = blockIdx.z;
    int og0 = blockIdx.y * 8;
    int on = O - og0; if (on > 8) on = 8;
    int Ct = C1 + C2;
    for (int t = threadIdx.x; t < Ct * 8; t += 256) {
        int c = t >> 3, o = t & 7;
        Wl[t] = (o < on) ? W[(long)(og0 + o) * wpitch + c] : 0.f;
    }
    __syncthreads();
    int n0 = blockIdx.x * 1024 + threadIdx.x * 4;
    float4 acc[8];
#pragma unroll
    for (int o = 0; o < 8; ++o) acc[o] = make_float4(0.f, 0.f, 0.f, 0.f);
    const float* p1 = in1 + (long)b * ibs1 + n0;
    {
        float4 v = *reinterpret_cast<const float4*>(p1);
        for (int c = 0; c < C1 - 1; ++c) {
            float4 vn = *reinterpret_cast<const float4*>(p1 + (long)(c + 1) * Nn);
            int c8 = c * 8;
            CONV_FMA8();
            v = vn;
        }
        int c8 = (C1 - 1) * 8;
        CONV_FMA8();
    }
    if (in2) {
        const float* p2 = in2 + (long)b * ibs2 + n0;
        float4 v = *reinterpret_cast<const float4*>(p2);
        for (int c = 0; c < C2 - 1; ++c) {
            float4 vn = *reinterpret_cast<const float4*>(p2 + (long)(c + 1) * Nn);
            int c8 = (C1 + c) * 8;
            CONV_FMA8();
            v = vn;
        }
        int c8 = (Ct - 1) * 8;
        CONV_FMA8();
    }
#pragma unroll
    for (int o = 0; o < 8; ++o) {
        if (o < on) {
            float e = extra ? extra[(long)b * O + og0 + o] : 0.f;
            float s = sc ? sc[og0 + o] : 1.f;
            float bv = bi ? bi[og0 + o] : 0.f;
            float4 a = acc[o];
            a.x = (a.x + e) * s + bv;
            a.y = (a.y + e) * s + bv;
            a.z = (a.z + e) * s + bv;
            a.w = (a.w + e) * s + bv;
            if (do_relu) {
                a.x = fmaxf(a.x, 0.f); a.y = fmaxf(a.y, 0.f);
                a.z = fmaxf(a.z, 0.f); a.w = fmaxf(a.w, 0.f);
            }
            *reinterpret_cast<float4*>(out + (long)b * obs + (long)(og0 + o) * Nn + n0) = a;
        }
    }
}

// ---------------- scores[b][e][n] = sigmoid(sum_c feat*vec), all 8 e per block ----------------
__global__ __launch_bounds__(256) void k_scores(const float* __restrict__ feat,
                                                const float* __restrict__ maxp,
                                                float* __restrict__ scores) {
    __shared__ float vl[1024];
    int b = blockIdx.z;
    for (int t = threadIdx.x; t < 1024; t += 256) vl[t] = maxp[b * 1024 + t];
    __syncthreads();
    int n0 = blockIdx.x * 1024 + threadIdx.x * 4;
    float4 acc[8];
#pragma unroll
    for (int e = 0; e < 8; ++e) acc[e] = make_float4(0.f, 0.f, 0.f, 0.f);
    const float* p = feat + (long)b * 128 * NPTS + n0;
    for (int c = 0; c < 128; ++c) {
        float4 v = *reinterpret_cast<const float4*>(p + (long)c * NPTS);
#pragma unroll
        for (int e = 0; e < 8; ++e) {
            float w = vl[c * 8 + e];
            acc[e].x = fmaf(w, v.x, acc[e].x);
            acc[e].y = fmaf(w, v.y, acc[e].y);
            acc[e].z = fmaf(w, v.z, acc[e].z);
            acc[e].w = fmaf(w, v.w, acc[e].w);
        }
    }
#pragma unroll
    for (int e = 0; e < 8; ++e) {
        float4 a = acc[e];
        a.x = 1.f / (1.f + expf(-a.x));
        a.y = 1.f / (1.f + expf(-a.y));
        a.z = 1.f / (1.f + expf(-a.z));
        a.w = 1.f / (1.f + expf(-a.w));
        *reinterpret_cast<float4*>(scores + ((long)b * 8 + e) * NPTS + n0) = a;
    }
}

// ---------------- hierarchical exact sorted top-256 per (b,e) ----------------
__global__ __launch_bounds__(256) void k_sorta(const float* __restrict__ scores,
                                               unsigned int* __restrict__ kout,
                                               unsigned short* __restrict__ iout) {
    __shared__ unsigned int kv[1024];
    __shared__ unsigned short ki[1024];
    int ch = blockIdx.x & 7;
    const float* sp = scores + (long)(blockIdx.x >> 3) * NPTS + ch * 1024;
    for (int t = threadIdx.x; t < 1024; t += 256) {
        kv[t] = __float_as_uint(sp[t]) ^ 0xFFFFFFFFu;
        ki[t] = (unsigned short)(ch * 1024 + t);
    }
    __syncthreads();
    for (int k = 2; k <= 1024; k <<= 1) {
        for (int j = k >> 1; j > 0; j >>= 1) {
            for (int t = threadIdx.x; t < 1024; t += 256) {
                int ixj = t ^ j;
                if (ixj > t) {
                    unsigned int va = kv[t], vb = kv[ixj];
                    unsigned short ia = ki[t], ib = ki[ixj];
                    bool up = ((t & k) == 0);
                    bool gt = (va > vb) || (va == vb && ia > ib);
                    if (gt == up) { kv[t] = vb; kv[ixj] = va; ki[t] = ib; ki[ixj] = ia; }
                }
            }
            __syncthreads();
        }
    }
    if (threadIdx.x < 256) {
        kout[blockIdx.x * 256 + threadIdx.x] = kv[threadIdx.x];
        iout[blockIdx.x * 256 + threadIdx.x] = ki[threadIdx.x];
    }
}

__global__ __launch_bounds__(512) void k_sortb(const unsigned int* __restrict__ kin,
                                               const unsigned short* __restrict__ iin,
                                               float* __restrict__ topv,
                                               int* __restrict__ topi) {
    __shared__ unsigned int kv[2048];
    __shared__ unsigned short ki[2048];
    int be = blockIdx.x, b = be >> 3, e = be & 7;
    for (int t = threadIdx.x; t < 2048; t += 512) {
        kv[t] = kin[be * 2048 + t];
        ki[t] = iin[be * 2048 + t];
    }
    __syncthreads();
    for (int k = 2; k <= 2048; k <<= 1) {
        for (int j = k >> 1; j > 0; j >>= 1) {
            for (int t = threadIdx.x; t < 2048; t += 512) {
                int ixj = t ^ j;
                if (ixj > t) {
                    unsigned int va = kv[t], vb = kv[ixj];
                    unsigned short ia = ki[t], ib = ki[ixj];
                    bool up = ((t & k) == 0);
                    bool gt = (va > vb) || (va == vb && ia > ib);
                    if (gt == up) { kv[t] = vb; kv[ixj] = va; ki[t] = ib; ki[ixj] = ia; }
                }
            }
            __syncthreads();
        }
    }
    for (int r = threadIdx.x; r < 256; r += 512) {
        int j = r * 8 + e;  // torch-order reshape: values[b, r*8+e] = v[b,e,r]
        topv[b * 2048 + j] = __uint_as_float(kv[r] ^ 0xFFFFFFFFu);
        topi[b * 2048 + j] = (int)ki[r];
    }
}

// ---------------- pool gather: node, node_static (coords) ----------------
__global__ __launch_bounds__(256) void k_poolgather(const float* __restrict__ xyz,
                                                    const float* __restrict__ topv,
                                                    const int* __restrict__ topi,
                                                    float* __restrict__ node_ws,
                                                    float* __restrict__ out_node,
                                                    float* __restrict__ out_nstat) {
    int t = blockIdx.x * 256 + threadIdx.x;
    int j = t & 2047, b = t >> 11;
    int i = topi[b * 2048 + j];
    float v = topv[b * 2048 + j];
#pragma unroll
    for (int k = 0; k < 3; ++k) {
        float sx = xyz[((long)b * 3 + k) * NPTS + i];
        float nd = sx * v;
        out_nstat[((long)b * 3 + k) * MNODE + j] = sx;
        out_node[((long)b * 3 + k) * MNODE + j] = nd;
        node_ws[((long)b * 3 + k) * MNODE + j] = nd;
    }
}

// ---------------- nf1: h ch0-127 = feat gathered * values ----------------
__global__ __launch_bounds__(256) void k_nf1(const float* __restrict__ feat,
                                             const float* __restrict__ topv,
                                             const int* __restrict__ topi,
                                             float* __restrict__ h) {
    int t = blockIdx.x * 256 + threadIdx.x;
    int j = t & 2047, c = (t >> 11) & 127, b = t >> 18;
    int i = topi[b * 2048 + j];
    float v = topv[b * 2048 + j];
    h[((long)b * 256 + c) * MNODE + j] = feat[((long)b * 128 + c) * NPTS + i] * v;
}

// ---------------- knn20 (block-per-node): exact stable top-20 ----------------
__device__ __forceinline__ unsigned int fsortbits(float f) {
    unsigned int u = __float_as_uint(f);
    return u ^ ((unsigned int)((int)u >> 31) | 0x80000000u);
}

__global__ __launch_bounds__(256) void k_knn20(const float* __restrict__ xyz,
                                               const float* __restrict__ node,
                                               int* __restrict__ k20) {
    __shared__ unsigned int s1[256];
    __shared__ int s2[256];
    __shared__ int lcnt;
    int m = blockIdx.x & 2047, b = blockIdx.x >> 11;
    int t = threadIdx.x;
    float nx = node[((long)b * 3 + 0) * MNODE + m];
    float ny = node[((long)b * 3 + 1) * MNODE + m];
    float nz = node[((long)b * 3 + 2) * MNODE + m];
    float sm = nx * nx + ny * ny + nz * nz;
    const float* xb = xyz + (long)b * 3 * NPTS;
    unsigned int kmin = 0xFFFFFFFFu;
    for (int i = 0; i < 32; ++i) {
        int n = i * 256 + t;
        float px = xb[n], py = xb[NPTS + n], pz = xb[2 * NPTS + n];
        float d = (px * px + py * py + pz * pz) + sm - 2.f * (px * nx + py * ny + pz * nz);
        unsigned int key = fsortbits(d);
        kmin = key < kmin ? key : kmin;
    }
    s1[t] = kmin;
    if (t == 0) lcnt = 0;
    __syncthreads();
    for (int k = 2; k <= 256; k <<= 1) {
        for (int j = k >> 1; j > 0; j >>= 1) {
            int ixj = t ^ j;
            if (ixj > t) {
                unsigned int va = s1[t], vb = s1[ixj];
                bool up = ((t & k) == 0);
                if ((va > vb) == up) { s1[t] = vb; s1[ixj] = va; }
            }
            __syncthreads();
        }
    }
    unsigned int keyT = s1[19];
    __syncthreads();
    for (int i = 0; i < 32; ++i) {
        int n = i * 256 + t;
        float px = xb[n], py = xb[NPTS + n], pz = xb[2 * NPTS + n];
        float d = (px * px + py * py + pz * pz) + sm - 2.f * (px * nx + py * ny + pz * nz);
        unsigned int key = fsortbits(d);
        if (key <= keyT) {
            int p = atomicAdd(&lcnt, 1);
            if (p < 128) { s1[p] = key; s2[p] = n; }
        }
    }
    __syncthreads();
    int cnt = lcnt;
    if (cnt <= 128) {
        if (t >= cnt && t < 128) { s1[t] = 0xFFFFFFFFu; s2[t] = 0x7FFFFFFF; }
        __syncthreads();
        for (int k = 2; k <= 128; k <<= 1) {
            for (int j = k >> 1; j > 0; j >>= 1) {
                if (t < 128) {
                    int ixj = t ^ j;
                    if (ixj > t) {
                        unsigned int va = s1[t], vb = s1[ixj];
                        int ia = s2[t], ib = s2[ixj];
                        bool up = ((t & k) == 0);
                        bool gt = (va > vb) || (va == vb && ia > ib);
                        if (gt == up) { s1[t] = vb; s1[ixj] = va; s2[t] = ib; s2[ixj] = ia; }
                    }
                }
                __syncthreads();
            }
        }
        if (t < 20) k20[((long)b * 2048 + m) * 20 + t] = s2[t];
    } else {
        unsigned int lastk = 0u; int lasti = -1;
        for (int r = 0; r < 20; ++r) {
            unsigned int bk = 0xFFFFFFFFu; int bi = 0x7FFFFFFF;
            for (int i = 0; i < 32; ++i) {
                int n = i * 256 + t;
                float px = xb[n], py = xb[NPTS + n], pz = xb[2 * NPTS + n];
                float d = (px * px + py * py + pz * pz) + sm - 2.f * (px * nx + py * ny + pz * nz);
                unsigned int key = fsortbits(d);
                bool gtlast = (key > lastk) || (key == lastk && n > lasti);
                bool ltbest = (key < bk) || (key == bk && n < bi);
                if (gtlast && ltbest) { bk = key; bi = n; }
            }
            s1[t] = bk; s2[t] = bi;
            __syncthreads();
            for (int s = 128; s > 0; s >>= 1) {
                if (t < s) {
                    unsigned int vo = s1[t + s]; int io = s2[t + s];
                    unsigned int vm = s1[t]; int im = s2[t];
                    if (vo < vm || (vo == vm && io < im)) { s1[t] = vo; s2[t] = io; }
                }
                __syncthreads();
            }
            if (t == 0) k20[((long)b * 2048 + m) * 20 + r] = s2[0];
            lastk = s1[0]; lasti = s2[0];
            __syncthreads();
        }
    }
}

// ---------------- aggregate: h ch128-255 = max over 20 gathered feats ----------------
__global__ __launch_bounds__(256) void k_agg(const float* __restrict__ feat,
                                             const int* __restrict__ k20,
                                             float* __restrict__ h) {
    int t = blockIdx.x * 256 + threadIdx.x;
    int m = t & 2047, c = (t >> 11) & 127, b = t >> 18;
    const int* ip = k20 + ((long)b * 2048 + m) * 20;
    const float* fb = feat + ((long)b * 128 + c) * NPTS;
    float mx = -3.0e38f;
#pragma unroll
    for (int q = 0; q < 20; ++q) mx = fmaxf(mx, fb[ip[q] & 8191]);
    h[((long)b * 256 + 128 + c) * MNODE + m] = mx;
}

// ---------------- gemv: block per output o, all 4 batches; coalesced row read ----------------
__global__ __launch_bounds__(256) void k_gemv(const float* __restrict__ in, int C,
                                              const float* __restrict__ W, int wpitch,
                                              const float* __restrict__ lb,
                                              const float* __restrict__ sc,
                                              const float* __restrict__ bi, int do_relu,
                                              float* __restrict__ out, int O) {
    __shared__ float red[256];
    int o = blockIdx.x;
    int t = threadIdx.x;
    const float* wp = W + (long)o * wpitch;
    float a0 = 0.f, a1 = 0.f, a2 = 0.f, a3 = 0.f;
    for (int c = t * 4; c < C; c += 1024) {
        float4 w = *reinterpret_cast<const float4*>(wp + c);
        float4 v0 = *reinterpret_cast<const float4*>(in + 0L * C + c);
        float4 v1 = *reinterpret_cast<const float4*>(in + 1L * C + c);
        float4 v2 = *reinterpret_cast<const float4*>(in + 2L * C + c);
        float4 v3 = *reinterpret_cast<const float4*>(in + 3L * C + c);
        a0 += w.x * v0.x + w.y * v0.y + w.z * v0.z + w.w * v0.w;
        a1 += w.x * v1.x + w.y * v1.y + w.z * v1.z + w.w * v1.w;
        a2 += w.x * v2.x + w.y * v2.y + w.z * v2.z + w.w * v2.w;
        a3 += w.x * v3.x + w.y * v3.y + w.z * v3.z + w.w * v3.w;
    }
    float lbv = lb ? lb[o] : 0.f;
    float scv = sc ? sc[o] : 1.f;
    float biv = bi ? bi[o] : 0.f;
#pragma unroll
    for (int b = 0; b < 4; ++b) {
        float a = (b == 0) ? a0 : (b == 1) ? a1 : (b == 2) ? a2 : a3;
        __syncthreads();
        red[t] = a;
        __syncthreads();
        for (int s2 = 128; s2 > 0; s2 >>= 1) {
            if (t < s2) red[t] += red[t + s2];
            __syncthreads();
        }
        if (t == 0) {
            float r = (red[0] + lbv) * scv + biv;
            if (do_relu) r = fmaxf(r, 0.f);
            out[(long)b * O + o] = r;
        }
    }
}

// ---------------- unpool knn3 ----------------
__global__ __launch_bounds__(256) void k_knn3(const float* __restrict__ xyz,
                                              const float* __restrict__ node,
                                              int* __restrict__ k3i, float* __restrict__ k3w) {
    __shared__ float sx[2048], sy[2048], sz[2048], sn[2048];
    __shared__ float md[256][3];
    __shared__ int   mi[256][3];
    int b = blockIdx.x >> 8;
    int pbase = (blockIdx.x & 255) * 32;
    int t = threadIdx.x;
    const float* nb = node + (long)b * 3 * MNODE;
    for (int j = t; j < 2048; j += 256) {
        float qx = nb[j], qy = nb[MNODE + j], qz = nb[2 * MNODE + j];
        sx[j] = qx; sy[j] = qy; sz[j] = qz;
        sn[j] = qx * qx + qy * qy + qz * qz;
    }
    __syncthreads();
    int i = t & 31, q = t >> 5;
    int n = pbase + i;
    float px = xyz[((long)b * 3 + 0) * NPTS + n];
    float py = xyz[((long)b * 3 + 1) * NPTS + n];
    float pz = xyz[((long)b * 3 + 2) * NPTS + n];
    float sp = px * px + py * py + pz * pz;
    float d0 = 3.0e38f, d1 = 3.0e38f, d2 = 3.0e38f;
    int i0 = 0, i1 = 0, i2 = 0;
    int m0 = q * 256;
#pragma unroll 4
    for (int k = 0; k < 256; ++k) {
        int m = m0 + k;
        float d = (sp + sn[m]) - 2.f * (px * sx[m] + py * sy[m] + pz * sz[m]);
        if (d < d2) {
            d2 = d; i2 = m;
            if (d2 < d1) { float td = d1; d1 = d2; d2 = td; int ti = i1; i1 = i2; i2 = ti; }
            if (d1 < d0) { float td = d0; d0 = d1; d1 = td; int ti = i0; i0 = i1; i1 = ti; }
        }
    }
    md[t][0] = d0; md[t][1] = d1; md[t][2] = d2;
    mi[t][0] = i0; mi[t][1] = i1; mi[t][2] = i2;
    __syncthreads();
    if (t < 32) {
        int p0 = 0, p1 = 0, p2 = 0, p3 = 0, p4 = 0, p5 = 0, p6 = 0, p7 = 0;
        float rd[3]; int ri[3];
#pragma unroll
        for (int r = 0; r < 3; ++r) {
            float bestd = 3.0e38f; int besti = 0x7FFFFFFF; int bestq = -1;
#define KNN3_HEAD(QQ, PV)                                                              \
            {                                                                          \
                float dd = md[(QQ) * 32 + t][PV]; int ii = mi[(QQ) * 32 + t][PV];      \
                if (dd < bestd || (dd == bestd && ii < besti)) {                       \
                    bestd = dd; besti = ii; bestq = (QQ);                              \
                }                                                                      \
            }
            KNN3_HEAD(0, p0) KNN3_HEAD(1, p1) KNN3_HEAD(2, p2) KNN3_HEAD(3, p3)
            KNN3_HEAD(4, p4) KNN3_HEAD(5, p5) KNN3_HEAD(6, p6) KNN3_HEAD(7, p7)
#undef KNN3_HEAD
            rd[r] = bestd; ri[r] = besti;
            p0 += (bestq == 0); p1 += (bestq == 1); p2 += (bestq == 2); p3 += (bestq == 3);
            p4 += (bestq == 4); p5 += (bestq == 5); p6 += (bestq == 6); p7 += (bestq == 7);
        }
        float mxd = fmaxf(rd[0], fmaxf(rd[1], rd[2]));
        float e0 = expf(rd[0] - mxd), e1 = expf(rd[1] - mxd), e2 = expf(rd[2] - mxd);
        float inv = 1.f / (e0 + e1 + e2);
        long base = ((long)b * NPTS + pbase + t) * 3;
        k3i[base] = ri[0]; k3i[base + 1] = ri[1]; k3i[base + 2] = ri[2];
        k3w[base] = e0 * inv; k3w[base + 1] = e1 * inv; k3w[base + 2] = e2 * inv;
    }
}

__global__ __launch_bounds__(256) void k_unpool(const float* __restrict__ s7,
                                                const int* __restrict__ k3i,
                                                const float* __restrict__ k3w,
                                                float* __restrict__ sup) {
    int t = blockIdx.x * 256 + threadIdx.x;
    int n = t & 8191, c = (t >> 13) & 127, b = t >> 20;
    long base = ((long)b * NPTS + n) * 3;
    const float* spp = s7 + ((long)b * 128 + c) * MNODE;
    float a = k3w[base] * spp[k3i[base]] + k3w[base + 1] * spp[k3i[base + 1]] +
              k3w[base + 2] * spp[k3i[base + 2]];
    sup[((long)b * 128 + c) * NPTS + n] = a;
}

extern "C" void kernel_launch(void* const* d_in, const int* in_sizes, int n_in,
                              void* d_out, int out_size, void* d_ws, size_t ws_size,
                              hipStream_t stream) {
    const float* x     = (const float*)d_in[0];
    const float* c1w   = (const float*)d_in[1];
    const float* c2w   = (const float*)d_in[2];
    const float* c2mw  = (const float*)d_in[3];
    const float* c3w   = (const float*)d_in[4];
    const float* c4w   = (const float*)d_in[5];
    const float* c5w   = (const float*)d_in[6];
    const float* c6w   = (const float*)d_in[7];
    const float* c7w   = (const float*)d_in[8];
    const float* c8w   = (const float*)d_in[9];
    const float* c9w   = (const float*)d_in[10];
    const float* c10w  = (const float*)d_in[11];
    const float* bn1s  = (const float*)d_in[12]; const float* bn1b  = (const float*)d_in[13];
    const float* bn2s  = (const float*)d_in[14]; const float* bn2b  = (const float*)d_in[15];
    const float* bn2ms = (const float*)d_in[16]; const float* bn2mb = (const float*)d_in[17];
    const float* bn3s  = (const float*)d_in[18]; const float* bn3b  = (const float*)d_in[19];
    const float* bn4s  = (const float*)d_in[20]; const float* bn4b  = (const float*)d_in[21];
    const float* bn5s  = (const float*)d_in[22]; const float* bn5b  = (const float*)d_in[23];
    const float* bn6cs = (const float*)d_in[24]; const float* bn6cb = (const float*)d_in[25];
    const float* bn7cs = (const float*)d_in[26]; const float* bn7cb = (const float*)d_in[27];
    const float* bn8s  = (const float*)d_in[28]; const float* bn8b  = (const float*)d_in[29];
    const float* bn9s  = (const float*)d_in[30]; const float* bn9b  = (const float*)d_in[31];
    const float* bn6hs = (const float*)d_in[32]; const float* bn6hb = (const float*)d_in[33];
    const float* bn7hs = (const float*)d_in[34]; const float* bn7hb = (const float*)d_in[35];
    const float* poolw = (const float*)d_in[36]; const float* poolb = (const float*)d_in[37];
    const float* l1w   = (const float*)d_in[38];
    const float* l2w   = (const float*)d_in[39]; const float* l2b   = (const float*)d_in[40];
    const float* l3w   = (const float*)d_in[41]; const float* l3b   = (const float*)d_in[42];

    float* ws   = (float*)d_ws;
    float* xt1  = ws + WS_XT1;
    float* x34  = ws + WS_A;
    float* scor = ws + WS_B;
    float* s8   = ws + WS_B;                 // aliases scores (dead by then)
    float* hbuf = ws + WS_C;
    float* s6   = ws + WS_C;
    float* s7   = ws + WS_C + 1048576L;
    float* sup  = ws + WS_D;
    float* s9   = ws + WS_D;
    float* topv = ws + WS_TOPV;
    int*   topi = (int*)(ws + WS_TOPI);
    float* node = ws + WS_NODE;
    float* maxp = ws + WS_MAXP;
    float* vec  = ws + WS_VEC;
    float* c1b  = ws + WS_C1;
    float* c2b_ = ws + WS_C2;
    float* b6   = ws + WS_B6;
    int*   k20  = (int*)(ws + WS_K20);
    float* pmax1 = ws + WS_K20;              // 32*4*1024 = 131072 floats
    float* pmax2 = ws + WS_K20 + 131072;     // 8*4*1024 = 32768 -> total 163840 = k20 size
    int*   k3i  = (int*)(ws + WS_K3I);
    float* k3w  = ws + WS_K3W;
    unsigned int*   sskeys = (unsigned int*)(ws + WS_A);
    unsigned short* ssidx  = (unsigned short*)(ws + WS_A + 65536);
    // bf16 staging (lifetime-aliased):
    u16* xtb   = (u16*)(ws + WS_C);                 // [4][8192][128] bf16 (dead before nf1)
    u16* c2mwb = (u16*)(ws + WS_D);                 // [1024][128] bf16 (dead before unpool)
    u16* x34b  = (u16*)(ws + WS_B);                 // [4][2048][512] bf16 (scores dead, s8 later)
    u16* c5wb  = (u16*)(ws + WS_B + 2097152);       // [1024][512] bf16

    float* out       = (float*)d_out;
    float* out_cls   = out;
    float* out_seg   = out + 60;
    float* out_node  = out + 60 + 65536;
    float* out_nstat = out_node + 24576;

    // x1, x2 -> xt1_
    k_conv1<<<dim3(8192), dim3(256), 0, stream>>>(x, c1w, bn1s, bn1b, xt1);
    k_conv2<<<dim3(8192), dim3(256), 0, stream>>>(xt1, c2w, bn2s, bn2b, xt1);
    // conv2m via bf16-MFMA: pack xt1 -> xtb, c2mw -> c2mwb, then MFMA convmax
    k_packT<<<dim3(256, 4, 4), dim3(256), 0, stream>>>(xt1, 128, NPTS, xtb);
    k_packw<<<dim3(512), dim3(256), 0, stream>>>(c2mw, 128, 128, 1024, c2mwb);
    k_cvmx_bf<<<dim3(32, 16, 4), dim3(256), 0, stream>>>(xtb, c2mwb, 128,
                                                         bn2ms, bn2mb, 1, pmax1, 1024, NPTS);
    // pool-proj stays fp32 (top-k rank-sensitive)
    k_convmax<<<dim3(8, 64, 4), dim3(256), 16 * 257 * 4, stream>>>(
        xt1, 128, 128L * NPTS,
        poolw, poolb, nullptr, nullptr, 0, pmax2,
        nullptr, nullptr, nullptr, nullptr, 0, nullptr,
        128, 1024, NPTS);
    k_maxred2<<<dim3(32), dim3(256), 0, stream>>>(pmax1, 32, 1024, vec, 2048,
                                                  pmax2, 8, 1024, maxp, 1024, 16);
    // scores
    k_scores<<<dim3(8, 1, 4), dim3(256), 0, stream>>>(xt1, maxp, scor);
    // exact top-256 per (b,e)
    k_sorta<<<dim3(256), dim3(256), 0, stream>>>(scor, sskeys, ssidx);
    k_sortb<<<dim3(32), dim3(512), 0, stream>>>(sskeys, ssidx, topv, topi);
    // node / node_static / nf1
    k_poolgather<<<dim3(32), dim3(256), 0, stream>>>(x, topv, topi, node, out_node, out_nstat);
    k_nf1<<<dim3(4096), dim3(256), 0, stream>>>(xt1, topv, topi, hbuf);
    // aggregate
    k_knn20<<<dim3(8192), dim3(256), 0, stream>>>(x, node, k20);
    k_agg<<<dim3(4096), dim3(256), 0, stream>>>(xt1, k20, hbuf);
    // conv3 / conv4 -> x34
    k_conv<<<dim3(2, 32, 4), dim3(256), 0, stream>>>(hbuf, 256, 256L * MNODE, nullptr, 0, 0,
                                                     c3w, 256, nullptr, bn3s, bn3b, 1,
                                                     x34, 512L * MNODE, 256, MNODE);
    k_conv<<<dim3(2, 32, 4), dim3(256), 0, stream>>>(x34, 256, 512L * MNODE, nullptr, 0, 0,
                                                     c4w, 256, nullptr, bn4s, bn4b, 1,
                                                     x34 + 256L * MNODE, 512L * MNODE, 256, MNODE);
    // conv5 via bf16-MFMA: pack x34 -> x34b, c5w -> c5wb
    k_packT<<<dim3(64, 16, 4), dim3(256), 0, stream>>>(x34, 512, MNODE, x34b);
    k_packw<<<dim3(2048), dim3(256), 0, stream>>>(c5w, 512, 512, 1024, c5wb);
    k_cvmx_bf<<<dim3(8, 16, 4), dim3(256), 0, stream>>>(x34b, c5wb, 512,
                                                        bn5s, bn5b, 1, pmax1, 1024, MNODE);
    k_maxred<<<dim3(16), dim3(256), 0, stream>>>(pmax1, 8, 1024, vec + 1024, 2048);
    // classification head
    k_gemv<<<dim3(512), dim3(256), 0, stream>>>(vec, 2048, l1w, 2048, nullptr, bn6hs, bn6hb, 1, c1b, 512);
    k_gemv<<<dim3(256), dim3(256), 0, stream>>>(c1b, 512, l2w, 512, l2b, bn7hs, bn7hb, 1, c2b_, 256);
    k_gemv<<<dim3(15), dim3(256), 0, stream>>>(c2b_, 256, l3w, 256, l3b, nullptr, nullptr, 0, out_cls, 15);
    // conv6 / conv7
    k_gemv<<<dim3(128), dim3(256), 0, stream>>>(vec, 2048, c6w, 2304, nullptr, nullptr, nullptr, 0, b6, 128);
    k_conv<<<dim3(2, 16, 4), dim3(256), 0, stream>>>(x34 + 256L * MNODE, 256, 512L * MNODE,
                                                     nullptr, 0, 0, c6w + 2048, 2304, b6,
                                                     bn6cs, bn6cb, 1, s6, 128L * MNODE, 128, MNODE);
    k_conv<<<dim3(2, 16, 4), dim3(256), 0, stream>>>(s6, 128, 128L * MNODE, x34, 256, 512L * MNODE,
                                                     c7w, 384, nullptr, bn7cs, bn7cb, 1,
                                                     s7, 128L * MNODE, 128, MNODE);
    // unpool
    k_knn3<<<dim3(1024), dim3(256), 0, stream>>>(x, node, k3i, k3w);
    k_unpool<<<dim3(16384), dim3(256), 0, stream>>>(s7, k3i, k3w, sup);
    // conv8 / conv9 / conv10
    k_conv<<<dim3(8, 16, 4), dim3(256), 0, stream>>>(sup, 128, 128L * NPTS, xt1 + 64L * NPTS, 64,
                                                     128L * NPTS, c8w, 192, nullptr, bn8s, bn8b, 1,
                                                     s8, 128L * NPTS, 128, NPTS);
    k_conv<<<dim3(8, 16, 4), dim3(256), 0, stream>>>(s8, 128, 128L * NPTS, xt1, 64, 128L * NPTS,
                                                     c9w, 192, nullptr, bn9s, bn9b, 1,
                                                     s9, 128L * NPTS, 128, NPTS);
    k_conv<<<dim3(8, 1, 4), dim3(256), 0, stream>>>(s9, 128, 128L * NPTS, nullptr, 0, 0,
                                                    c10w, 128, nullptr, nullptr, nullptr, 0,
                                                    out_seg, 2L * NPTS, 2, NPTS);
    (void)in_sizes; (void)n_in; (void)out_size; (void)ws_size;
}

// Round 16
// 920.902 us; speedup vs baseline: 6.3935x; 1.0226x over previous
//
#include <hip/hip_runtime.h>
#include <math.h>

typedef unsigned short u16;
typedef short bf8 __attribute__((ext_vector_type(8)));   // 8 bf16 (4 VGPRs)
typedef float f4 __attribute__((ext_vector_type(4)));    // 4 fp32

// Problem constants
#define NPTS 8192
#define MNODE 2048

// ---------------- ws layout (float element offsets) ----------------
#define WS_XT1  0L          // xt1_ [4][128][8192] — live whole pass
#define WS_A    4194304L    // x34 [4][512][2048]; sort scratch EARLY
#define WS_B    8388608L    // scores early; x34b+c5wb mid; s8 late
#define WS_C    12582912L   // xtb early; h [4][256][2048]; s6/s7 later
#define WS_D    14680064L   // c2mwb early; sup [4][128][8192]; s9 later
#define WS_TOPV 18874368L
#define WS_TOPI 18882560L
#define WS_NODE 18890752L
#define WS_MAXP 18915328L
#define WS_VEC  18919424L
#define WS_C1   18927616L
#define WS_C2   18929664L
#define WS_B6   18930688L
#define WS_K20  18931200L   // int [4][2048][20]; ALSO pmax scratch (disjoint lifetime)
#define WS_K3I  19095040L
#define WS_K3W  19193344L
// end = 19291648 floats = 73.6 MB

__device__ __forceinline__ u16 bf16rne(float f) {
    unsigned u = __float_as_uint(f);
    unsigned r = u + 0x7FFFu + ((u >> 16) & 1u);
    return (u16)(r >> 16);
}

// ---------------- conv1: x[4,3,8192] -> xt1_ ch0-63 ----------------
__global__ __launch_bounds__(256) void k_conv1(const float* __restrict__ x,
                                               const float* __restrict__ W,
                                               const float* __restrict__ sc,
                                               const float* __restrict__ bi,
                                               float* __restrict__ out) {
    int t = blockIdx.x * 256 + threadIdx.x;
    int n = t & 8191, o = (t >> 13) & 63, b = t >> 19;
    const float* xb = x + (long)b * 3 * NPTS;
    float a = W[o * 3 + 0] * xb[n] + W[o * 3 + 1] * xb[NPTS + n] + W[o * 3 + 2] * xb[2 * NPTS + n];
    a = fmaxf(a * sc[o] + bi[o], 0.f);
    out[((long)b * 128 + o) * NPTS + n] = a;
}

// ---------------- bf16 packing ----------------
// MFMA 16x16x32 bf16 A/B frag k-layout: element j of lane l covers
// k = (l>>4)*4 + (j&3) + 16*(j>>2). Pre-permute k inside each 32-block so a
// lane's 8 frag elements are 8 CONTIGUOUS packed entries at offset (l>>4)*8.

// weights: W f32 [O][wpitch] -> out bf16 [O][C] (k-permuted)
__global__ __launch_bounds__(256) void k_packw(const float* __restrict__ W, int wpitch,
                                               int C, int O, u16* __restrict__ out) {
    int t = blockIdx.x * 256 + threadIdx.x;
    if (t >= O * C) return;
    int o = t / C, p = t - o * C;
    int blk = p >> 5, pj = p & 31;
    int g = pj >> 3, j = pj & 7;
    int k = (blk << 5) + g * 4 + (j & 3) + 16 * (j >> 2);
    out[t] = bf16rne(W[(long)o * wpitch + k]);
}

// input: in f32 [B][C][Nn] -> out bf16 [B][Nn][C] (transpose + k-permute), LDS-tiled
__global__ __launch_bounds__(256) void k_packT(const float* __restrict__ in, int C, int Nn,
                                               u16* __restrict__ out) {
    __shared__ float tile[32][33];
    int b = blockIdx.z;
    int k0 = blockIdx.y * 32, n0 = blockIdx.x * 32;
    int tx = threadIdx.x & 31, ty = threadIdx.x >> 5;   // 32 x 8
    for (int r = 0; r < 32; r += 8)
        tile[ty + r][tx] = in[((long)b * C + k0 + ty + r) * Nn + n0 + tx];
    __syncthreads();
    for (int r = 0; r < 32; r += 8) {
        int n = n0 + ty + r;
        int p = tx;
        int g = p >> 3, j = p & 7;
        int kin = g * 4 + (j & 3) + 16 * (j >> 2);
        out[((long)b * Nn + n) * C + k0 + p] = bf16rne(tile[kin][ty + r]);
    }
}

// ---------------- bf16-MFMA conv + bn/relu + partial max over n ----------------
__global__ __launch_bounds__(256) void k_cvmx_bf(const u16* __restrict__ in,
                                                 const u16* __restrict__ wpk, int C,
                                                 const float* __restrict__ sc,
                                                 const float* __restrict__ bi, int do_relu,
                                                 float* __restrict__ pmax, int O, int Nn) {
    __shared__ float red[4][16][17];
    int b = blockIdx.z, nc = blockIdx.x;
    int lane = threadIdx.x & 63, w = threadIdx.x >> 6;
    int o0 = (blockIdx.y * 4 + w) * 16;
    const u16* wp = wpk + (long)(o0 + (lane & 15)) * C + ((lane >> 4) << 3);
    const u16* ip = in + ((long)b * Nn + nc * 256 + (lane & 15)) * C + ((lane >> 4) << 3);
    long nstride = 16L * C;
    f4 acc[16];
#pragma unroll
    for (int t = 0; t < 16; ++t) acc[t] = (f4)(0.f);
    for (int kk = 0; kk < C; kk += 32) {
        bf8 a = *(const bf8*)(wp + kk);
#pragma unroll
        for (int t = 0; t < 16; ++t) {
            bf8 bb = *(const bf8*)(ip + t * nstride + kk);
            acc[t] = __builtin_amdgcn_mfma_f32_16x16x32_bf16(a, bb, acc[t], 0, 0, 0);
        }
    }
#pragma unroll
    for (int j = 0; j < 4; ++j) {
        int ol = (lane >> 4) * 4 + j;
        int o = o0 + ol;
        float scv = sc ? sc[o] : 1.f;
        float biv = bi ? bi[o] : 0.f;
        float mm = -3.0e38f;
#pragma unroll
        for (int t = 0; t < 16; ++t) {
            float v = acc[t][j] * scv + biv;
            if (do_relu) v = fmaxf(v, 0.f);
            mm = fmaxf(mm, v);
        }
        red[w][ol][lane & 15] = mm;
    }
    __syncthreads();
    if (threadIdx.x < 64) {
        int ww = threadIdx.x >> 4, oo = threadIdx.x & 15;
        float mm = red[ww][oo][0];
#pragma unroll
        for (int i = 1; i < 16; ++i) mm = fmaxf(mm, red[ww][oo][i]);
        int og = (blockIdx.y * 4 + ww) * 16 + oo;
        pmax[((long)nc * 4 + b) * O + og] = mm;
    }
}

// 16-output-tile FMA block (fp32 path)
#define CMAX_FMA16()                                                        \
    {                                                                       \
        const float4* wp4 = reinterpret_cast<const float4*>(Wl + c16);      \
        _Pragma("unroll")                                                   \
        for (int g = 0; g < 4; ++g) {                                       \
            float4 w = wp4[g];                                              \
            acc[4 * g + 0].x = fmaf(w.x, v.x, acc[4 * g + 0].x);            \
            acc[4 * g + 0].y = fmaf(w.x, v.y, acc[4 * g + 0].y);            \
            acc[4 * g + 0].z = fmaf(w.x, v.z, acc[4 * g + 0].z);            \
            acc[4 * g + 0].w = fmaf(w.x, v.w, acc[4 * g + 0].w);            \
            acc[4 * g + 1].x = fmaf(w.y, v.x, acc[4 * g + 1].x);            \
            acc[4 * g + 1].y = fmaf(w.y, v.y, acc[4 * g + 1].y);            \
            acc[4 * g + 1].z = fmaf(w.y, v.z, acc[4 * g + 1].z);            \
            acc[4 * g + 1].w = fmaf(w.y, v.w, acc[4 * g + 1].w);            \
            acc[4 * g + 2].x = fmaf(w.z, v.x, acc[4 * g + 2].x);            \
            acc[4 * g + 2].y = fmaf(w.z, v.y, acc[4 * g + 2].y);            \
            acc[4 * g + 2].z = fmaf(w.z, v.z, acc[4 * g + 2].z);            \
            acc[4 * g + 2].w = fmaf(w.z, v.w, acc[4 * g + 2].w);            \
            acc[4 * g + 3].x = fmaf(w.w, v.x, acc[4 * g + 3].x);            \
            acc[4 * g + 3].y = fmaf(w.w, v.y, acc[4 * g + 3].y);            \
            acc[4 * g + 3].z = fmaf(w.w, v.z, acc[4 * g + 3].z);            \
            acc[4 * g + 3].w = fmaf(w.w, v.w, acc[4 * g + 3].w);            \
        }                                                                   \
    }

// ---------------- fp32 convmax (pool-proj only; rank-sensitive path) ----------------
// NOTE: no min-waves bound (R13: (256,8) forced VGPR 52->32 spill, 5.9x slowdown).
__global__ __launch_bounds__(256) void k_convmax(
        const float* __restrict__ in, int C, long ibs,
        const float* __restrict__ W1, const float* __restrict__ cb1,
        const float* __restrict__ sc1, const float* __restrict__ bi1, int relu1,
        float* __restrict__ pmax1,
        const float* __restrict__ W2, const float* __restrict__ cb2,
        const float* __restrict__ sc2, const float* __restrict__ bi2, int relu2,
        float* __restrict__ pmax2,
        int wpitch, int O, int Nn) {
    extern __shared__ float sm_[];
    float* Wl = sm_;              // [C][16]
    float* red = sm_;             // [16][257] — aliases Wl (disjoint lifetime)
    int b = blockIdx.z;
    int ns = blockIdx.x;
    int oblocks = O >> 4;
    int setid = (int)blockIdx.y / oblocks;
    int og0 = ((int)blockIdx.y - setid * oblocks) * 16;
    const float* W  = setid ? W2 : W1;
    const float* cb = setid ? cb2 : cb1;
    const float* sc = setid ? sc2 : sc1;
    const float* bi = setid ? bi2 : bi1;
    int do_relu     = setid ? relu2 : relu1;
    float* pmax     = setid ? pmax2 : pmax1;
    for (int t = threadIdx.x; t < 16 * C; t += 256) {
        int c = t >> 4, o = t & 15;
        Wl[t] = W[(long)(og0 + o) * wpitch + c];
    }
    __syncthreads();
    int n0 = ns * 1024 + threadIdx.x * 4;
    float4 acc[16];
#pragma unroll
    for (int o = 0; o < 16; ++o) acc[o] = make_float4(0.f, 0.f, 0.f, 0.f);
    const float* p = in + (long)b * ibs + n0;
    float4 v = *reinterpret_cast<const float4*>(p);
    for (int c = 0; c < C - 1; ++c) {
        float4 vn = *reinterpret_cast<const float4*>(p + (long)(c + 1) * Nn);
        int c16 = c * 16;
        CMAX_FMA16();
        v = vn;
    }
    {
        int c16 = (C - 1) * 16;
        CMAX_FMA16();
    }
    float h2[16];
#pragma unroll
    for (int o = 0; o < 16; ++o) {
        float cbv = cb ? cb[og0 + o] : 0.f;
        float scv = sc ? sc[og0 + o] : 1.f;
        float biv = bi ? bi[og0 + o] : 0.f;
        float4 a = acc[o];
        float vx = (a.x + cbv) * scv + biv;
        float vy = (a.y + cbv) * scv + biv;
        float vz = (a.z + cbv) * scv + biv;
        float vw = (a.w + cbv) * scv + biv;
        if (do_relu) {
            vx = fmaxf(vx, 0.f); vy = fmaxf(vy, 0.f);
            vz = fmaxf(vz, 0.f); vw = fmaxf(vw, 0.f);
        }
        h2[o] = fmaxf(fmaxf(vx, vy), fmaxf(vz, vw));
    }
    __syncthreads();
#pragma unroll
    for (int o = 0; o < 16; ++o) red[o * 257 + threadIdx.x] = h2[o];
    __syncthreads();
    for (int ls = 7; ls >= 0; --ls) {
        int s = 1 << ls;
        for (int w = threadIdx.x; w < 16 * s; w += 256) {
            int o = w >> ls, i = w & (s - 1);
            float* r = red + o * 257;
            r[i] = fmaxf(r[i], r[i + s]);
        }
        __syncthreads();
    }
    if (threadIdx.x < 16)
        pmax[((long)ns * 4 + b) * O + og0 + threadIdx.x] = red[threadIdx.x * 257];
}

// finalize: out[b*obs + o] = max over nsplit partials. Dual-set variant.
__global__ __launch_bounds__(256) void k_maxred2(const float* __restrict__ pA, int nsA, int OA,
                                                 float* __restrict__ outA, long obsA,
                                                 const float* __restrict__ pB, int nsB, int OB,
                                                 float* __restrict__ outB, long obsB,
                                                 int blocksA) {
    const float* pm; int ns, O; float* out; long obs; int bid = blockIdx.x;
    if (bid < blocksA) { pm = pA; ns = nsA; O = OA; out = outA; obs = obsA; }
    else { pm = pB; ns = nsB; O = OB; out = outB; obs = obsB; bid -= blocksA; }
    int t = bid * 256 + threadIdx.x;
    if (t >= 4 * O) return;
    int o = t % O, b = t / O;
    float m = -3.0e38f;
    for (int s = 0; s < ns; ++s) m = fmaxf(m, pm[((long)s * 4 + b) * O + o]);
    out[(long)b * obs + o] = m;
}

__global__ __launch_bounds__(256) void k_maxred(const float* __restrict__ pmax, int nsplit,
                                                int O, float* __restrict__ out, long obs) {
    int t = blockIdx.x * 256 + threadIdx.x;
    if (t >= 4 * O) return;
    int o = t % O, b = t / O;
    float m = -3.0e38f;
    for (int s = 0; s < nsplit; ++s) m = fmaxf(m, pmax[((long)s * 4 + b) * O + o]);
    out[(long)b * obs + o] = m;
}

// ---------------- generic conv(+extra)(+bn)(+relu), up to 2 concat inputs ----------------
#define CONV_FMA8()                                                         \
    {                                                                       \
        const float4* wp4 = reinterpret_cast<const float4*>(Wl + c8);       \
        _Pragma("unroll")                                                   \
        for (int g = 0; g < 2; ++g) {                                       \
            float4 w = wp4[g];                                              \
            acc[4 * g + 0].x = fmaf(w.x, v.x, acc[4 * g + 0].x);            \
            acc[4 * g + 0].y = fmaf(w.x, v.y, acc[4 * g + 0].y);            \
            acc[4 * g + 0].z = fmaf(w.x, v.z, acc[4 * g + 0].z);            \
            acc[4 * g + 0].w = fmaf(w.x, v.w, acc[4 * g + 0].w);            \
            acc[4 * g + 1].x = fmaf(w.y, v.x, acc[4 * g + 1].x);            \
            acc[4 * g + 1].y = fmaf(w.y, v.y, acc[4 * g + 1].y);            \
            acc[4 * g + 1].z = fmaf(w.y, v.z, acc[4 * g + 1].z);            \
            acc[4 * g + 1].w = fmaf(w.y, v.w, acc[4 * g + 1].w);            \
            acc[4 * g + 2].x = fmaf(w.z, v.x, acc[4 * g + 2].x);            \
            acc[4 * g + 2].y = fmaf(w.z, v.y, acc[4 * g + 2].y);            \
            acc[4 * g + 2].z = fmaf(w.z, v.z, acc[4 * g + 2].z);            \
            acc[4 * g + 2].w = fmaf(w.z, v.w, acc[4 * g + 2].w);            \
            acc[4 * g + 3].x = fmaf(w.w, v.x, acc[4 * g + 3].x);            \
            acc[4 * g + 3].y = fmaf(w.w, v.y, acc[4 * g + 3].y);            \
            acc[4 * g + 3].z = fmaf(w.w, v.z, acc[4 * g + 3].z);            \
            acc[4 * g + 3].w = fmaf(w.w, v.w, acc[4 * g + 3].w);            \
        }                                                                   \
    }

__global__ __launch_bounds__(256) void k_conv(const float* __restrict__ in1, int C1, long ibs1,
                                              const float* __restrict__ in2, int C2, long ibs2,
                                              const float* __restrict__ W, int wpitch,
                                              const float* __restrict__ extra,
                                              const float* __restrict__ sc,
                                              const float* __restrict__ bi, int do_relu,
                                              float* __restrict__ out, long obs, int O, int Nn) {
    __shared__ float Wl[384 * 8];
    int b = blockIdx.z;
    int og0 = blockIdx.y * 8;
    int on = O - og0; if (on > 8) on = 8;
    int Ct = C1 + C2;
    for (int t = threadIdx.x; t < Ct * 8; t += 256) {
        int c = t >> 3, o = t & 7;
        Wl[t] = (o < on) ? W[(long)(og0 + o) * wpitch + c] : 0.f;
    }
    __syncthreads();
    int n0 = blockIdx.x * 1024 + threadIdx.x * 4;
    float4 acc[8];
#pragma unroll
    for (int o = 0; o < 8; ++o) acc[o] = make_float4(0.f, 0.f, 0.f, 0.f);
    const float* p1 = in1 + (long)b * ibs1 + n0;
    {
        float4 v = *reinterpret_cast<const float4*>(p1);
        for (int c = 0; c < C1 - 1; ++c) {
            float4 vn = *reinterpret_cast<const float4*>(p1 + (long)(c + 1) * Nn);
            int c8 = c * 8;
            CONV_FMA8();
            v = vn;
        }
        int c8 = (C1 - 1) * 8;
        CONV_FMA8();
    }
    if (in2) {
        const float* p2 = in2 + (long)b * ibs2 + n0;
        float4 v = *reinterpret_cast<const float4*>(p2);
        for (int c = 0; c < C2 - 1; ++c) {
            float4 vn = *reinterpret_cast<const float4*>(p2 + (long)(c + 1) * Nn);
            int c8 = (C1 + c) * 8;
            CONV_FMA8();
            v = vn;
        }
        int c8 = (Ct - 1) * 8;
        CONV_FMA8();
    }
#pragma unroll
    for (int o = 0; o < 8; ++o) {
        if (o < on) {
            float e = extra ? extra[(long)b * O + og0 + o] : 0.f;
            float s = sc ? sc[og0 + o] : 1.f;
            float bv = bi ? bi[og0 + o] : 0.f;
            float4 a = acc[o];
            a.x = (a.x + e) * s + bv;
            a.y = (a.y + e) * s + bv;
            a.z = (a.z + e) * s + bv;
            a.w = (a.w + e) * s + bv;
            if (do_relu) {
                a.x = fmaxf(a.x, 0.f); a.y = fmaxf(a.y, 0.f);
                a.z = fmaxf(a.z, 0.f); a.w = fmaxf(a.w, 0.f);
            }
            *reinterpret_cast<float4*>(out + (long)b * obs + (long)(og0 + o) * Nn + n0) = a;
        }
    }
}

// ---------------- scores: one n per thread, all 8 e; grid (32,1,4)=128 blocks ----------------
// Same per-output c-ascending summation order as before -> bit-identical results.
__global__ __launch_bounds__(256) void k_scores(const float* __restrict__ feat,
                                                const float* __restrict__ maxp,
                                                float* __restrict__ scores) {
    __shared__ float vl[1024];
    int b = blockIdx.z;
    for (int t = threadIdx.x; t < 1024; t += 256) vl[t] = maxp[b * 1024 + t];
    __syncthreads();
    int n = blockIdx.x * 256 + threadIdx.x;
    float acc[8];
#pragma unroll
    for (int e = 0; e < 8; ++e) acc[e] = 0.f;
    const float* p = feat + (long)b * 128 * NPTS + n;
    float v = p[0];
    for (int c = 0; c < 127; ++c) {
        float vn = p[(long)(c + 1) * NPTS];
#pragma unroll
        for (int e = 0; e < 8; ++e) acc[e] = fmaf(vl[c * 8 + e], v, acc[e]);
        v = vn;
    }
#pragma unroll
    for (int e = 0; e < 8; ++e) acc[e] = fmaf(vl[127 * 8 + e], v, acc[e]);
#pragma unroll
    for (int e = 0; e < 8; ++e)
        scores[((long)b * 8 + e) * NPTS + n] = 1.f / (1.f + expf(-acc[e]));
}

// ---------------- hierarchical exact sorted top-256 per (b,e) ----------------
__global__ __launch_bounds__(256) void k_sorta(const float* __restrict__ scores,
                                               unsigned int* __restrict__ kout,
                                               unsigned short* __restrict__ iout) {
    __shared__ unsigned int kv[1024];
    __shared__ unsigned short ki[1024];
    int ch = blockIdx.x & 7;
    const float* sp = scores + (long)(blockIdx.x >> 3) * NPTS + ch * 1024;
    for (int t = threadIdx.x; t < 1024; t += 256) {
        kv[t] = __float_as_uint(sp[t]) ^ 0xFFFFFFFFu;
        ki[t] = (unsigned short)(ch * 1024 + t);
    }
    __syncthreads();
    for (int k = 2; k <= 1024; k <<= 1) {
        for (int j = k >> 1; j > 0; j >>= 1) {
            for (int t = threadIdx.x; t < 1024; t += 256) {
                int ixj = t ^ j;
                if (ixj > t) {
                    unsigned int va = kv[t], vb = kv[ixj];
                    unsigned short ia = ki[t], ib = ki[ixj];
                    bool up = ((t & k) == 0);
                    bool gt = (va > vb) || (va == vb && ia > ib);
                    if (gt == up) { kv[t] = vb; kv[ixj] = va; ki[t] = ib; ki[ixj] = ia; }
                }
            }
            __syncthreads();
        }
    }
    if (threadIdx.x < 256) {
        kout[blockIdx.x * 256 + threadIdx.x] = kv[threadIdx.x];
        iout[blockIdx.x * 256 + threadIdx.x] = ki[threadIdx.x];
    }
}

__global__ __launch_bounds__(512) void k_sortb(const unsigned int* __restrict__ kin,
                                               const unsigned short* __restrict__ iin,
                                               float* __restrict__ topv,
                                               int* __restrict__ topi) {
    __shared__ unsigned int kv[2048];
    __shared__ unsigned short ki[2048];
    int be = blockIdx.x, b = be >> 3, e = be & 7;
    for (int t = threadIdx.x; t < 2048; t += 512) {
        kv[t] = kin[be * 2048 + t];
        ki[t] = iin[be * 2048 + t];
    }
    __syncthreads();
    for (int k = 2; k <= 2048; k <<= 1) {
        for (int j = k >> 1; j > 0; j >>= 1) {
            for (int t = threadIdx.x; t < 2048; t += 512) {
                int ixj = t ^ j;
                if (ixj > t) {
                    unsigned int va = kv[t], vb = kv[ixj];
                    unsigned short ia = ki[t], ib = ki[ixj];
                    bool up = ((t & k) == 0);
                    bool gt = (va > vb) || (va == vb && ia > ib);
                    if (gt == up) { kv[t] = vb; kv[ixj] = va; ki[t] = ib; ki[ixj] = ia; }
                }
            }
            __syncthreads();
        }
    }
    for (int r = threadIdx.x; r < 256; r += 512) {
        int j = r * 8 + e;  // torch-order reshape: values[b, r*8+e] = v[b,e,r]
        topv[b * 2048 + j] = __uint_as_float(kv[r] ^ 0xFFFFFFFFu);
        topi[b * 2048 + j] = (int)ki[r];
    }
}

// ---------------- pool gather: node, node_static (coords) ----------------
__global__ __launch_bounds__(256) void k_poolgather(const float* __restrict__ xyz,
                                                    const float* __restrict__ topv,
                                                    const int* __restrict__ topi,
                                                    float* __restrict__ node_ws,
                                                    float* __restrict__ out_node,
                                                    float* __restrict__ out_nstat) {
    int t = blockIdx.x * 256 + threadIdx.x;
    int j = t & 2047, b = t >> 11;
    int i = topi[b * 2048 + j];
    float v = topv[b * 2048 + j];
#pragma unroll
    for (int k = 0; k < 3; ++k) {
        float sx = xyz[((long)b * 3 + k) * NPTS + i];
        float nd = sx * v;
        out_nstat[((long)b * 3 + k) * MNODE + j] = sx;
        out_node[((long)b * 3 + k) * MNODE + j] = nd;
        node_ws[((long)b * 3 + k) * MNODE + j] = nd;
    }
}

// ---------------- nf1: h ch0-127 = feat gathered * values ----------------
__global__ __launch_bounds__(256) void k_nf1(const float* __restrict__ feat,
                                             const float* __restrict__ topv,
                                             const int* __restrict__ topi,
                                             float* __restrict__ h) {
    int t = blockIdx.x * 256 + threadIdx.x;
    int j = t & 2047, c = (t >> 11) & 127, b = t >> 18;
    int i = topi[b * 2048 + j];
    float v = topv[b * 2048 + j];
    h[((long)b * 256 + c) * MNODE + j] = feat[((long)b * 128 + c) * NPTS + i] * v;
}

// ---------------- knn20 (block-per-node): exact stable top-20 ----------------
__device__ __forceinline__ unsigned int fsortbits(float f) {
    unsigned int u = __float_as_uint(f);
    return u ^ ((unsigned int)((int)u >> 31) | 0x80000000u);
}

__global__ __launch_bounds__(256) void k_knn20(const float* __restrict__ xyz,
                                               const float* __restrict__ node,
                                               int* __restrict__ k20) {
    __shared__ unsigned int s1[256];
    __shared__ int s2[256];
    __shared__ int lcnt;
    int m = blockIdx.x & 2047, b = blockIdx.x >> 11;
    int t = threadIdx.x;
    float nx = node[((long)b * 3 + 0) * MNODE + m];
    float ny = node[((long)b * 3 + 1) * MNODE + m];
    float nz = node[((long)b * 3 + 2) * MNODE + m];
    float sm = nx * nx + ny * ny + nz * nz;
    const float* xb = xyz + (long)b * 3 * NPTS;
    unsigned int kmin = 0xFFFFFFFFu;
    for (int i = 0; i < 32; ++i) {
        int n = i * 256 + t;
        float px = xb[n], py = xb[NPTS + n], pz = xb[2 * NPTS + n];
        float d = (px * px + py * py + pz * pz) + sm - 2.f * (px * nx + py * ny + pz * nz);
        unsigned int key = fsortbits(d);
        kmin = key < kmin ? key : kmin;
    }
    s1[t] = kmin;
    if (t == 0) lcnt = 0;
    __syncthreads();
    for (int k = 2; k <= 256; k <<= 1) {
        for (int j = k >> 1; j > 0; j >>= 1) {
            int ixj = t ^ j;
            if (ixj > t) {
                unsigned int va = s1[t], vb = s1[ixj];
                bool up = ((t & k) == 0);
                if ((va > vb) == up) { s1[t] = vb; s1[ixj] = va; }
            }
            __syncthreads();
        }
    }
    unsigned int keyT = s1[19];
    __syncthreads();
    for (int i = 0; i < 32; ++i) {
        int n = i * 256 + t;
        float px = xb[n], py = xb[NPTS + n], pz = xb[2 * NPTS + n];
        float d = (px * px + py * py + pz * pz) + sm - 2.f * (px * nx + py * ny + pz * nz);
        unsigned int key = fsortbits(d);
        if (key <= keyT) {
            int p = atomicAdd(&lcnt, 1);
            if (p < 128) { s1[p] = key; s2[p] = n; }
        }
    }
    __syncthreads();
    int cnt = lcnt;
    if (cnt <= 128) {
        if (t >= cnt && t < 128) { s1[t] = 0xFFFFFFFFu; s2[t] = 0x7FFFFFFF; }
        __syncthreads();
        for (int k = 2; k <= 128; k <<= 1) {
            for (int j = k >> 1; j > 0; j >>= 1) {
                if (t < 128) {
                    int ixj = t ^ j;
                    if (ixj > t) {
                        unsigned int va = s1[t], vb = s1[ixj];
                        int ia = s2[t], ib = s2[ixj];
                        bool up = ((t & k) == 0);
                        bool gt = (va > vb) || (va == vb && ia > ib);
                        if (gt == up) { s1[t] = vb; s1[ixj] = va; s2[t] = ib; s2[ixj] = ia; }
                    }
                }
                __syncthreads();
            }
        }
        if (t < 20) k20[((long)b * 2048 + m) * 20 + t] = s2[t];
    } else {
        unsigned int lastk = 0u; int lasti = -1;
        for (int r = 0; r < 20; ++r) {
            unsigned int bk = 0xFFFFFFFFu; int bi = 0x7FFFFFFF;
            for (int i = 0; i < 32; ++i) {
                int n = i * 256 + t;
                float px = xb[n], py = xb[NPTS + n], pz = xb[2 * NPTS + n];
                float d = (px * px + py * py + pz * pz) + sm - 2.f * (px * nx + py * ny + pz * nz);
                unsigned int key = fsortbits(d);
                bool gtlast = (key > lastk) || (key == lastk && n > lasti);
                bool ltbest = (key < bk) || (key == bk && n < bi);
                if (gtlast && ltbest) { bk = key; bi = n; }
            }
            s1[t] = bk; s2[t] = bi;
            __syncthreads();
            for (int s = 128; s > 0; s >>= 1) {
                if (t < s) {
                    unsigned int vo = s1[t + s]; int io = s2[t + s];
                    unsigned int vm = s1[t]; int im = s2[t];
                    if (vo < vm || (vo == vm && io < im)) { s1[t] = vo; s2[t] = io; }
                }
                __syncthreads();
            }
            if (t == 0) k20[((long)b * 2048 + m) * 20 + r] = s2[0];
            lastk = s1[0]; lasti = s2[0];
            __syncthreads();
        }
    }
}

// ---------------- aggregate: h ch128-255 = max over 20 gathered feats ----------------
__global__ __launch_bounds__(256) void k_agg(const float* __restrict__ feat,
                                             const int* __restrict__ k20,
                                             float* __restrict__ h) {
    int t = blockIdx.x * 256 + threadIdx.x;
    int m = t & 2047, c = (t >> 11) & 127, b = t >> 18;
    const int* ip = k20 + ((long)b * 2048 + m) * 20;
    const float* fb = feat + ((long)b * 128 + c) * NPTS;
    float mx = -3.0e38f;
#pragma unroll
    for (int q = 0; q < 20; ++q) mx = fmaxf(mx, fb[ip[q] & 8191]);
    h[((long)b * 256 + 128 + c) * MNODE + m] = mx;
}

// ---------------- gemv: block per output o, all 4 batches; coalesced row read ----------------
__global__ __launch_bounds__(256) void k_gemv(const float* __restrict__ in, int C,
                                              const float* __restrict__ W, int wpitch,
                                              const float* __restrict__ lb,
                                              const float* __restrict__ sc,
                                              const float* __restrict__ bi, int do_relu,
                                              float* __restrict__ out, int O) {
    __shared__ float red[256];
    int o = blockIdx.x;
    int t = threadIdx.x;
    const float* wp = W + (long)o * wpitch;
    float a0 = 0.f, a1 = 0.f, a2 = 0.f, a3 = 0.f;
    for (int c = t * 4; c < C; c += 1024) {
        float4 w = *reinterpret_cast<const float4*>(wp + c);
        float4 v0 = *reinterpret_cast<const float4*>(in + 0L * C + c);
        float4 v1 = *reinterpret_cast<const float4*>(in + 1L * C + c);
        float4 v2 = *reinterpret_cast<const float4*>(in + 2L * C + c);
        float4 v3 = *reinterpret_cast<const float4*>(in + 3L * C + c);
        a0 += w.x * v0.x + w.y * v0.y + w.z * v0.z + w.w * v0.w;
        a1 += w.x * v1.x + w.y * v1.y + w.z * v1.z + w.w * v1.w;
        a2 += w.x * v2.x + w.y * v2.y + w.z * v2.z + w.w * v2.w;
        a3 += w.x * v3.x + w.y * v3.y + w.z * v3.z + w.w * v3.w;
    }
    float lbv = lb ? lb[o] : 0.f;
    float scv = sc ? sc[o] : 1.f;
    float biv = bi ? bi[o] : 0.f;
#pragma unroll
    for (int b = 0; b < 4; ++b) {
        float a = (b == 0) ? a0 : (b == 1) ? a1 : (b == 2) ? a2 : a3;
        __syncthreads();
        red[t] = a;
        __syncthreads();
        for (int s2 = 128; s2 > 0; s2 >>= 1) {
            if (t < s2) red[t] += red[t + s2];
            __syncthreads();
        }
        if (t == 0) {
            float r = (red[0] + lbv) * scv + biv;
            if (do_relu) r = fmaxf(r, 0.f);
            out[(long)b * O + o] = r;
        }
    }
}

// ---------------- unpool knn3 ----------------
__global__ __launch_bounds__(256) void k_knn3(const float* __restrict__ xyz,
                                              const float* __restrict__ node,
                                              int* __restrict__ k3i, float* __restrict__ k3w) {
    __shared__ float sx[2048], sy[2048], sz[2048], sn[2048];
    __shared__ float md[256][3];
    __shared__ int   mi[256][3];
    int b = blockIdx.x >> 8;
    int pbase = (blockIdx.x & 255) * 32;
    int t = threadIdx.x;
    const float* nb = node + (long)b * 3 * MNODE;
    for (int j = t; j < 2048; j += 256) {
        float qx = nb[j], qy = nb[MNODE + j], qz = nb[2 * MNODE + j];
        sx[j] = qx; sy[j] = qy; sz[j] = qz;
        sn[j] = qx * qx + qy * qy + qz * qz;
    }
    __syncthreads();
    int i = t & 31, q = t >> 5;
    int n = pbase + i;
    float px = xyz[((long)b * 3 + 0) * NPTS + n];
    float py = xyz[((long)b * 3 + 1) * NPTS + n];
    float pz = xyz[((long)b * 3 + 2) * NPTS + n];
    float sp = px * px + py * py + pz * pz;
    float d0 = 3.0e38f, d1 = 3.0e38f, d2 = 3.0e38f;
    int i0 = 0, i1 = 0, i2 = 0;
    int m0 = q * 256;
#pragma unroll 4
    for (int k = 0; k < 256; ++k) {
        int m = m0 + k;
        float d = (sp + sn[m]) - 2.f * (px * sx[m] + py * sy[m] + pz * sz[m]);
        if (d < d2) {
            d2 = d; i2 = m;
            if (d2 < d1) { float td = d1; d1 = d2; d2 = td; int ti = i1; i1 = i2; i2 = ti; }
            if (d1 < d0) { float td = d0; d0 = d1; d1 = td; int ti = i0; i0 = i1; i1 = ti; }
        }
    }
    md[t][0] = d0; md[t][1] = d1; md[t][2] = d2;
    mi[t][0] = i0; mi[t][1] = i1; mi[t][2] = i2;
    __syncthreads();
    if (t < 32) {
        int p0 = 0, p1 = 0, p2 = 0, p3 = 0, p4 = 0, p5 = 0, p6 = 0, p7 = 0;
        float rd[3]; int ri[3];
#pragma unroll
        for (int r = 0; r < 3; ++r) {
            float bestd = 3.0e38f; int besti = 0x7FFFFFFF; int bestq = -1;
#define KNN3_HEAD(QQ, PV)                                                              \
            {                                                                          \
                float dd = md[(QQ) * 32 + t][PV]; int ii = mi[(QQ) * 32 + t][PV];      \
                if (dd < bestd || (dd == bestd && ii < besti)) {                       \
                    bestd = dd; besti = ii; bestq = (QQ);                              \
                }                                                                      \
            }
            KNN3_HEAD(0, p0) KNN3_HEAD(1, p1) KNN3_HEAD(2, p2) KNN3_HEAD(3, p3)
            KNN3_HEAD(4, p4) KNN3_HEAD(5, p5) KNN3_HEAD(6, p6) KNN3_HEAD(7, p7)
#undef KNN3_HEAD
            rd[r] = bestd; ri[r] = besti;
            p0 += (bestq == 0); p1 += (bestq == 1); p2 += (bestq == 2); p3 += (bestq == 3);
            p4 += (bestq == 4); p5 += (bestq == 5); p6 += (bestq == 6); p7 += (bestq == 7);
        }
        float mxd = fmaxf(rd[0], fmaxf(rd[1], rd[2]));
        float e0 = expf(rd[0] - mxd), e1 = expf(rd[1] - mxd), e2 = expf(rd[2] - mxd);
        float inv = 1.f / (e0 + e1 + e2);
        long base = ((long)b * NPTS + pbase + t) * 3;
        k3i[base] = ri[0]; k3i[base + 1] = ri[1]; k3i[base + 2] = ri[2];
        k3w[base] = e0 * inv; k3w[base + 1] = e1 * inv; k3w[base + 2] = e2 * inv;
    }
}

__global__ __launch_bounds__(256) void k_unpool(const float* __restrict__ s7,
                                                const int* __restrict__ k3i,
                                                const float* __restrict__ k3w,
                                                float* __restrict__ sup) {
    int t = blockIdx.x * 256 + threadIdx.x;
    int n = t & 8191, c = (t >> 13) & 127, b = t >> 20;
    long base = ((long)b * NPTS + n) * 3;
    const float* spp = s7 + ((long)b * 128 + c) * MNODE;
    float a = k3w[base] * spp[k3i[base]] + k3w[base + 1] * spp[k3i[base + 1]] +
              k3w[base + 2] * spp[k3i[base + 2]];
    sup[((long)b * 128 + c) * NPTS + n] = a;
}

extern "C" void kernel_launch(void* const* d_in, const int* in_sizes, int n_in,
                              void* d_out, int out_size, void* d_ws, size_t ws_size,
                              hipStream_t stream) {
    const float* x     = (const float*)d_in[0];
    const float* c1w   = (const float*)d_in[1];
    const float* c2w   = (const float*)d_in[2];
    const float* c2mw  = (const float*)d_in[3];
    const float* c3w   = (const float*)d_in[4];
    const float* c4w   = (const float*)d_in[5];
    const float* c5w   = (const float*)d_in[6];
    const float* c6w   = (const float*)d_in[7];
    const float* c7w   = (const float*)d_in[8];
    const float* c8w   = (const float*)d_in[9];
    const float* c9w   = (const float*)d_in[10];
    const float* c10w  = (const float*)d_in[11];
    const float* bn1s  = (const float*)d_in[12]; const float* bn1b  = (const float*)d_in[13];
    const float* bn2s  = (const float*)d_in[14]; const float* bn2b  = (const float*)d_in[15];
    const float* bn2ms = (const float*)d_in[16]; const float* bn2mb = (const float*)d_in[17];
    const float* bn3s  = (const float*)d_in[18]; const float* bn3b  = (const float*)d_in[19];
    const float* bn4s  = (const float*)d_in[20]; const float* bn4b  = (const float*)d_in[21];
    const float* bn5s  = (const float*)d_in[22]; const float* bn5b  = (const float*)d_in[23];
    const float* bn6cs = (const float*)d_in[24]; const float* bn6cb = (const float*)d_in[25];
    const float* bn7cs = (const float*)d_in[26]; const float* bn7cb = (const float*)d_in[27];
    const float* bn8s  = (const float*)d_in[28]; const float* bn8b  = (const float*)d_in[29];
    const float* bn9s  = (const float*)d_in[30]; const float* bn9b  = (const float*)d_in[31];
    const float* bn6hs = (const float*)d_in[32]; const float* bn6hb = (const float*)d_in[33];
    const float* bn7hs = (const float*)d_in[34]; const float* bn7hb = (const float*)d_in[35];
    const float* poolw = (const float*)d_in[36]; const float* poolb = (const float*)d_in[37];
    const float* l1w   = (const float*)d_in[38];
    const float* l2w   = (const float*)d_in[39]; const float* l2b   = (const float*)d_in[40];
    const float* l3w   = (const float*)d_in[41]; const float* l3b   = (const float*)d_in[42];

    float* ws   = (float*)d_ws;
    float* xt1  = ws + WS_XT1;
    float* x34  = ws + WS_A;
    float* scor = ws + WS_B;
    float* s8   = ws + WS_B;
    float* hbuf = ws + WS_C;
    float* s6   = ws + WS_C;
    float* s7   = ws + WS_C + 1048576L;
    float* sup  = ws + WS_D;
    float* s9   = ws + WS_D;
    float* topv = ws + WS_TOPV;
    int*   topi = (int*)(ws + WS_TOPI);
    float* node = ws + WS_NODE;
    float* maxp = ws + WS_MAXP;
    float* vec  = ws + WS_VEC;
    float* c1b  = ws + WS_C1;
    float* c2b_ = ws + WS_C2;
    float* b6   = ws + WS_B6;
    int*   k20  = (int*)(ws + WS_K20);
    float* pmax1 = ws + WS_K20;              // 32*4*1024 = 131072 floats
    float* pmax2 = ws + WS_K20 + 131072;     // + 32768 -> total 163840 = k20 size
    int*   k3i  = (int*)(ws + WS_K3I);
    float* k3w  = ws + WS_K3W;
    unsigned int*   sskeys = (unsigned int*)(ws + WS_A);
    unsigned short* ssidx  = (unsigned short*)(ws + WS_A + 65536);
    // bf16 staging (lifetime-aliased):
    u16* xtb   = (u16*)(ws + WS_C);                 // [4][8192][128] bf16
    u16* c2mwb = (u16*)(ws + WS_D);                 // [1024][128] bf16
    u16* x34b  = (u16*)(ws + WS_B);                 // [4][2048][512] bf16
    u16* c5wb  = (u16*)(ws + WS_B + 2097152);       // [1024][512] bf16

    float* out       = (float*)d_out;
    float* out_cls   = out;
    float* out_seg   = out + 60;
    float* out_node  = out + 60 + 65536;
    float* out_nstat = out_node + 24576;

    // x1 -> xt1_ ch0-63; x2 via k_conv (LDS weights + float4 loads)
    k_conv1<<<dim3(8192), dim3(256), 0, stream>>>(x, c1w, bn1s, bn1b, xt1);
    k_conv<<<dim3(8, 8, 4), dim3(256), 0, stream>>>(xt1, 64, 128L * NPTS, nullptr, 0, 0,
                                                    c2w, 64, nullptr, bn2s, bn2b, 1,
                                                    xt1 + 64L * NPTS, 128L * NPTS, 64, NPTS);
    // conv2m via bf16-MFMA
    k_packT<<<dim3(256, 4, 4), dim3(256), 0, stream>>>(xt1, 128, NPTS, xtb);
    k_packw<<<dim3(512), dim3(256), 0, stream>>>(c2mw, 128, 128, 1024, c2mwb);
    k_cvmx_bf<<<dim3(32, 16, 4), dim3(256), 0, stream>>>(xtb, c2mwb, 128,
                                                         bn2ms, bn2mb, 1, pmax1, 1024, NPTS);
    // pool-proj stays fp32 (top-k rank-sensitive)
    k_convmax<<<dim3(8, 64, 4), dim3(256), 16 * 257 * 4, stream>>>(
        xt1, 128, 128L * NPTS,
        poolw, poolb, nullptr, nullptr, 0, pmax2,
        nullptr, nullptr, nullptr, nullptr, 0, nullptr,
        128, 1024, NPTS);
    k_maxred2<<<dim3(32), dim3(256), 0, stream>>>(pmax1, 32, 1024, vec, 2048,
                                                  pmax2, 8, 1024, maxp, 1024, 16);
    // scores (128 blocks, bit-identical summation)
    k_scores<<<dim3(32, 1, 4), dim3(256), 0, stream>>>(xt1, maxp, scor);
    // exact top-256 per (b,e)
    k_sorta<<<dim3(256), dim3(256), 0, stream>>>(scor, sskeys, ssidx);
    k_sortb<<<dim3(32), dim3(512), 0, stream>>>(sskeys, ssidx, topv, topi);
    // node / node_static / nf1
    k_poolgather<<<dim3(32), dim3(256), 0, stream>>>(x, topv, topi, node, out_node, out_nstat);
    k_nf1<<<dim3(4096), dim3(256), 0, stream>>>(xt1, topv, topi, hbuf);
    // aggregate
    k_knn20<<<dim3(8192), dim3(256), 0, stream>>>(x, node, k20);
    k_agg<<<dim3(4096), dim3(256), 0, stream>>>(xt1, k20, hbuf);
    // conv3 / conv4 -> x34
    k_conv<<<dim3(2, 32, 4), dim3(256), 0, stream>>>(hbuf, 256, 256L * MNODE, nullptr, 0, 0,
                                                     c3w, 256, nullptr, bn3s, bn3b, 1,
                                                     x34, 512L * MNODE, 256, MNODE);
    k_conv<<<dim3(2, 32, 4), dim3(256), 0, stream>>>(x34, 256, 512L * MNODE, nullptr, 0, 0,
                                                     c4w, 256, nullptr, bn4s, bn4b, 1,
                                                     x34 + 256L * MNODE, 512L * MNODE, 256, MNODE);
    // conv5 via bf16-MFMA
    k_packT<<<dim3(64, 16, 4), dim3(256), 0, stream>>>(x34, 512, MNODE, x34b);
    k_packw<<<dim3(2048), dim3(256), 0, stream>>>(c5w, 512, 512, 1024, c5wb);
    k_cvmx_bf<<<dim3(8, 16, 4), dim3(256), 0, stream>>>(x34b, c5wb, 512,
                                                        bn5s, bn5b, 1, pmax1, 1024, MNODE);
    k_maxred<<<dim3(16), dim3(256), 0, stream>>>(pmax1, 8, 1024, vec + 1024, 2048);
    // classification head
    k_gemv<<<dim3(512), dim3(256), 0, stream>>>(vec, 2048, l1w, 2048, nullptr, bn6hs, bn6hb, 1, c1b, 512);
    k_gemv<<<dim3(256), dim3(256), 0, stream>>>(c1b, 512, l2w, 512, l2b, bn7hs, bn7hb, 1, c2b_, 256);
    k_gemv<<<dim3(15), dim3(256), 0, stream>>>(c2b_, 256, l3w, 256, l3b, nullptr, nullptr, 0, out_cls, 15);
    // conv6 / conv7
    k_gemv<<<dim3(128), dim3(256), 0, stream>>>(vec, 2048, c6w, 2304, nullptr, nullptr, nullptr, 0, b6, 128);
    k_conv<<<dim3(2, 16, 4), dim3(256), 0, stream>>>(x34 + 256L * MNODE, 256, 512L * MNODE,
                                                     nullptr, 0, 0, c6w + 2048, 2304, b6,
                                                     bn6cs, bn6cb, 1, s6, 128L * MNODE, 128, MNODE);
    k_conv<<<dim3(2, 16, 4), dim3(256), 0, stream>>>(s6, 128, 128L * MNODE, x34, 256, 512L * MNODE,
                                                     c7w, 384, nullptr, bn7cs, bn7cb, 1,
                                                     s7, 128L * MNODE, 128, MNODE);
    // unpool
    k_knn3<<<dim3(1024), dim3(256), 0, stream>>>(x, node, k3i, k3w);
    k_unpool<<<dim3(16384), dim3(256), 0, stream>>>(s7, k3i, k3w, sup);
    // conv8 / conv9 / conv10
    k_conv<<<dim3(8, 16, 4), dim3(256), 0, stream>>>(sup, 128, 128L * NPTS, xt1 + 64L * NPTS, 64,
                                                     128L * NPTS, c8w, 192, nullptr, bn8s, bn8b, 1,
                                                     s8, 128L * NPTS, 128, NPTS);
    k_conv<<<dim3(8, 16, 4), dim3(256), 0, stream>>>(s8, 128, 128L * NPTS, xt1, 64, 128L * NPTS,
                                                     c9w, 192, nullptr, bn9s, bn9b, 1,
                                                     s9, 128L * NPTS, 128, NPTS);
    k_conv<<<dim3(8, 1, 4), dim3(256), 0, stream>>>(s9, 128, 128L * NPTS, nullptr, 0, 0,
                                                    c10w, 128, nullptr, nullptr, nullptr, 0,
                                                    out_seg, 2L * NPTS, 2, NPTS);
    (void)in_sizes; (void)n_in; (void)out_size; (void)ws_size;
}

// Round 17
// 885.491 us; speedup vs baseline: 6.6491x; 1.0400x over previous
//
#include <hip/hip_runtime.h>
#include <math.h>

typedef unsigned short u16;
typedef short bf8 __attribute__((ext_vector_type(8)));   // 8 bf16 (4 VGPRs)
typedef float f4 __attribute__((ext_vector_type(4)));    // 4 fp32

// Problem constants
#define NPTS 8192
#define MNODE 2048

// ---------------- ws layout (float element offsets) ----------------
#define WS_XT1  0L          // xt1_ [4][128][8192] — live whole pass
#define WS_A    4194304L    // sort scratch EARLY; x34 [4][512][2048] mid; s8 LATE (x34 dead)
#define WS_B    8388608L    // scores early; x34b+c5wb mid; sp8/sp9+c8wb/c9wb late
#define WS_C    12582912L   // xtb early; h [4][256][2048]; s6/s7 later
#define WS_D    14680064L   // c2mwb early; hb/x3p/c3wb/c4wb mid; sup then s9 late
#define WS_TOPV 18874368L
#define WS_TOPI 18882560L
#define WS_NODE 18890752L
#define WS_MAXP 18915328L
#define WS_VEC  18919424L
#define WS_C1   18927616L
#define WS_C2   18929664L
#define WS_B6   18930688L
#define WS_K20  18931200L   // int [4][2048][20]; ALSO pmax scratch (disjoint lifetime)
#define WS_K3I  19095040L
#define WS_K3W  19193344L
// end = 19291648 floats = 73.6 MB

__device__ __forceinline__ u16 bf16rne(float f) {
    unsigned u = __float_as_uint(f);
    unsigned r = u + 0x7FFFu + ((u >> 16) & 1u);
    return (u16)(r >> 16);
}

// ---------------- conv1: x[4,3,8192] -> xt1_ ch0-63 ----------------
__global__ __launch_bounds__(256) void k_conv1(const float* __restrict__ x,
                                               const float* __restrict__ W,
                                               const float* __restrict__ sc,
                                               const float* __restrict__ bi,
                                               float* __restrict__ out) {
    int t = blockIdx.x * 256 + threadIdx.x;
    int n = t & 8191, o = (t >> 13) & 63, b = t >> 19;
    const float* xb = x + (long)b * 3 * NPTS;
    float a = W[o * 3 + 0] * xb[n] + W[o * 3 + 1] * xb[NPTS + n] + W[o * 3 + 2] * xb[2 * NPTS + n];
    a = fmaxf(a * sc[o] + bi[o], 0.f);
    out[((long)b * 128 + o) * NPTS + n] = a;
}

// ---------------- bf16 packing ----------------
// MFMA 16x16x32 bf16 A/B frag k-layout: element j of lane l covers
// k = (l>>4)*4 + (j&3) + 16*(j>>2). Pre-permute k inside each 32-block so a
// lane's 8 frag elements are 8 CONTIGUOUS packed entries at offset (l>>4)*8.

// weights: W f32 [O][wpitch] -> out bf16 [O][C] (k-permuted)
__global__ __launch_bounds__(256) void k_packw(const float* __restrict__ W, int wpitch,
                                               int C, int O, u16* __restrict__ out) {
    int t = blockIdx.x * 256 + threadIdx.x;
    if (t >= O * C) return;
    int o = t / C, p = t - o * C;
    int blk = p >> 5, pj = p & 31;
    int g = pj >> 3, j = pj & 7;
    int k = (blk << 5) + g * 4 + (j & 3) + 16 * (j >> 2);
    out[t] = bf16rne(W[(long)o * wpitch + k]);
}

// input: in f32 (batch stride ibs, row stride Nn) C channels -> out bf16 [B][Nn][opitch]
// at column offset coff (transpose + k-permute), LDS-tiled. C, coff multiples of 32.
__global__ __launch_bounds__(256) void k_packT2(const float* __restrict__ in, long ibs,
                                                int C, int Nn, u16* __restrict__ out,
                                                int opitch, int coff) {
    __shared__ float tile[32][33];
    int b = blockIdx.z;
    int k0 = blockIdx.y * 32, n0 = blockIdx.x * 32;
    int tx = threadIdx.x & 31, ty = threadIdx.x >> 5;   // 32 x 8
    for (int r = 0; r < 32; r += 8)
        tile[ty + r][tx] = in[(long)b * ibs + (long)(k0 + ty + r) * Nn + n0 + tx];
    __syncthreads();
    for (int r = 0; r < 32; r += 8) {
        int n = n0 + ty + r;
        int p = tx;
        int g = p >> 3, j = p & 7;
        int kin = g * 4 + (j & 3) + 16 * (j >> 2);
        out[((long)b * Nn + n) * opitch + coff + k0 + p] = bf16rne(tile[kin][ty + r]);
    }
}

// ---------------- bf16-MFMA conv + bn/relu + partial max over n ----------------
__global__ __launch_bounds__(256) void k_cvmx_bf(const u16* __restrict__ in,
                                                 const u16* __restrict__ wpk, int C,
                                                 const float* __restrict__ sc,
                                                 const float* __restrict__ bi, int do_relu,
                                                 float* __restrict__ pmax, int O, int Nn) {
    __shared__ float red[4][16][17];
    int b = blockIdx.z, nc = blockIdx.x;
    int lane = threadIdx.x & 63, w = threadIdx.x >> 6;
    int o0 = (blockIdx.y * 4 + w) * 16;
    const u16* wp = wpk + (long)(o0 + (lane & 15)) * C + ((lane >> 4) << 3);
    const u16* ip = in + ((long)b * Nn + nc * 256 + (lane & 15)) * C + ((lane >> 4) << 3);
    long nstride = 16L * C;
    f4 acc[16];
#pragma unroll
    for (int t = 0; t < 16; ++t) acc[t] = (f4)(0.f);
    for (int kk = 0; kk < C; kk += 32) {
        bf8 a = *(const bf8*)(wp + kk);
#pragma unroll
        for (int t = 0; t < 16; ++t) {
            bf8 bb = *(const bf8*)(ip + t * nstride + kk);
            acc[t] = __builtin_amdgcn_mfma_f32_16x16x32_bf16(a, bb, acc[t], 0, 0, 0);
        }
    }
#pragma unroll
    for (int j = 0; j < 4; ++j) {
        int ol = (lane >> 4) * 4 + j;
        int o = o0 + ol;
        float scv = sc ? sc[o] : 1.f;
        float biv = bi ? bi[o] : 0.f;
        float mm = -3.0e38f;
#pragma unroll
        for (int t = 0; t < 16; ++t) {
            float v = acc[t][j] * scv + biv;
            if (do_relu) v = fmaxf(v, 0.f);
            mm = fmaxf(mm, v);
        }
        red[w][ol][lane & 15] = mm;
    }
    __syncthreads();
    if (threadIdx.x < 64) {
        int ww = threadIdx.x >> 4, oo = threadIdx.x & 15;
        float mm = red[ww][oo][0];
#pragma unroll
        for (int i = 1; i < 16; ++i) mm = fmaxf(mm, red[ww][oo][i]);
        int og = (blockIdx.y * 4 + ww) * 16 + oo;
        pmax[((long)nc * 4 + b) * O + og] = mm;
    }
}

// ---------------- bf16-MFMA conv + bn/relu, FULL output [B][O][Nn] ----------------
// Same frag structure as k_cvmx_bf (validated R15); writes instead of max-reduce.
__global__ __launch_bounds__(256) void k_conv_bf(const u16* __restrict__ in,
                                                 int C,   // packed pitch
                                                 const u16* __restrict__ wpk,
                                                 const float* __restrict__ sc,
                                                 const float* __restrict__ bi, int do_relu,
                                                 float* __restrict__ out, long obs, int Nn) {
    int b = blockIdx.z, nc = blockIdx.x;
    int lane = threadIdx.x & 63, w = threadIdx.x >> 6;
    int o0 = (blockIdx.y * 4 + w) * 16;
    const u16* wp = wpk + (long)(o0 + (lane & 15)) * C + ((lane >> 4) << 3);
    const u16* ip = in + ((long)b * Nn + nc * 256 + (lane & 15)) * C + ((lane >> 4) << 3);
    long nstride = 16L * C;
    f4 acc[16];
#pragma unroll
    for (int t = 0; t < 16; ++t) acc[t] = (f4)(0.f);
    for (int kk = 0; kk < C; kk += 32) {
        bf8 a = *(const bf8*)(wp + kk);
#pragma unroll
        for (int t = 0; t < 16; ++t) {
            bf8 bb = *(const bf8*)(ip + t * nstride + kk);
            acc[t] = __builtin_amdgcn_mfma_f32_16x16x32_bf16(a, bb, acc[t], 0, 0, 0);
        }
    }
#pragma unroll
    for (int j = 0; j < 4; ++j) {
        int o = o0 + (lane >> 4) * 4 + j;
        float scv = sc ? sc[o] : 1.f;
        float biv = bi ? bi[o] : 0.f;
        float* op = out + (long)b * obs + (long)o * Nn + nc * 256 + (lane & 15);
#pragma unroll
        for (int t = 0; t < 16; ++t) {
            float v = acc[t][j] * scv + biv;
            if (do_relu) v = fmaxf(v, 0.f);
            op[t * 16] = v;
        }
    }
}

// 16-output-tile FMA block (fp32 path)
#define CMAX_FMA16()                                                        \
    {                                                                       \
        const float4* wp4 = reinterpret_cast<const float4*>(Wl + c16);      \
        _Pragma("unroll")                                                   \
        for (int g = 0; g < 4; ++g) {                                       \
            float4 w = wp4[g];                                              \
            acc[4 * g + 0].x = fmaf(w.x, v.x, acc[4 * g + 0].x);            \
            acc[4 * g + 0].y = fmaf(w.x, v.y, acc[4 * g + 0].y);            \
            acc[4 * g + 0].z = fmaf(w.x, v.z, acc[4 * g + 0].z);            \
            acc[4 * g + 0].w = fmaf(w.x, v.w, acc[4 * g + 0].w);            \
            acc[4 * g + 1].x = fmaf(w.y, v.x, acc[4 * g + 1].x);            \
            acc[4 * g + 1].y = fmaf(w.y, v.y, acc[4 * g + 1].y);            \
            acc[4 * g + 1].z = fmaf(w.y, v.z, acc[4 * g + 1].z);            \
            acc[4 * g + 1].w = fmaf(w.y, v.w, acc[4 * g + 1].w);            \
            acc[4 * g + 2].x = fmaf(w.z, v.x, acc[4 * g + 2].x);            \
            acc[4 * g + 2].y = fmaf(w.z, v.y, acc[4 * g + 2].y);            \
            acc[4 * g + 2].z = fmaf(w.z, v.z, acc[4 * g + 2].z);            \
            acc[4 * g + 2].w = fmaf(w.z, v.w, acc[4 * g + 2].w);            \
            acc[4 * g + 3].x = fmaf(w.w, v.x, acc[4 * g + 3].x);            \
            acc[4 * g + 3].y = fmaf(w.w, v.y, acc[4 * g + 3].y);            \
            acc[4 * g + 3].z = fmaf(w.w, v.z, acc[4 * g + 3].z);            \
            acc[4 * g + 3].w = fmaf(w.w, v.w, acc[4 * g + 3].w);            \
        }                                                                   \
    }

// ---------------- fp32 convmax (pool-proj only; rank-sensitive path) ----------------
// NOTE: no min-waves bound (R13: (256,8) forced VGPR 52->32 spill, 5.9x slowdown).
__global__ __launch_bounds__(256) void k_convmax(
        const float* __restrict__ in, int C, long ibs,
        const float* __restrict__ W1, const float* __restrict__ cb1,
        const float* __restrict__ sc1, const float* __restrict__ bi1, int relu1,
        float* __restrict__ pmax1,
        const float* __restrict__ W2, const float* __restrict__ cb2,
        const float* __restrict__ sc2, const float* __restrict__ bi2, int relu2,
        float* __restrict__ pmax2,
        int wpitch, int O, int Nn) {
    extern __shared__ float sm_[];
    float* Wl = sm_;              // [C][16]
    float* red = sm_;             // [16][257] — aliases Wl (disjoint lifetime)
    int b = blockIdx.z;
    int ns = blockIdx.x;
    int oblocks = O >> 4;
    int setid = (int)blockIdx.y / oblocks;
    int og0 = ((int)blockIdx.y - setid * oblocks) * 16;
    const float* W  = setid ? W2 : W1;
    const float* cb = setid ? cb2 : cb1;
    const float* sc = setid ? sc2 : sc1;
    const float* bi = setid ? bi2 : bi1;
    int do_relu     = setid ? relu2 : relu1;
    float* pmax     = setid ? pmax2 : pmax1;
    for (int t = threadIdx.x; t < 16 * C; t += 256) {
        int c = t >> 4, o = t & 15;
        Wl[t] = W[(long)(og0 + o) * wpitch + c];
    }
    __syncthreads();
    int n0 = ns * 1024 + threadIdx.x * 4;
    float4 acc[16];
#pragma unroll
    for (int o = 0; o < 16; ++o) acc[o] = make_float4(0.f, 0.f, 0.f, 0.f);
    const float* p = in + (long)b * ibs + n0;
    float4 v = *reinterpret_cast<const float4*>(p);
    for (int c = 0; c < C - 1; ++c) {
        float4 vn = *reinterpret_cast<const float4*>(p + (long)(c + 1) * Nn);
        int c16 = c * 16;
        CMAX_FMA16();
        v = vn;
    }
    {
        int c16 = (C - 1) * 16;
        CMAX_FMA16();
    }
    float h2[16];
#pragma unroll
    for (int o = 0; o < 16; ++o) {
        float cbv = cb ? cb[og0 + o] : 0.f;
        float scv = sc ? sc[og0 + o] : 1.f;
        float biv = bi ? bi[og0 + o] : 0.f;
        float4 a = acc[o];
        float vx = (a.x + cbv) * scv + biv;
        float vy = (a.y + cbv) * scv + biv;
        float vz = (a.z + cbv) * scv + biv;
        float vw = (a.w + cbv) * scv + biv;
        if (do_relu) {
            vx = fmaxf(vx, 0.f); vy = fmaxf(vy, 0.f);
            vz = fmaxf(vz, 0.f); vw = fmaxf(vw, 0.f);
        }
        h2[o] = fmaxf(fmaxf(vx, vy), fmaxf(vz, vw));
    }
    __syncthreads();
#pragma unroll
    for (int o = 0; o < 16; ++o) red[o * 257 + threadIdx.x] = h2[o];
    __syncthreads();
    for (int ls = 7; ls >= 0; --ls) {
        int s = 1 << ls;
        for (int w = threadIdx.x; w < 16 * s; w += 256) {
            int o = w >> ls, i = w & (s - 1);
            float* r = red + o * 257;
            r[i] = fmaxf(r[i], r[i + s]);
        }
        __syncthreads();
    }
    if (threadIdx.x < 16)
        pmax[((long)ns * 4 + b) * O + og0 + threadIdx.x] = red[threadIdx.x * 257];
}

// finalize: out[b*obs + o] = max over nsplit partials. Dual-set variant.
__global__ __launch_bounds__(256) void k_maxred2(const float* __restrict__ pA, int nsA, int OA,
                                                 float* __restrict__ outA, long obsA,
                                                 const float* __restrict__ pB, int nsB, int OB,
                                                 float* __restrict__ outB, long obsB,
                                                 int blocksA) {
    const float* pm; int ns, O; float* out; long obs; int bid = blockIdx.x;
    if (bid < blocksA) { pm = pA; ns = nsA; O = OA; out = outA; obs = obsA; }
    else { pm = pB; ns = nsB; O = OB; out = outB; obs = obsB; bid -= blocksA; }
    int t = bid * 256 + threadIdx.x;
    if (t >= 4 * O) return;
    int o = t % O, b = t / O;
    float m = -3.0e38f;
    for (int s = 0; s < ns; ++s) m = fmaxf(m, pm[((long)s * 4 + b) * O + o]);
    out[(long)b * obs + o] = m;
}

__global__ __launch_bounds__(256) void k_maxred(const float* __restrict__ pmax, int nsplit,
                                                int O, float* __restrict__ out, long obs) {
    int t = blockIdx.x * 256 + threadIdx.x;
    if (t >= 4 * O) return;
    int o = t % O, b = t / O;
    float m = -3.0e38f;
    for (int s = 0; s < nsplit; ++s) m = fmaxf(m, pmax[((long)s * 4 + b) * O + o]);
    out[(long)b * obs + o] = m;
}

// ---------------- generic fp32 conv(+extra)(+bn)(+relu), up to 2 concat inputs ----------------
#define CONV_FMA8()                                                         \
    {                                                                       \
        const float4* wp4 = reinterpret_cast<const float4*>(Wl + c8);       \
        _Pragma("unroll")                                                   \
        for (int g = 0; g < 2; ++g) {                                       \
            float4 w = wp4[g];                                              \
            acc[4 * g + 0].x = fmaf(w.x, v.x, acc[4 * g + 0].x);            \
            acc[4 * g + 0].y = fmaf(w.x, v.y, acc[4 * g + 0].y);            \
            acc[4 * g + 0].z = fmaf(w.x, v.z, acc[4 * g + 0].z);            \
            acc[4 * g + 0].w = fmaf(w.x, v.w, acc[4 * g + 0].w);            \
            acc[4 * g + 1].x = fmaf(w.y, v.x, acc[4 * g + 1].x);            \
            acc[4 * g + 1].y = fmaf(w.y, v.y, acc[4 * g + 1].y);            \
            acc[4 * g + 1].z = fmaf(w.y, v.z, acc[4 * g + 1].z);            \
            acc[4 * g + 1].w = fmaf(w.y, v.w, acc[4 * g + 1].w);            \
            acc[4 * g + 2].x = fmaf(w.z, v.x, acc[4 * g + 2].x);            \
            acc[4 * g + 2].y = fmaf(w.z, v.y, acc[4 * g + 2].y);            \
            acc[4 * g + 2].z = fmaf(w.z, v.z, acc[4 * g + 2].z);            \
            acc[4 * g + 2].w = fmaf(w.z, v.w, acc[4 * g + 2].w);            \
            acc[4 * g + 3].x = fmaf(w.w, v.x, acc[4 * g + 3].x);            \
            acc[4 * g + 3].y = fmaf(w.w, v.y, acc[4 * g + 3].y);            \
            acc[4 * g + 3].z = fmaf(w.w, v.z, acc[4 * g + 3].z);            \
            acc[4 * g + 3].w = fmaf(w.w, v.w, acc[4 * g + 3].w);            \
        }                                                                   \
    }

__global__ __launch_bounds__(256) void k_conv(const float* __restrict__ in1, int C1, long ibs1,
                                              const float* __restrict__ in2, int C2, long ibs2,
                                              const float* __restrict__ W, int wpitch,
                                              const float* __restrict__ extra,
                                              const float* __restrict__ sc,
                                              const float* __restrict__ bi, int do_relu,
                                              float* __restrict__ out, long obs, int O, int Nn) {
    __shared__ float Wl[384 * 8];
    int b = blockIdx.z;
    int og0 = blockIdx.y * 8;
    int on = O - og0; if (on > 8) on = 8;
    int Ct = C1 + C2;
    for (int t = threadIdx.x; t < Ct * 8; t += 256) {
        int c = t >> 3, o = t & 7;
        Wl[t] = (o < on) ? W[(long)(og0 + o) * wpitch + c] : 0.f;
    }
    __syncthreads();
    int n0 = blockIdx.x * 1024 + threadIdx.x * 4;
    float4 acc[8];
#pragma unroll
    for (int o = 0; o < 8; ++o) acc[o] = make_float4(0.f, 0.f, 0.f, 0.f);
    const float* p1 = in1 + (long)b * ibs1 + n0;
    {
        float4 v = *reinterpret_cast<const float4*>(p1);
        for (int c = 0; c < C1 - 1; ++c) {
            float4 vn = *reinterpret_cast<const float4*>(p1 + (long)(c + 1) * Nn);
            int c8 = c * 8;
            CONV_FMA8();
            v = vn;
        }
        int c8 = (C1 - 1) * 8;
        CONV_FMA8();
    }
    if (in2) {
        const float* p2 = in2 + (long)b * ibs2 + n0;
        float4 v = *reinterpret_cast<const float4*>(p2);
        for (int c = 0; c < C2 - 1; ++c) {
            float4 vn = *reinterpret_cast<const float4*>(p2 + (long)(c + 1) * Nn);
            int c8 = (C1 + c) * 8;
            CONV_FMA8();
            v = vn;
        }
        int c8 = (Ct - 1) * 8;
        CONV_FMA8();
    }
#pragma unroll
    for (int o = 0; o < 8; ++o) {
        if (o < on) {
            float e = extra ? extra[(long)b * O + og0 + o] : 0.f;
            float s = sc ? sc[og0 + o] : 1.f;
            float bv = bi ? bi[og0 + o] : 0.f;
            float4 a = acc[o];
            a.x = (a.x + e) * s + bv;
            a.y = (a.y + e) * s + bv;
            a.z = (a.z + e) * s + bv;
            a.w = (a.w + e) * s + bv;
            if (do_relu) {
                a.x = fmaxf(a.x, 0.f); a.y = fmaxf(a.y, 0.f);
                a.z = fmaxf(a.z, 0.f); a.w = fmaxf(a.w, 0.f);
            }
            *reinterpret_cast<float4*>(out + (long)b * obs + (long)(og0 + o) * Nn + n0) = a;
        }
    }
}

// ---------------- scores: one n per thread, all 8 e; grid (32,1,4)=128 blocks ----------------
__global__ __launch_bounds__(256) void k_scores(const float* __restrict__ feat,
                                                const float* __restrict__ maxp,
                                                float* __restrict__ scores) {
    __shared__ float vl[1024];
    int b = blockIdx.z;
    for (int t = threadIdx.x; t < 1024; t += 256) vl[t] = maxp[b * 1024 + t];
    __syncthreads();
    int n = blockIdx.x * 256 + threadIdx.x;
    float acc[8];
#pragma unroll
    for (int e = 0; e < 8; ++e) acc[e] = 0.f;
    const float* p = feat + (long)b * 128 * NPTS + n;
    float v = p[0];
    for (int c = 0; c < 127; ++c) {
        float vn = p[(long)(c + 1) * NPTS];
#pragma unroll
        for (int e = 0; e < 8; ++e) acc[e] = fmaf(vl[c * 8 + e], v, acc[e]);
        v = vn;
    }
#pragma unroll
    for (int e = 0; e < 8; ++e) acc[e] = fmaf(vl[127 * 8 + e], v, acc[e]);
#pragma unroll
    for (int e = 0; e < 8; ++e)
        scores[((long)b * 8 + e) * NPTS + n] = 1.f / (1.f + expf(-acc[e]));
}

// ---------------- hierarchical exact sorted top-256 per (b,e) ----------------
__global__ __launch_bounds__(256) void k_sorta(const float* __restrict__ scores,
                                               unsigned int* __restrict__ kout,
                                               unsigned short* __restrict__ iout) {
    __shared__ unsigned int kv[1024];
    __shared__ unsigned short ki[1024];
    int ch = blockIdx.x & 7;
    const float* sp = scores + (long)(blockIdx.x >> 3) * NPTS + ch * 1024;
    for (int t = threadIdx.x; t < 1024; t += 256) {
        kv[t] = __float_as_uint(sp[t]) ^ 0xFFFFFFFFu;
        ki[t] = (unsigned short)(ch * 1024 + t);
    }
    __syncthreads();
    for (int k = 2; k <= 1024; k <<= 1) {
        for (int j = k >> 1; j > 0; j >>= 1) {
            for (int t = threadIdx.x; t < 1024; t += 256) {
                int ixj = t ^ j;
                if (ixj > t) {
                    unsigned int va = kv[t], vb = kv[ixj];
                    unsigned short ia = ki[t], ib = ki[ixj];
                    bool up = ((t & k) == 0);
                    bool gt = (va > vb) || (va == vb && ia > ib);
                    if (gt == up) { kv[t] = vb; kv[ixj] = va; ki[t] = ib; ki[ixj] = ia; }
                }
            }
            __syncthreads();
        }
    }
    if (threadIdx.x < 256) {
        kout[blockIdx.x * 256 + threadIdx.x] = kv[threadIdx.x];
        iout[blockIdx.x * 256 + threadIdx.x] = ki[threadIdx.x];
    }
}

__global__ __launch_bounds__(512) void k_sortb(const unsigned int* __restrict__ kin,
                                               const unsigned short* __restrict__ iin,
                                               float* __restrict__ topv,
                                               int* __restrict__ topi) {
    __shared__ unsigned int kv[2048];
    __shared__ unsigned short ki[2048];
    int be = blockIdx.x, b = be >> 3, e = be & 7;
    for (int t = threadIdx.x; t < 2048; t += 512) {
        kv[t] = kin[be * 2048 + t];
        ki[t] = iin[be * 2048 + t];
    }
    __syncthreads();
    for (int k = 2; k <= 2048; k <<= 1) {
        for (int j = k >> 1; j > 0; j >>= 1) {
            for (int t = threadIdx.x; t < 2048; t += 512) {
                int ixj = t ^ j;
                if (ixj > t) {
                    unsigned int va = kv[t], vb = kv[ixj];
                    unsigned short ia = ki[t], ib = ki[ixj];
                    bool up = ((t & k) == 0);
                    bool gt = (va > vb) || (va == vb && ia > ib);
                    if (gt == up) { kv[t] = vb; kv[ixj] = va; ki[t] = ib; ki[ixj] = ia; }
                }
            }
            __syncthreads();
        }
    }
    for (int r = threadIdx.x; r < 256; r += 512) {
        int j = r * 8 + e;  // torch-order reshape: values[b, r*8+e] = v[b,e,r]
        topv[b * 2048 + j] = __uint_as_float(kv[r] ^ 0xFFFFFFFFu);
        topi[b * 2048 + j] = (int)ki[r];
    }
}

// ---------------- pool gather: node, node_static (coords) ----------------
__global__ __launch_bounds__(256) void k_poolgather(const float* __restrict__ xyz,
                                                    const float* __restrict__ topv,
                                                    const int* __restrict__ topi,
                                                    float* __restrict__ node_ws,
                                                    float* __restrict__ out_node,
                                                    float* __restrict__ out_nstat) {
    int t = blockIdx.x * 256 + threadIdx.x;
    int j = t & 2047, b = t >> 11;
    int i = topi[b * 2048 + j];
    float v = topv[b * 2048 + j];
#pragma unroll
    for (int k = 0; k < 3; ++k) {
        float sx = xyz[((long)b * 3 + k) * NPTS + i];
        float nd = sx * v;
        out_nstat[((long)b * 3 + k) * MNODE + j] = sx;
        out_node[((long)b * 3 + k) * MNODE + j] = nd;
        node_ws[((long)b * 3 + k) * MNODE + j] = nd;
    }
}

// ---------------- nf1: h ch0-127 = feat gathered * values ----------------
__global__ __launch_bounds__(256) void k_nf1(const float* __restrict__ feat,
                                             const float* __restrict__ topv,
                                             const int* __restrict__ topi,
                                             float* __restrict__ h) {
    int t = blockIdx.x * 256 + threadIdx.x;
    int j = t & 2047, c = (t >> 11) & 127, b = t >> 18;
    int i = topi[b * 2048 + j];
    float v = topv[b * 2048 + j];
    h[((long)b * 256 + c) * MNODE + j] = feat[((long)b * 128 + c) * NPTS + i] * v;
}

// ---------------- knn20 (block-per-node): exact stable top-20 ----------------
__device__ __forceinline__ unsigned int fsortbits(float f) {
    unsigned int u = __float_as_uint(f);
    return u ^ ((unsigned int)((int)u >> 31) | 0x80000000u);
}

__global__ __launch_bounds__(256) void k_knn20(const float* __restrict__ xyz,
                                               const float* __restrict__ node,
                                               int* __restrict__ k20) {
    __shared__ unsigned int s1[256];
    __shared__ int s2[256];
    __shared__ int lcnt;
    int m = blockIdx.x & 2047, b = blockIdx.x >> 11;
    int t = threadIdx.x;
    float nx = node[((long)b * 3 + 0) * MNODE + m];
    float ny = node[((long)b * 3 + 1) * MNODE + m];
    float nz = node[((long)b * 3 + 2) * MNODE + m];
    float sm = nx * nx + ny * ny + nz * nz;
    const float* xb = xyz + (long)b * 3 * NPTS;
    unsigned int kmin = 0xFFFFFFFFu;
    for (int i = 0; i < 32; ++i) {
        int n = i * 256 + t;
        float px = xb[n], py = xb[NPTS + n], pz = xb[2 * NPTS + n];
        float d = (px * px + py * py + pz * pz) + sm - 2.f * (px * nx + py * ny + pz * nz);
        unsigned int key = fsortbits(d);
        kmin = key < kmin ? key : kmin;
    }
    s1[t] = kmin;
    if (t == 0) lcnt = 0;
    __syncthreads();
    for (int k = 2; k <= 256; k <<= 1) {
        for (int j = k >> 1; j > 0; j >>= 1) {
            int ixj = t ^ j;
            if (ixj > t) {
                unsigned int va = s1[t], vb = s1[ixj];
                bool up = ((t & k) == 0);
                if ((va > vb) == up) { s1[t] = vb; s1[ixj] = va; }
            }
            __syncthreads();
        }
    }
    unsigned int keyT = s1[19];
    __syncthreads();
    for (int i = 0; i < 32; ++i) {
        int n = i * 256 + t;
        float px = xb[n], py = xb[NPTS + n], pz = xb[2 * NPTS + n];
        float d = (px * px + py * py + pz * pz) + sm - 2.f * (px * nx + py * ny + pz * nz);
        unsigned int key = fsortbits(d);
        if (key <= keyT) {
            int p = atomicAdd(&lcnt, 1);
            if (p < 128) { s1[p] = key; s2[p] = n; }
        }
    }
    __syncthreads();
    int cnt = lcnt;
    if (cnt <= 128) {
        if (t >= cnt && t < 128) { s1[t] = 0xFFFFFFFFu; s2[t] = 0x7FFFFFFF; }
        __syncthreads();
        for (int k = 2; k <= 128; k <<= 1) {
            for (int j = k >> 1; j > 0; j >>= 1) {
                if (t < 128) {
                    int ixj = t ^ j;
                    if (ixj > t) {
                        unsigned int va = s1[t], vb = s1[ixj];
                        int ia = s2[t], ib = s2[ixj];
                        bool up = ((t & k) == 0);
                        bool gt = (va > vb) || (va == vb && ia > ib);
                        if (gt == up) { s1[t] = vb; s1[ixj] = va; s2[t] = ib; s2[ixj] = ia; }
                    }
                }
                __syncthreads();
            }
        }
        if (t < 20) k20[((long)b * 2048 + m) * 20 + t] = s2[t];
    } else {
        unsigned int lastk = 0u; int lasti = -1;
        for (int r = 0; r < 20; ++r) {
            unsigned int bk = 0xFFFFFFFFu; int bi = 0x7FFFFFFF;
            for (int i = 0; i < 32; ++i) {
                int n = i * 256 + t;
                float px = xb[n], py = xb[NPTS + n], pz = xb[2 * NPTS + n];
                float d = (px * px + py * py + pz * pz) + sm - 2.f * (px * nx + py * ny + pz * nz);
                unsigned int key = fsortbits(d);
                bool gtlast = (key > lastk) || (key == lastk && n > lasti);
                bool ltbest = (key < bk) || (key == bk && n < bi);
                if (gtlast && ltbest) { bk = key; bi = n; }
            }
            s1[t] = bk; s2[t] = bi;
            __syncthreads();
            for (int s = 128; s > 0; s >>= 1) {
                if (t < s) {
                    unsigned int vo = s1[t + s]; int io = s2[t + s];
                    unsigned int vm = s1[t]; int im = s2[t];
                    if (vo < vm || (vo == vm && io < im)) { s1[t] = vo; s2[t] = io; }
                }
                __syncthreads();
            }
            if (t == 0) k20[((long)b * 2048 + m) * 20 + r] = s2[0];
            lastk = s1[0]; lasti = s2[0];
            __syncthreads();
        }
    }
}

// ---------------- aggregate: h ch128-255 = max over 20 gathered feats ----------------
__global__ __launch_bounds__(256) void k_agg(const float* __restrict__ feat,
                                             const int* __restrict__ k20,
                                             float* __restrict__ h) {
    int t = blockIdx.x * 256 + threadIdx.x;
    int m = t & 2047, c = (t >> 11) & 127, b = t >> 18;
    const int* ip = k20 + ((long)b * 2048 + m) * 20;
    const float* fb = feat + ((long)b * 128 + c) * NPTS;
    float mx = -3.0e38f;
#pragma unroll
    for (int q = 0; q < 20; ++q) mx = fmaxf(mx, fb[ip[q] & 8191]);
    h[((long)b * 256 + 128 + c) * MNODE + m] = mx;
}

// ---------------- gemv: block per output o, all 4 batches; coalesced row read ----------------
__global__ __launch_bounds__(256) void k_gemv(const float* __restrict__ in, int C,
                                              const float* __restrict__ W, int wpitch,
                                              const float* __restrict__ lb,
                                              const float* __restrict__ sc,
                                              const float* __restrict__ bi, int do_relu,
                                              float* __restrict__ out, int O) {
    __shared__ float red[256];
    int o = blockIdx.x;
    int t = threadIdx.x;
    const float* wp = W + (long)o * wpitch;
    float a0 = 0.f, a1 = 0.f, a2 = 0.f, a3 = 0.f;
    for (int c = t * 4; c < C; c += 1024) {
        float4 w = *reinterpret_cast<const float4*>(wp + c);
        float4 v0 = *reinterpret_cast<const float4*>(in + 0L * C + c);
        float4 v1 = *reinterpret_cast<const float4*>(in + 1L * C + c);
        float4 v2 = *reinterpret_cast<const float4*>(in + 2L * C + c);
        float4 v3 = *reinterpret_cast<const float4*>(in + 3L * C + c);
        a0 += w.x * v0.x + w.y * v0.y + w.z * v0.z + w.w * v0.w;
        a1 += w.x * v1.x + w.y * v1.y + w.z * v1.z + w.w * v1.w;
        a2 += w.x * v2.x + w.y * v2.y + w.z * v2.z + w.w * v2.w;
        a3 += w.x * v3.x + w.y * v3.y + w.z * v3.z + w.w * v3.w;
    }
    float lbv = lb ? lb[o] : 0.f;
    float scv = sc ? sc[o] : 1.f;
    float biv = bi ? bi[o] : 0.f;
#pragma unroll
    for (int b = 0; b < 4; ++b) {
        float a = (b == 0) ? a0 : (b == 1) ? a1 : (b == 2) ? a2 : a3;
        __syncthreads();
        red[t] = a;
        __syncthreads();
        for (int s2 = 128; s2 > 0; s2 >>= 1) {
            if (t < s2) red[t] += red[t + s2];
            __syncthreads();
        }
        if (t == 0) {
            float r = (red[0] + lbv) * scv + biv;
            if (do_relu) r = fmaxf(r, 0.f);
            out[(long)b * O + o] = r;
        }
    }
}

// ---------------- unpool knn3 ----------------
__global__ __launch_bounds__(256) void k_knn3(const float* __restrict__ xyz,
                                              const float* __restrict__ node,
                                              int* __restrict__ k3i, float* __restrict__ k3w) {
    __shared__ float sx[2048], sy[2048], sz[2048], sn[2048];
    __shared__ float md[256][3];
    __shared__ int   mi[256][3];
    int b = blockIdx.x >> 8;
    int pbase = (blockIdx.x & 255) * 32;
    int t = threadIdx.x;
    const float* nb = node + (long)b * 3 * MNODE;
    for (int j = t; j < 2048; j += 256) {
        float qx = nb[j], qy = nb[MNODE + j], qz = nb[2 * MNODE + j];
        sx[j] = qx; sy[j] = qy; sz[j] = qz;
        sn[j] = qx * qx + qy * qy + qz * qz;
    }
    __syncthreads();
    int i = t & 31, q = t >> 5;
    int n = pbase + i;
    float px = xyz[((long)b * 3 + 0) * NPTS + n];
    float py = xyz[((long)b * 3 + 1) * NPTS + n];
    float pz = xyz[((long)b * 3 + 2) * NPTS + n];
    float sp = px * px + py * py + pz * pz;
    float d0 = 3.0e38f, d1 = 3.0e38f, d2 = 3.0e38f;
    int i0 = 0, i1 = 0, i2 = 0;
    int m0 = q * 256;
#pragma unroll 4
    for (int k = 0; k < 256; ++k) {
        int m = m0 + k;
        float d = (sp + sn[m]) - 2.f * (px * sx[m] + py * sy[m] + pz * sz[m]);
        if (d < d2) {
            d2 = d; i2 = m;
            if (d2 < d1) { float td = d1; d1 = d2; d2 = td; int ti = i1; i1 = i2; i2 = ti; }
            if (d1 < d0) { float td = d0; d0 = d1; d1 = td; int ti = i0; i0 = i1; i1 = ti; }
        }
    }
    md[t][0] = d0; md[t][1] = d1; md[t][2] = d2;
    mi[t][0] = i0; mi[t][1] = i1; mi[t][2] = i2;
    __syncthreads();
    if (t < 32) {
        int p0 = 0, p1 = 0, p2 = 0, p3 = 0, p4 = 0, p5 = 0, p6 = 0, p7 = 0;
        float rd[3]; int ri[3];
#pragma unroll
        for (int r = 0; r < 3; ++r) {
            float bestd = 3.0e38f; int besti = 0x7FFFFFFF; int bestq = -1;
#define KNN3_HEAD(QQ, PV)                                                              \
            {                                                                          \
                float dd = md[(QQ) * 32 + t][PV]; int ii = mi[(QQ) * 32 + t][PV];      \
                if (dd < bestd || (dd == bestd && ii < besti)) {                       \
                    bestd = dd; besti = ii; bestq = (QQ);                              \
                }                                                                      \
            }
            KNN3_HEAD(0, p0) KNN3_HEAD(1, p1) KNN3_HEAD(2, p2) KNN3_HEAD(3, p3)
            KNN3_HEAD(4, p4) KNN3_HEAD(5, p5) KNN3_HEAD(6, p6) KNN3_HEAD(7, p7)
#undef KNN3_HEAD
            rd[r] = bestd; ri[r] = besti;
            p0 += (bestq == 0); p1 += (bestq == 1); p2 += (bestq == 2); p3 += (bestq == 3);
            p4 += (bestq == 4); p5 += (bestq == 5); p6 += (bestq == 6); p7 += (bestq == 7);
        }
        float mxd = fmaxf(rd[0], fmaxf(rd[1], rd[2]));
        float e0 = expf(rd[0] - mxd), e1 = expf(rd[1] - mxd), e2 = expf(rd[2] - mxd);
        float inv = 1.f / (e0 + e1 + e2);
        long base = ((long)b * NPTS + pbase + t) * 3;
        k3i[base] = ri[0]; k3i[base + 1] = ri[1]; k3i[base + 2] = ri[2];
        k3w[base] = e0 * inv; k3w[base + 1] = e1 * inv; k3w[base + 2] = e2 * inv;
    }
}

__global__ __launch_bounds__(256) void k_unpool(const float* __restrict__ s7,
                                                const int* __restrict__ k3i,
                                                const float* __restrict__ k3w,
                                                float* __restrict__ sup) {
    int t = blockIdx.x * 256 + threadIdx.x;
    int n = t & 8191, c = (t >> 13) & 127, b = t >> 20;
    long base = ((long)b * NPTS + n) * 3;
    const float* spp = s7 + ((long)b * 128 + c) * MNODE;
    float a = k3w[base] * spp[k3i[base]] + k3w[base + 1] * spp[k3i[base + 1]] +
              k3w[base + 2] * spp[k3i[base + 2]];
    sup[((long)b * 128 + c) * NPTS + n] = a;
}

extern "C" void kernel_launch(void* const* d_in, const int* in_sizes, int n_in,
                              void* d_out, int out_size, void* d_ws, size_t ws_size,
                              hipStream_t stream) {
    const float* x     = (const float*)d_in[0];
    const float* c1w   = (const float*)d_in[1];
    const float* c2w   = (const float*)d_in[2];
    const float* c2mw  = (const float*)d_in[3];
    const float* c3w   = (const float*)d_in[4];
    const float* c4w   = (const float*)d_in[5];
    const float* c5w   = (const float*)d_in[6];
    const float* c6w   = (const float*)d_in[7];
    const float* c7w   = (const float*)d_in[8];
    const float* c8w   = (const float*)d_in[9];
    const float* c9w   = (const float*)d_in[10];
    const float* c10w  = (const float*)d_in[11];
    const float* bn1s  = (const float*)d_in[12]; const float* bn1b  = (const float*)d_in[13];
    const float* bn2s  = (const float*)d_in[14]; const float* bn2b  = (const float*)d_in[15];
    const float* bn2ms = (const float*)d_in[16]; const float* bn2mb = (const float*)d_in[17];
    const float* bn3s  = (const float*)d_in[18]; const float* bn3b  = (const float*)d_in[19];
    const float* bn4s  = (const float*)d_in[20]; const float* bn4b  = (const float*)d_in[21];
    const float* bn5s  = (const float*)d_in[22]; const float* bn5b  = (const float*)d_in[23];
    const float* bn6cs = (const float*)d_in[24]; const float* bn6cb = (const float*)d_in[25];
    const float* bn7cs = (const float*)d_in[26]; const float* bn7cb = (const float*)d_in[27];
    const float* bn8s  = (const float*)d_in[28]; const float* bn8b  = (const float*)d_in[29];
    const float* bn9s  = (const float*)d_in[30]; const float* bn9b  = (const float*)d_in[31];
    const float* bn6hs = (const float*)d_in[32]; const float* bn6hb = (const float*)d_in[33];
    const float* bn7hs = (const float*)d_in[34]; const float* bn7hb = (const float*)d_in[35];
    const float* poolw = (const float*)d_in[36]; const float* poolb = (const float*)d_in[37];
    const float* l1w   = (const float*)d_in[38];
    const float* l2w   = (const float*)d_in[39]; const float* l2b   = (const float*)d_in[40];
    const float* l3w   = (const float*)d_in[41]; const float* l3b   = (const float*)d_in[42];

    float* ws   = (float*)d_ws;
    float* xt1  = ws + WS_XT1;
    float* x34  = ws + WS_A;
    float* s8   = ws + WS_A;                 // LATE alias: x34 dead after conv7
    float* scor = ws + WS_B;
    float* hbuf = ws + WS_C;
    float* s6   = ws + WS_C;
    float* s7   = ws + WS_C + 1048576L;
    float* sup  = ws + WS_D;
    float* s9   = ws + WS_D;                 // LATE alias: sup dead after sp8 pack
    float* topv = ws + WS_TOPV;
    int*   topi = (int*)(ws + WS_TOPI);
    float* node = ws + WS_NODE;
    float* maxp = ws + WS_MAXP;
    float* vec  = ws + WS_VEC;
    float* c1b  = ws + WS_C1;
    float* c2b_ = ws + WS_C2;
    float* b6   = ws + WS_B6;
    int*   k20  = (int*)(ws + WS_K20);
    float* pmax1 = ws + WS_K20;              // 32*4*1024 = 131072 floats
    float* pmax2 = ws + WS_K20 + 131072;     // + 32768 -> total 163840 = k20 size
    int*   k3i  = (int*)(ws + WS_K3I);
    float* k3w  = ws + WS_K3W;
    unsigned int*   sskeys = (unsigned int*)(ws + WS_A);
    unsigned short* ssidx  = (unsigned short*)(ws + WS_A + 65536);
    // bf16 staging (lifetime-aliased):
    u16* xtb   = (u16*)(ws + WS_C);                 // [4][8192][128] (before hbuf)
    u16* c2mwb = (u16*)(ws + WS_D);                 // [1024][128] (early)
    u16* x34b  = (u16*)(ws + WS_B);                 // [4][2048][512] (after scores)
    u16* c5wb  = (u16*)(ws + WS_B + 2097152);       // [1024][512]
    u16* hb    = (u16*)(ws + WS_D);                 // [4][2048][256] (mid; sup later)
    u16* x3p   = (u16*)(ws + WS_D + 1048576);       // [4][2048][256]
    u16* c3wb  = (u16*)(ws + WS_D + 2097152);       // [256][256]
    u16* c4wb  = (u16*)(ws + WS_D + 2129920);       // [256][256]
    u16* sp8   = (u16*)(ws + WS_B);                 // [4][8192][192] (late; scores/x34b dead)
    u16* cc8wb = (u16*)(ws + WS_B + 3145728);       // [128][192]
    u16* sp9   = (u16*)(ws + WS_B);                 // reuse after conv8
    u16* cc9wb = (u16*)(ws + WS_B + 3145728);       // reuse after conv8

    float* out       = (float*)d_out;
    float* out_cls   = out;
    float* out_seg   = out + 60;
    float* out_node  = out + 60 + 65536;
    float* out_nstat = out_node + 24576;

    // x1 -> xt1_ ch0-63; x2 via fp32 k_conv
    k_conv1<<<dim3(8192), dim3(256), 0, stream>>>(x, c1w, bn1s, bn1b, xt1);
    k_conv<<<dim3(8, 8, 4), dim3(256), 0, stream>>>(xt1, 64, 128L * NPTS, nullptr, 0, 0,
                                                    c2w, 64, nullptr, bn2s, bn2b, 1,
                                                    xt1 + 64L * NPTS, 128L * NPTS, 64, NPTS);
    // conv2m via bf16-MFMA
    k_packT2<<<dim3(256, 4, 4), dim3(256), 0, stream>>>(xt1, 128L * NPTS, 128, NPTS, xtb, 128, 0);
    k_packw<<<dim3(512), dim3(256), 0, stream>>>(c2mw, 128, 128, 1024, c2mwb);
    k_cvmx_bf<<<dim3(32, 16, 4), dim3(256), 0, stream>>>(xtb, c2mwb, 128,
                                                         bn2ms, bn2mb, 1, pmax1, 1024, NPTS);
    // pool-proj stays fp32 (top-k rank-sensitive)
    k_convmax<<<dim3(8, 64, 4), dim3(256), 16 * 257 * 4, stream>>>(
        xt1, 128, 128L * NPTS,
        poolw, poolb, nullptr, nullptr, 0, pmax2,
        nullptr, nullptr, nullptr, nullptr, 0, nullptr,
        128, 1024, NPTS);
    k_maxred2<<<dim3(32), dim3(256), 0, stream>>>(pmax1, 32, 1024, vec, 2048,
                                                  pmax2, 8, 1024, maxp, 1024, 16);
    // scores
    k_scores<<<dim3(32, 1, 4), dim3(256), 0, stream>>>(xt1, maxp, scor);
    // exact top-256 per (b,e)
    k_sorta<<<dim3(256), dim3(256), 0, stream>>>(scor, sskeys, ssidx);
    k_sortb<<<dim3(32), dim3(512), 0, stream>>>(sskeys, ssidx, topv, topi);
    // node / node_static / nf1
    k_poolgather<<<dim3(32), dim3(256), 0, stream>>>(x, topv, topi, node, out_node, out_nstat);
    k_nf1<<<dim3(4096), dim3(256), 0, stream>>>(xt1, topv, topi, hbuf);
    // aggregate
    k_knn20<<<dim3(8192), dim3(256), 0, stream>>>(x, node, k20);
    k_agg<<<dim3(4096), dim3(256), 0, stream>>>(xt1, k20, hbuf);
    // conv3 via bf16-MFMA: hbuf -> hb, c3w -> c3wb, out = x34 ch0-255
    k_packT2<<<dim3(64, 8, 4), dim3(256), 0, stream>>>(hbuf, 256L * MNODE, 256, MNODE, hb, 256, 0);
    k_packw<<<dim3(256), dim3(256), 0, stream>>>(c3w, 256, 256, 256, c3wb);
    k_conv_bf<<<dim3(8, 4, 4), dim3(256), 0, stream>>>(hb, 256, c3wb, bn3s, bn3b, 1,
                                                       x34, 512L * MNODE, MNODE);
    // conv4 via bf16-MFMA: x3 -> x3p, out = x34 ch256-511
    k_packT2<<<dim3(64, 8, 4), dim3(256), 0, stream>>>(x34, 512L * MNODE, 256, MNODE, x3p, 256, 0);
    k_packw<<<dim3(256), dim3(256), 0, stream>>>(c4w, 256, 256, 256, c4wb);
    k_conv_bf<<<dim3(8, 4, 4), dim3(256), 0, stream>>>(x3p, 256, c4wb, bn4s, bn4b, 1,
                                                       x34 + 256L * MNODE, 512L * MNODE, MNODE);
    // conv5 via bf16-MFMA
    k_packT2<<<dim3(64, 16, 4), dim3(256), 0, stream>>>(x34, 512L * MNODE, 512, MNODE, x34b, 512, 0);
    k_packw<<<dim3(2048), dim3(256), 0, stream>>>(c5w, 512, 512, 1024, c5wb);
    k_cvmx_bf<<<dim3(8, 16, 4), dim3(256), 0, stream>>>(x34b, c5wb, 512,
                                                        bn5s, bn5b, 1, pmax1, 1024, MNODE);
    k_maxred<<<dim3(16), dim3(256), 0, stream>>>(pmax1, 8, 1024, vec + 1024, 2048);
    // classification head
    k_gemv<<<dim3(512), dim3(256), 0, stream>>>(vec, 2048, l1w, 2048, nullptr, bn6hs, bn6hb, 1, c1b, 512);
    k_gemv<<<dim3(256), dim3(256), 0, stream>>>(c1b, 512, l2w, 512, l2b, bn7hs, bn7hb, 1, c2b_, 256);
    k_gemv<<<dim3(15), dim3(256), 0, stream>>>(c2b_, 256, l3w, 256, l3b, nullptr, nullptr, 0, out_cls, 15);
    // conv6 / conv7 (fp32)
    k_gemv<<<dim3(128), dim3(256), 0, stream>>>(vec, 2048, c6w, 2304, nullptr, nullptr, nullptr, 0, b6, 128);
    k_conv<<<dim3(2, 16, 4), dim3(256), 0, stream>>>(x34 + 256L * MNODE, 256, 512L * MNODE,
                                                     nullptr, 0, 0, c6w + 2048, 2304, b6,
                                                     bn6cs, bn6cb, 1, s6, 128L * MNODE, 128, MNODE);
    k_conv<<<dim3(2, 16, 4), dim3(256), 0, stream>>>(s6, 128, 128L * MNODE, x34, 256, 512L * MNODE,
                                                     c7w, 384, nullptr, bn7cs, bn7cb, 1,
                                                     s7, 128L * MNODE, 128, MNODE);
    // unpool
    k_knn3<<<dim3(1024), dim3(256), 0, stream>>>(x, node, k3i, k3w);
    k_unpool<<<dim3(16384), dim3(256), 0, stream>>>(s7, k3i, k3w, sup);
    // conv8 via bf16-MFMA: concat(sup, xt1 ch64-127) -> sp8, out s8 (WS_A; x34 dead)
    k_packT2<<<dim3(256, 4, 4), dim3(256), 0, stream>>>(sup, 128L * NPTS, 128, NPTS, sp8, 192, 0);
    k_packT2<<<dim3(256, 2, 4), dim3(256), 0, stream>>>(xt1 + 64L * NPTS, 128L * NPTS, 64, NPTS,
                                                        sp8, 192, 128);
    k_packw<<<dim3(96), dim3(256), 0, stream>>>(c8w, 192, 192, 128, cc8wb);
    k_conv_bf<<<dim3(32, 2, 4), dim3(256), 0, stream>>>(sp8, 192, cc8wb, bn8s, bn8b, 1,
                                                        s8, 128L * NPTS, NPTS);
    // conv9 via bf16-MFMA: concat(s8, xt1 ch0-63) -> sp9, out s9 (WS_D; sup dead)
    k_packT2<<<dim3(256, 4, 4), dim3(256), 0, stream>>>(s8, 128L * NPTS, 128, NPTS, sp9, 192, 0);
    k_packT2<<<dim3(256, 2, 4), dim3(256), 0, stream>>>(xt1, 128L * NPTS, 64, NPTS, sp9, 192, 128);
    k_packw<<<dim3(96), dim3(256), 0, stream>>>(c9w, 192, 192, 128, cc9wb);
    k_conv_bf<<<dim3(32, 2, 4), dim3(256), 0, stream>>>(sp9, 192, cc9wb, bn9s, bn9b, 1,
                                                        s9, 128L * NPTS, NPTS);
    // conv10 (fp32, tiny)
    k_conv<<<dim3(8, 1, 4), dim3(256), 0, stream>>>(s9, 128, 128L * NPTS, nullptr, 0, 0,
                                                    c10w, 128, nullptr, nullptr, nullptr, 0,
                                                    out_seg, 2L * NPTS, 2, NPTS);
    (void)in_sizes; (void)n_in; (void)out_size; (void)ws_size;
}

// Round 18
// 825.446 us; speedup vs baseline: 7.1328x; 1.0727x over previous
//
#include <hip/hip_runtime.h>
#include <math.h>

typedef unsigned short u16;
typedef short bf8 __attribute__((ext_vector_type(8)));   // 8 bf16 (4 VGPRs)
typedef float f4 __attribute__((ext_vector_type(4)));    // 4 fp32

// Problem constants
#define NPTS 8192
#define MNODE 2048

// ---------------- ws layout (float element offsets) ----------------
#define WS_XT1  0L          // xt1_ [4][128][8192] — live whole pass
#define WS_A    4194304L    // sort scratch EARLY; x34 [4][512][2048] mid; s8 LATE (x34 dead)
#define WS_B    8388608L    // scores early; x34b+c5wb mid; sp8/sp9+c8wb/c9wb late
#define WS_C    12582912L   // xtb early; h [4][256][2048]; s6/s7 later
#define WS_D    14680064L   // c2mwb early; hb/x3p/c3wb/c4wb mid; s6p/c6wb/c7wb; sup then s9 late
#define WS_TOPV 18874368L
#define WS_TOPI 18882560L
#define WS_NODE 18890752L
#define WS_MAXP 18915328L
#define WS_VEC  18919424L
#define WS_C1   18927616L
#define WS_C2   18929664L
#define WS_B6   18930688L
#define WS_K20  18931200L   // int [4][2048][20]; ALSO pmax scratch (disjoint lifetime)
#define WS_K3I  19095040L
#define WS_K3W  19193344L
// end = 19291648 floats = 73.6 MB

__device__ __forceinline__ u16 bf16rne(float f) {
    unsigned u = __float_as_uint(f);
    unsigned r = u + 0x7FFFu + ((u >> 16) & 1u);
    return (u16)(r >> 16);
}

// ---------------- conv1: x[4,3,8192] -> xt1_ ch0-63 ----------------
__global__ __launch_bounds__(256) void k_conv1(const float* __restrict__ x,
                                               const float* __restrict__ W,
                                               const float* __restrict__ sc,
                                               const float* __restrict__ bi,
                                               float* __restrict__ out) {
    int t = blockIdx.x * 256 + threadIdx.x;
    int n = t & 8191, o = (t >> 13) & 63, b = t >> 19;
    const float* xb = x + (long)b * 3 * NPTS;
    float a = W[o * 3 + 0] * xb[n] + W[o * 3 + 1] * xb[NPTS + n] + W[o * 3 + 2] * xb[2 * NPTS + n];
    a = fmaxf(a * sc[o] + bi[o], 0.f);
    out[((long)b * 128 + o) * NPTS + n] = a;
}

// ---------------- bf16 packing ----------------
// MFMA 16x16x32 bf16 A/B frag k-layout: element j of lane l covers
// k = (l>>4)*4 + (j&3) + 16*(j>>2). Pre-permute k inside each 32-block so a
// lane's 8 frag elements are 8 CONTIGUOUS packed entries at offset (l>>4)*8.

// weights: W f32 [O][wpitch] -> out bf16 [O][C] (k-permuted)
__global__ __launch_bounds__(256) void k_packw(const float* __restrict__ W, int wpitch,
                                               int C, int O, u16* __restrict__ out) {
    int t = blockIdx.x * 256 + threadIdx.x;
    if (t >= O * C) return;
    int o = t / C, p = t - o * C;
    int blk = p >> 5, pj = p & 31;
    int g = pj >> 3, j = pj & 7;
    int k = (blk << 5) + g * 4 + (j & 3) + 16 * (j >> 2);
    out[t] = bf16rne(W[(long)o * wpitch + k]);
}

// input: in f32 (batch stride ibs, row stride Nn) C channels -> out bf16 [B][Nn][opitch]
// at column offset coff (transpose + k-permute), LDS-tiled. C, coff multiples of 32.
__global__ __launch_bounds__(256) void k_packT2(const float* __restrict__ in, long ibs,
                                                int C, int Nn, u16* __restrict__ out,
                                                int opitch, int coff) {
    __shared__ float tile[32][33];
    int b = blockIdx.z;
    int k0 = blockIdx.y * 32, n0 = blockIdx.x * 32;
    int tx = threadIdx.x & 31, ty = threadIdx.x >> 5;   // 32 x 8
    for (int r = 0; r < 32; r += 8)
        tile[ty + r][tx] = in[(long)b * ibs + (long)(k0 + ty + r) * Nn + n0 + tx];
    __syncthreads();
    for (int r = 0; r < 32; r += 8) {
        int n = n0 + ty + r;
        int p = tx;
        int g = p >> 3, j = p & 7;
        int kin = g * 4 + (j & 3) + 16 * (j >> 2);
        out[((long)b * Nn + n) * opitch + coff + k0 + p] = bf16rne(tile[kin][ty + r]);
    }
}

// ---------------- bf16-MFMA conv + bn/relu + partial max over n ----------------
__global__ __launch_bounds__(256) void k_cvmx_bf(const u16* __restrict__ in,
                                                 const u16* __restrict__ wpk, int C,
                                                 const float* __restrict__ sc,
                                                 const float* __restrict__ bi, int do_relu,
                                                 float* __restrict__ pmax, int O, int Nn) {
    __shared__ float red[4][16][17];
    int b = blockIdx.z, nc = blockIdx.x;
    int lane = threadIdx.x & 63, w = threadIdx.x >> 6;
    int o0 = (blockIdx.y * 4 + w) * 16;
    const u16* wp = wpk + (long)(o0 + (lane & 15)) * C + ((lane >> 4) << 3);
    const u16* ip = in + ((long)b * Nn + nc * 256 + (lane & 15)) * C + ((lane >> 4) << 3);
    long nstride = 16L * C;
    f4 acc[16];
#pragma unroll
    for (int t = 0; t < 16; ++t) acc[t] = (f4)(0.f);
    for (int kk = 0; kk < C; kk += 32) {
        bf8 a = *(const bf8*)(wp + kk);
#pragma unroll
        for (int t = 0; t < 16; ++t) {
            bf8 bb = *(const bf8*)(ip + t * nstride + kk);
            acc[t] = __builtin_amdgcn_mfma_f32_16x16x32_bf16(a, bb, acc[t], 0, 0, 0);
        }
    }
#pragma unroll
    for (int j = 0; j < 4; ++j) {
        int ol = (lane >> 4) * 4 + j;
        int o = o0 + ol;
        float scv = sc ? sc[o] : 1.f;
        float biv = bi ? bi[o] : 0.f;
        float mm = -3.0e38f;
#pragma unroll
        for (int t = 0; t < 16; ++t) {
            float v = acc[t][j] * scv + biv;
            if (do_relu) v = fmaxf(v, 0.f);
            mm = fmaxf(mm, v);
        }
        red[w][ol][lane & 15] = mm;
    }
    __syncthreads();
    if (threadIdx.x < 64) {
        int ww = threadIdx.x >> 4, oo = threadIdx.x & 15;
        float mm = red[ww][oo][0];
#pragma unroll
        for (int i = 1; i < 16; ++i) mm = fmaxf(mm, red[ww][oo][i]);
        int og = (blockIdx.y * 4 + ww) * 16 + oo;
        pmax[((long)nc * 4 + b) * O + og] = mm;
    }
}

// ---------------- bf16-MFMA conv + bn/relu, FULL output [B][O][Nn] ----------------
__global__ __launch_bounds__(256) void k_conv_bf(const u16* __restrict__ in,
                                                 int C,   // packed pitch
                                                 const u16* __restrict__ wpk,
                                                 const float* __restrict__ sc,
                                                 const float* __restrict__ bi, int do_relu,
                                                 float* __restrict__ out, long obs, int Nn) {
    int b = blockIdx.z, nc = blockIdx.x;
    int lane = threadIdx.x & 63, w = threadIdx.x >> 6;
    int o0 = (blockIdx.y * 4 + w) * 16;
    const u16* wp = wpk + (long)(o0 + (lane & 15)) * C + ((lane >> 4) << 3);
    const u16* ip = in + ((long)b * Nn + nc * 256 + (lane & 15)) * C + ((lane >> 4) << 3);
    long nstride = 16L * C;
    f4 acc[16];
#pragma unroll
    for (int t = 0; t < 16; ++t) acc[t] = (f4)(0.f);
    for (int kk = 0; kk < C; kk += 32) {
        bf8 a = *(const bf8*)(wp + kk);
#pragma unroll
        for (int t = 0; t < 16; ++t) {
            bf8 bb = *(const bf8*)(ip + t * nstride + kk);
            acc[t] = __builtin_amdgcn_mfma_f32_16x16x32_bf16(a, bb, acc[t], 0, 0, 0);
        }
    }
#pragma unroll
    for (int j = 0; j < 4; ++j) {
        int o = o0 + (lane >> 4) * 4 + j;
        float scv = sc ? sc[o] : 1.f;
        float biv = bi ? bi[o] : 0.f;
        float* op = out + (long)b * obs + (long)o * Nn + nc * 256 + (lane & 15);
#pragma unroll
        for (int t = 0; t < 16; ++t) {
            float v = acc[t][j] * scv + biv;
            if (do_relu) v = fmaxf(v, 0.f);
            op[t * 16] = v;
        }
    }
}

// ---------------- bf16-MFMA conv, TWO packed inputs + per-(b,o) extra ----------------
// in1 pitch p1 (use C1 cols), in2 pitch p2 (use C2 cols); wpk [O][C1+C2] packed.
// epilogue: v = (acc + extra[b][o]) * sc + bi; optional relu. Validated frag layout (R15).
__global__ __launch_bounds__(256) void k_conv_bf2(
        const u16* __restrict__ in1, int p1, int C1,
        const u16* __restrict__ in2, int p2, int C2,
        const u16* __restrict__ wpk,
        const float* __restrict__ extra,
        const float* __restrict__ sc, const float* __restrict__ bi, int do_relu,
        float* __restrict__ out, long obs, int O, int Nn) {
    int b = blockIdx.z, nc = blockIdx.x;
    int lane = threadIdx.x & 63, w = threadIdx.x >> 6;
    int o0 = (blockIdx.y * 4 + w) * 16;
    int Ct = C1 + C2;
    const u16* wp = wpk + (long)(o0 + (lane & 15)) * Ct + ((lane >> 4) << 3);
    f4 acc[16];
#pragma unroll
    for (int t = 0; t < 16; ++t) acc[t] = (f4)(0.f);
    {
        const u16* ip1 = in1 + ((long)b * Nn + nc * 256 + (lane & 15)) * p1 + ((lane >> 4) << 3);
        long ns1 = 16L * p1;
        for (int kk = 0; kk < C1; kk += 32) {
            bf8 a = *(const bf8*)(wp + kk);
#pragma unroll
            for (int t = 0; t < 16; ++t) {
                bf8 bb = *(const bf8*)(ip1 + t * ns1 + kk);
                acc[t] = __builtin_amdgcn_mfma_f32_16x16x32_bf16(a, bb, acc[t], 0, 0, 0);
            }
        }
    }
    if (in2) {
        const u16* ip2 = in2 + ((long)b * Nn + nc * 256 + (lane & 15)) * p2 + ((lane >> 4) << 3);
        long ns2 = 16L * p2;
        for (int kk = 0; kk < C2; kk += 32) {
            bf8 a = *(const bf8*)(wp + C1 + kk);
#pragma unroll
            for (int t = 0; t < 16; ++t) {
                bf8 bb = *(const bf8*)(ip2 + t * ns2 + kk);
                acc[t] = __builtin_amdgcn_mfma_f32_16x16x32_bf16(a, bb, acc[t], 0, 0, 0);
            }
        }
    }
#pragma unroll
    for (int j = 0; j < 4; ++j) {
        int o = o0 + (lane >> 4) * 4 + j;
        float e = extra ? extra[(long)b * O + o] : 0.f;
        float scv = sc ? sc[o] : 1.f;
        float biv = bi ? bi[o] : 0.f;
        float* op = out + (long)b * obs + (long)o * Nn + nc * 256 + (lane & 15);
#pragma unroll
        for (int t = 0; t < 16; ++t) {
            float v = (acc[t][j] + e) * scv + biv;
            if (do_relu) v = fmaxf(v, 0.f);
            op[t * 16] = v;
        }
    }
}

// 16-output-tile FMA block (fp32 path)
#define CMAX_FMA16()                                                        \
    {                                                                       \
        const float4* wp4 = reinterpret_cast<const float4*>(Wl + c16);      \
        _Pragma("unroll")                                                   \
        for (int g = 0; g < 4; ++g) {                                       \
            float4 w = wp4[g];                                              \
            acc[4 * g + 0].x = fmaf(w.x, v.x, acc[4 * g + 0].x);            \
            acc[4 * g + 0].y = fmaf(w.x, v.y, acc[4 * g + 0].y);            \
            acc[4 * g + 0].z = fmaf(w.x, v.z, acc[4 * g + 0].z);            \
            acc[4 * g + 0].w = fmaf(w.x, v.w, acc[4 * g + 0].w);            \
            acc[4 * g + 1].x = fmaf(w.y, v.x, acc[4 * g + 1].x);            \
            acc[4 * g + 1].y = fmaf(w.y, v.y, acc[4 * g + 1].y);            \
            acc[4 * g + 1].z = fmaf(w.y, v.z, acc[4 * g + 1].z);            \
            acc[4 * g + 1].w = fmaf(w.y, v.w, acc[4 * g + 1].w);            \
            acc[4 * g + 2].x = fmaf(w.z, v.x, acc[4 * g + 2].x);            \
            acc[4 * g + 2].y = fmaf(w.z, v.y, acc[4 * g + 2].y);            \
            acc[4 * g + 2].z = fmaf(w.z, v.z, acc[4 * g + 2].z);            \
            acc[4 * g + 2].w = fmaf(w.z, v.w, acc[4 * g + 2].w);            \
            acc[4 * g + 3].x = fmaf(w.w, v.x, acc[4 * g + 3].x);            \
            acc[4 * g + 3].y = fmaf(w.w, v.y, acc[4 * g + 3].y);            \
            acc[4 * g + 3].z = fmaf(w.w, v.z, acc[4 * g + 3].z);            \
            acc[4 * g + 3].w = fmaf(w.w, v.w, acc[4 * g + 3].w);            \
        }                                                                   \
    }

// ---------------- fp32 convmax (pool-proj only; rank-sensitive path) ----------------
// NOTE: no min-waves bound (R13: (256,8) forced VGPR 52->32 spill, 5.9x slowdown).
__global__ __launch_bounds__(256) void k_convmax(
        const float* __restrict__ in, int C, long ibs,
        const float* __restrict__ W1, const float* __restrict__ cb1,
        const float* __restrict__ sc1, const float* __restrict__ bi1, int relu1,
        float* __restrict__ pmax1,
        const float* __restrict__ W2, const float* __restrict__ cb2,
        const float* __restrict__ sc2, const float* __restrict__ bi2, int relu2,
        float* __restrict__ pmax2,
        int wpitch, int O, int Nn) {
    extern __shared__ float sm_[];
    float* Wl = sm_;              // [C][16]
    float* red = sm_;             // [16][257] — aliases Wl (disjoint lifetime)
    int b = blockIdx.z;
    int ns = blockIdx.x;
    int oblocks = O >> 4;
    int setid = (int)blockIdx.y / oblocks;
    int og0 = ((int)blockIdx.y - setid * oblocks) * 16;
    const float* W  = setid ? W2 : W1;
    const float* cb = setid ? cb2 : cb1;
    const float* sc = setid ? sc2 : sc1;
    const float* bi = setid ? bi2 : bi1;
    int do_relu     = setid ? relu2 : relu1;
    float* pmax     = setid ? pmax2 : pmax1;
    for (int t = threadIdx.x; t < 16 * C; t += 256) {
        int c = t >> 4, o = t & 15;
        Wl[t] = W[(long)(og0 + o) * wpitch + c];
    }
    __syncthreads();
    int n0 = ns * 1024 + threadIdx.x * 4;
    float4 acc[16];
#pragma unroll
    for (int o = 0; o < 16; ++o) acc[o] = make_float4(0.f, 0.f, 0.f, 0.f);
    const float* p = in + (long)b * ibs + n0;
    float4 v = *reinterpret_cast<const float4*>(p);
    for (int c = 0; c < C - 1; ++c) {
        float4 vn = *reinterpret_cast<const float4*>(p + (long)(c + 1) * Nn);
        int c16 = c * 16;
        CMAX_FMA16();
        v = vn;
    }
    {
        int c16 = (C - 1) * 16;
        CMAX_FMA16();
    }
    float h2[16];
#pragma unroll
    for (int o = 0; o < 16; ++o) {
        float cbv = cb ? cb[og0 + o] : 0.f;
        float scv = sc ? sc[og0 + o] : 1.f;
        float biv = bi ? bi[og0 + o] : 0.f;
        float4 a = acc[o];
        float vx = (a.x + cbv) * scv + biv;
        float vy = (a.y + cbv) * scv + biv;
        float vz = (a.z + cbv) * scv + biv;
        float vw = (a.w + cbv) * scv + biv;
        if (do_relu) {
            vx = fmaxf(vx, 0.f); vy = fmaxf(vy, 0.f);
            vz = fmaxf(vz, 0.f); vw = fmaxf(vw, 0.f);
        }
        h2[o] = fmaxf(fmaxf(vx, vy), fmaxf(vz, vw));
    }
    __syncthreads();
#pragma unroll
    for (int o = 0; o < 16; ++o) red[o * 257 + threadIdx.x] = h2[o];
    __syncthreads();
    for (int ls = 7; ls >= 0; --ls) {
        int s = 1 << ls;
        for (int w = threadIdx.x; w < 16 * s; w += 256) {
            int o = w >> ls, i = w & (s - 1);
            float* r = red + o * 257;
            r[i] = fmaxf(r[i], r[i + s]);
        }
        __syncthreads();
    }
    if (threadIdx.x < 16)
        pmax[((long)ns * 4 + b) * O + og0 + threadIdx.x] = red[threadIdx.x * 257];
}

// finalize: out[b*obs + o] = max over nsplit partials. Dual-set variant.
__global__ __launch_bounds__(256) void k_maxred2(const float* __restrict__ pA, int nsA, int OA,
                                                 float* __restrict__ outA, long obsA,
                                                 const float* __restrict__ pB, int nsB, int OB,
                                                 float* __restrict__ outB, long obsB,
                                                 int blocksA) {
    const float* pm; int ns, O; float* out; long obs; int bid = blockIdx.x;
    if (bid < blocksA) { pm = pA; ns = nsA; O = OA; out = outA; obs = obsA; }
    else { pm = pB; ns = nsB; O = OB; out = outB; obs = obsB; bid -= blocksA; }
    int t = bid * 256 + threadIdx.x;
    if (t >= 4 * O) return;
    int o = t % O, b = t / O;
    float m = -3.0e38f;
    for (int s = 0; s < ns; ++s) m = fmaxf(m, pm[((long)s * 4 + b) * O + o]);
    out[(long)b * obs + o] = m;
}

__global__ __launch_bounds__(256) void k_maxred(const float* __restrict__ pmax, int nsplit,
                                                int O, float* __restrict__ out, long obs) {
    int t = blockIdx.x * 256 + threadIdx.x;
    if (t >= 4 * O) return;
    int o = t % O, b = t / O;
    float m = -3.0e38f;
    for (int s = 0; s < nsplit; ++s) m = fmaxf(m, pmax[((long)s * 4 + b) * O + o]);
    out[(long)b * obs + o] = m;
}

// ---------------- generic fp32 conv(+extra)(+bn)(+relu), up to 2 concat inputs ----------------
#define CONV_FMA8()                                                         \
    {                                                                       \
        const float4* wp4 = reinterpret_cast<const float4*>(Wl + c8);       \
        _Pragma("unroll")                                                   \
        for (int g = 0; g < 2; ++g) {                                       \
            float4 w = wp4[g];                                              \
            acc[4 * g + 0].x = fmaf(w.x, v.x, acc[4 * g + 0].x);            \
            acc[4 * g + 0].y = fmaf(w.x, v.y, acc[4 * g + 0].y);            \
            acc[4 * g + 0].z = fmaf(w.x, v.z, acc[4 * g + 0].z);            \
            acc[4 * g + 0].w = fmaf(w.x, v.w, acc[4 * g + 0].w);            \
            acc[4 * g + 1].x = fmaf(w.y, v.x, acc[4 * g + 1].x);            \
            acc[4 * g + 1].y = fmaf(w.y, v.y, acc[4 * g + 1].y);            \
            acc[4 * g + 1].z = fmaf(w.y, v.z, acc[4 * g + 1].z);            \
            acc[4 * g + 1].w = fmaf(w.y, v.w, acc[4 * g + 1].w);            \
            acc[4 * g + 2].x = fmaf(w.z, v.x, acc[4 * g + 2].x);            \
            acc[4 * g + 2].y = fmaf(w.z, v.y, acc[4 * g + 2].y);            \
            acc[4 * g + 2].z = fmaf(w.z, v.z, acc[4 * g + 2].z);            \
            acc[4 * g + 2].w = fmaf(w.z, v.w, acc[4 * g + 2].w);            \
            acc[4 * g + 3].x = fmaf(w.w, v.x, acc[4 * g + 3].x);            \
            acc[4 * g + 3].y = fmaf(w.w, v.y, acc[4 * g + 3].y);            \
            acc[4 * g + 3].z = fmaf(w.w, v.z, acc[4 * g + 3].z);            \
            acc[4 * g + 3].w = fmaf(w.w, v.w, acc[4 * g + 3].w);            \
        }                                                                   \
    }

__global__ __launch_bounds__(256) void k_conv(const float* __restrict__ in1, int C1, long ibs1,
                                              const float* __restrict__ in2, int C2, long ibs2,
                                              const float* __restrict__ W, int wpitch,
                                              const float* __restrict__ extra,
                                              const float* __restrict__ sc,
                                              const float* __restrict__ bi, int do_relu,
                                              float* __restrict__ out, long obs, int O, int Nn) {
    __shared__ float Wl[384 * 8];
    int b = blockIdx.z;
    int og0 = blockIdx.y * 8;
    int on = O - og0; if (on > 8) on = 8;
    int Ct = C1 + C2;
    for (int t = threadIdx.x; t < Ct * 8; t += 256) {
        int c = t >> 3, o = t & 7;
        Wl[t] = (o < on) ? W[(long)(og0 + o) * wpitch + c] : 0.f;
    }
    __syncthreads();
    int n0 = blockIdx.x * 1024 + threadIdx.x * 4;
    float4 acc[8];
#pragma unroll
    for (int o = 0; o < 8; ++o) acc[o] = make_float4(0.f, 0.f, 0.f, 0.f);
    const float* p1 = in1 + (long)b * ibs1 + n0;
    {
        float4 v = *reinterpret_cast<const float4*>(p1);
        for (int c = 0; c < C1 - 1; ++c) {
            float4 vn = *reinterpret_cast<const float4*>(p1 + (long)(c + 1) * Nn);
            int c8 = c * 8;
            CONV_FMA8();
            v = vn;
        }
        int c8 = (C1 - 1) * 8;
        CONV_FMA8();
    }
    if (in2) {
        const float* p2 = in2 + (long)b * ibs2 + n0;
        float4 v = *reinterpret_cast<const float4*>(p2);
        for (int c = 0; c < C2 - 1; ++c) {
            float4 vn = *reinterpret_cast<const float4*>(p2 + (long)(c + 1) * Nn);
            int c8 = (C1 + c) * 8;
            CONV_FMA8();
            v = vn;
        }
        int c8 = (Ct - 1) * 8;
        CONV_FMA8();
    }
#pragma unroll
    for (int o = 0; o < 8; ++o) {
        if (o < on) {
            float e = extra ? extra[(long)b * O + og0 + o] : 0.f;
            float s = sc ? sc[og0 + o] : 1.f;
            float bv = bi ? bi[og0 + o] : 0.f;
            float4 a = acc[o];
            a.x = (a.x + e) * s + bv;
            a.y = (a.y + e) * s + bv;
            a.z = (a.z + e) * s + bv;
            a.w = (a.w + e) * s + bv;
            if (do_relu) {
                a.x = fmaxf(a.x, 0.f); a.y = fmaxf(a.y, 0.f);
                a.z = fmaxf(a.z, 0.f); a.w = fmaxf(a.w, 0.f);
            }
            *reinterpret_cast<float4*>(out + (long)b * obs + (long)(og0 + o) * Nn + n0) = a;
        }
    }
}

// ---------------- scores: one n per thread, all 8 e; grid (32,1,4)=128 blocks ----------------
__global__ __launch_bounds__(256) void k_scores(const float* __restrict__ feat,
                                                const float* __restrict__ maxp,
                                                float* __restrict__ scores) {
    __shared__ float vl[1024];
    int b = blockIdx.z;
    for (int t = threadIdx.x; t < 1024; t += 256) vl[t] = maxp[b * 1024 + t];
    __syncthreads();
    int n = blockIdx.x * 256 + threadIdx.x;
    float acc[8];
#pragma unroll
    for (int e = 0; e < 8; ++e) acc[e] = 0.f;
    const float* p = feat + (long)b * 128 * NPTS + n;
    float v = p[0];
    for (int c = 0; c < 127; ++c) {
        float vn = p[(long)(c + 1) * NPTS];
#pragma unroll
        for (int e = 0; e < 8; ++e) acc[e] = fmaf(vl[c * 8 + e], v, acc[e]);
        v = vn;
    }
#pragma unroll
    for (int e = 0; e < 8; ++e) acc[e] = fmaf(vl[127 * 8 + e], v, acc[e]);
#pragma unroll
    for (int e = 0; e < 8; ++e)
        scores[((long)b * 8 + e) * NPTS + n] = 1.f / (1.f + expf(-acc[e]));
}

// ---------------- hierarchical exact sorted top-256 per (b,e) ----------------
__global__ __launch_bounds__(256) void k_sorta(const float* __restrict__ scores,
                                               unsigned int* __restrict__ kout,
                                               unsigned short* __restrict__ iout) {
    __shared__ unsigned int kv[1024];
    __shared__ unsigned short ki[1024];
    int ch = blockIdx.x & 7;
    const float* sp = scores + (long)(blockIdx.x >> 3) * NPTS + ch * 1024;
    for (int t = threadIdx.x; t < 1024; t += 256) {
        kv[t] = __float_as_uint(sp[t]) ^ 0xFFFFFFFFu;
        ki[t] = (unsigned short)(ch * 1024 + t);
    }
    __syncthreads();
    for (int k = 2; k <= 1024; k <<= 1) {
        for (int j = k >> 1; j > 0; j >>= 1) {
            for (int t = threadIdx.x; t < 1024; t += 256) {
                int ixj = t ^ j;
                if (ixj > t) {
                    unsigned int va = kv[t], vb = kv[ixj];
                    unsigned short ia = ki[t], ib = ki[ixj];
                    bool up = ((t & k) == 0);
                    bool gt = (va > vb) || (va == vb && ia > ib);
                    if (gt == up) { kv[t] = vb; kv[ixj] = va; ki[t] = ib; ki[ixj] = ia; }
                }
            }
            __syncthreads();
        }
    }
    if (threadIdx.x < 256) {
        kout[blockIdx.x * 256 + threadIdx.x] = kv[threadIdx.x];
        iout[blockIdx.x * 256 + threadIdx.x] = ki[threadIdx.x];
    }
}

__global__ __launch_bounds__(512) void k_sortb(const unsigned int* __restrict__ kin,
                                               const unsigned short* __restrict__ iin,
                                               float* __restrict__ topv,
                                               int* __restrict__ topi) {
    __shared__ unsigned int kv[2048];
    __shared__ unsigned short ki[2048];
    int be = blockIdx.x, b = be >> 3, e = be & 7;
    for (int t = threadIdx.x; t < 2048; t += 512) {
        kv[t] = kin[be * 2048 + t];
        ki[t] = iin[be * 2048 + t];
    }
    __syncthreads();
    for (int k = 2; k <= 2048; k <<= 1) {
        for (int j = k >> 1; j > 0; j >>= 1) {
            for (int t = threadIdx.x; t < 2048; t += 512) {
                int ixj = t ^ j;
                if (ixj > t) {
                    unsigned int va = kv[t], vb = kv[ixj];
                    unsigned short ia = ki[t], ib = ki[ixj];
                    bool up = ((t & k) == 0);
                    bool gt = (va > vb) || (va == vb && ia > ib);
                    if (gt == up) { kv[t] = vb; kv[ixj] = va; ki[t] = ib; ki[ixj] = ia; }
                }
            }
            __syncthreads();
        }
    }
    for (int r = threadIdx.x; r < 256; r += 512) {
        int j = r * 8 + e;  // torch-order reshape: values[b, r*8+e] = v[b,e,r]
        topv[b * 2048 + j] = __uint_as_float(kv[r] ^ 0xFFFFFFFFu);
        topi[b * 2048 + j] = (int)ki[r];
    }
}

// ---------------- pool gather: node, node_static (coords) ----------------
__global__ __launch_bounds__(256) void k_poolgather(const float* __restrict__ xyz,
                                                    const float* __restrict__ topv,
                                                    const int* __restrict__ topi,
                                                    float* __restrict__ node_ws,
                                                    float* __restrict__ out_node,
                                                    float* __restrict__ out_nstat) {
    int t = blockIdx.x * 256 + threadIdx.x;
    int j = t & 2047, b = t >> 11;
    int i = topi[b * 2048 + j];
    float v = topv[b * 2048 + j];
#pragma unroll
    for (int k = 0; k < 3; ++k) {
        float sx = xyz[((long)b * 3 + k) * NPTS + i];
        float nd = sx * v;
        out_nstat[((long)b * 3 + k) * MNODE + j] = sx;
        out_node[((long)b * 3 + k) * MNODE + j] = nd;
        node_ws[((long)b * 3 + k) * MNODE + j] = nd;
    }
}

// ---------------- nf1: h ch0-127 = feat gathered * values ----------------
__global__ __launch_bounds__(256) void k_nf1(const float* __restrict__ feat,
                                             const float* __restrict__ topv,
                                             const int* __restrict__ topi,
                                             float* __restrict__ h) {
    int t = blockIdx.x * 256 + threadIdx.x;
    int j = t & 2047, c = (t >> 11) & 127, b = t >> 18;
    int i = topi[b * 2048 + j];
    float v = topv[b * 2048 + j];
    h[((long)b * 256 + c) * MNODE + j] = feat[((long)b * 128 + c) * NPTS + i] * v;
}

// ---------------- knn20 (block-per-node): exact stable top-20 ----------------
__device__ __forceinline__ unsigned int fsortbits(float f) {
    unsigned int u = __float_as_uint(f);
    return u ^ ((unsigned int)((int)u >> 31) | 0x80000000u);
}

__global__ __launch_bounds__(256) void k_knn20(const float* __restrict__ xyz,
                                               const float* __restrict__ node,
                                               int* __restrict__ k20) {
    __shared__ unsigned int s1[256];
    __shared__ int s2[256];
    __shared__ int lcnt;
    int m = blockIdx.x & 2047, b = blockIdx.x >> 11;
    int t = threadIdx.x;
    float nx = node[((long)b * 3 + 0) * MNODE + m];
    float ny = node[((long)b * 3 + 1) * MNODE + m];
    float nz = node[((long)b * 3 + 2) * MNODE + m];
    float sm = nx * nx + ny * ny + nz * nz;
    const float* xb = xyz + (long)b * 3 * NPTS;
    unsigned int kmin = 0xFFFFFFFFu;
    for (int i = 0; i < 32; ++i) {
        int n = i * 256 + t;
        float px = xb[n], py = xb[NPTS + n], pz = xb[2 * NPTS + n];
        float d = (px * px + py * py + pz * pz) + sm - 2.f * (px * nx + py * ny + pz * nz);
        unsigned int key = fsortbits(d);
        kmin = key < kmin ? key : kmin;
    }
    s1[t] = kmin;
    if (t == 0) lcnt = 0;
    __syncthreads();
    for (int k = 2; k <= 256; k <<= 1) {
        for (int j = k >> 1; j > 0; j >>= 1) {
            int ixj = t ^ j;
            if (ixj > t) {
                unsigned int va = s1[t], vb = s1[ixj];
                bool up = ((t & k) == 0);
                if ((va > vb) == up) { s1[t] = vb; s1[ixj] = va; }
            }
            __syncthreads();
        }
    }
    unsigned int keyT = s1[19];
    __syncthreads();
    for (int i = 0; i < 32; ++i) {
        int n = i * 256 + t;
        float px = xb[n], py = xb[NPTS + n], pz = xb[2 * NPTS + n];
        float d = (px * px + py * py + pz * pz) + sm - 2.f * (px * nx + py * ny + pz * nz);
        unsigned int key = fsortbits(d);
        if (key <= keyT) {
            int p = atomicAdd(&lcnt, 1);
            if (p < 128) { s1[p] = key; s2[p] = n; }
        }
    }
    __syncthreads();
    int cnt = lcnt;
    if (cnt <= 128) {
        if (t >= cnt && t < 128) { s1[t] = 0xFFFFFFFFu; s2[t] = 0x7FFFFFFF; }
        __syncthreads();
        for (int k = 2; k <= 128; k <<= 1) {
            for (int j = k >> 1; j > 0; j >>= 1) {
                if (t < 128) {
                    int ixj = t ^ j;
                    if (ixj > t) {
                        unsigned int va = s1[t], vb = s1[ixj];
                        int ia = s2[t], ib = s2[ixj];
                        bool up = ((t & k) == 0);
                        bool gt = (va > vb) || (va == vb && ia > ib);
                        if (gt == up) { s1[t] = vb; s1[ixj] = va; s2[t] = ib; s2[ixj] = ia; }
                    }
                }
                __syncthreads();
            }
        }
        if (t < 20) k20[((long)b * 2048 + m) * 20 + t] = s2[t];
    } else {
        unsigned int lastk = 0u; int lasti = -1;
        for (int r = 0; r < 20; ++r) {
            unsigned int bk = 0xFFFFFFFFu; int bi = 0x7FFFFFFF;
            for (int i = 0; i < 32; ++i) {
                int n = i * 256 + t;
                float px = xb[n], py = xb[NPTS + n], pz = xb[2 * NPTS + n];
                float d = (px * px + py * py + pz * pz) + sm - 2.f * (px * nx + py * ny + pz * nz);
                unsigned int key = fsortbits(d);
                bool gtlast = (key > lastk) || (key == lastk && n > lasti);
                bool ltbest = (key < bk) || (key == bk && n < bi);
                if (gtlast && ltbest) { bk = key; bi = n; }
            }
            s1[t] = bk; s2[t] = bi;
            __syncthreads();
            for (int s = 128; s > 0; s >>= 1) {
                if (t < s) {
                    unsigned int vo = s1[t + s]; int io = s2[t + s];
                    unsigned int vm = s1[t]; int im = s2[t];
                    if (vo < vm || (vo == vm && io < im)) { s1[t] = vo; s2[t] = io; }
                }
                __syncthreads();
            }
            if (t == 0) k20[((long)b * 2048 + m) * 20 + r] = s2[0];
            lastk = s1[0]; lasti = s2[0];
            __syncthreads();
        }
    }
}

// ---------------- aggregate: h ch128-255 = max over 20 gathered feats ----------------
__global__ __launch_bounds__(256) void k_agg(const float* __restrict__ feat,
                                             const int* __restrict__ k20,
                                             float* __restrict__ h) {
    int t = blockIdx.x * 256 + threadIdx.x;
    int m = t & 2047, c = (t >> 11) & 127, b = t >> 18;
    const int* ip = k20 + ((long)b * 2048 + m) * 20;
    const float* fb = feat + ((long)b * 128 + c) * NPTS;
    float mx = -3.0e38f;
#pragma unroll
    for (int q = 0; q < 20; ++q) mx = fmaxf(mx, fb[ip[q] & 8191]);
    h[((long)b * 256 + 128 + c) * MNODE + m] = mx;
}

// ---------------- gemv: block per output o, all 4 batches; coalesced row read ----------------
__global__ __launch_bounds__(256) void k_gemv(const float* __restrict__ in, int C,
                                              const float* __restrict__ W, int wpitch,
                                              const float* __restrict__ lb,
                                              const float* __restrict__ sc,
                                              const float* __restrict__ bi, int do_relu,
                                              float* __restrict__ out, int O) {
    __shared__ float red[256];
    int o = blockIdx.x;
    int t = threadIdx.x;
    const float* wp = W + (long)o * wpitch;
    float a0 = 0.f, a1 = 0.f, a2 = 0.f, a3 = 0.f;
    for (int c = t * 4; c < C; c += 1024) {
        float4 w = *reinterpret_cast<const float4*>(wp + c);
        float4 v0 = *reinterpret_cast<const float4*>(in + 0L * C + c);
        float4 v1 = *reinterpret_cast<const float4*>(in + 1L * C + c);
        float4 v2 = *reinterpret_cast<const float4*>(in + 2L * C + c);
        float4 v3 = *reinterpret_cast<const float4*>(in + 3L * C + c);
        a0 += w.x * v0.x + w.y * v0.y + w.z * v0.z + w.w * v0.w;
        a1 += w.x * v1.x + w.y * v1.y + w.z * v1.z + w.w * v1.w;
        a2 += w.x * v2.x + w.y * v2.y + w.z * v2.z + w.w * v2.w;
        a3 += w.x * v3.x + w.y * v3.y + w.z * v3.z + w.w * v3.w;
    }
    float lbv = lb ? lb[o] : 0.f;
    float scv = sc ? sc[o] : 1.f;
    float biv = bi ? bi[o] : 0.f;
#pragma unroll
    for (int b = 0; b < 4; ++b) {
        float a = (b == 0) ? a0 : (b == 1) ? a1 : (b == 2) ? a2 : a3;
        __syncthreads();
        red[t] = a;
        __syncthreads();
        for (int s2 = 128; s2 > 0; s2 >>= 1) {
            if (t < s2) red[t] += red[t + s2];
            __syncthreads();
        }
        if (t == 0) {
            float r = (red[0] + lbv) * scv + biv;
            if (do_relu) r = fmaxf(r, 0.f);
            out[(long)b * O + o] = r;
        }
    }
}

// ---------------- unpool knn3 ----------------
__global__ __launch_bounds__(256) void k_knn3(const float* __restrict__ xyz,
                                              const float* __restrict__ node,
                                              int* __restrict__ k3i, float* __restrict__ k3w) {
    __shared__ float sx[2048], sy[2048], sz[2048], sn[2048];
    __shared__ float md[256][3];
    __shared__ int   mi[256][3];
    int b = blockIdx.x >> 8;
    int pbase = (blockIdx.x & 255) * 32;
    int t = threadIdx.x;
    const float* nb = node + (long)b * 3 * MNODE;
    for (int j = t; j < 2048; j += 256) {
        float qx = nb[j], qy = nb[MNODE + j], qz = nb[2 * MNODE + j];
        sx[j] = qx; sy[j] = qy; sz[j] = qz;
        sn[j] = qx * qx + qy * qy + qz * qz;
    }
    __syncthreads();
    int i = t & 31, q = t >> 5;
    int n = pbase + i;
    float px = xyz[((long)b * 3 + 0) * NPTS + n];
    float py = xyz[((long)b * 3 + 1) * NPTS + n];
    float pz = xyz[((long)b * 3 + 2) * NPTS + n];
    float sp = px * px + py * py + pz * pz;
    float d0 = 3.0e38f, d1 = 3.0e38f, d2 = 3.0e38f;
    int i0 = 0, i1 = 0, i2 = 0;
    int m0 = q * 256;
#pragma unroll 4
    for (int k = 0; k < 256; ++k) {
        int m = m0 + k;
        float d = (sp + sn[m]) - 2.f * (px * sx[m] + py * sy[m] + pz * sz[m]);
        if (d < d2) {
            d2 = d; i2 = m;
            if (d2 < d1) { float td = d1; d1 = d2; d2 = td; int ti = i1; i1 = i2; i2 = ti; }
            if (d1 < d0) { float td = d0; d0 = d1; d1 = td; int ti = i0; i0 = i1; i1 = ti; }
        }
    }
    md[t][0] = d0; md[t][1] = d1; md[t][2] = d2;
    mi[t][0] = i0; mi[t][1] = i1; mi[t][2] = i2;
    __syncthreads();
    if (t < 32) {
        int p0 = 0, p1 = 0, p2 = 0, p3 = 0, p4 = 0, p5 = 0, p6 = 0, p7 = 0;
        float rd[3]; int ri[3];
#pragma unroll
        for (int r = 0; r < 3; ++r) {
            float bestd = 3.0e38f; int besti = 0x7FFFFFFF; int bestq = -1;
#define KNN3_HEAD(QQ, PV)                                                              \
            {                                                                          \
                float dd = md[(QQ) * 32 + t][PV]; int ii = mi[(QQ) * 32 + t][PV];      \
                if (dd < bestd || (dd == bestd && ii < besti)) {                       \
                    bestd = dd; besti = ii; bestq = (QQ);                              \
                }                                                                      \
            }
            KNN3_HEAD(0, p0) KNN3_HEAD(1, p1) KNN3_HEAD(2, p2) KNN3_HEAD(3, p3)
            KNN3_HEAD(4, p4) KNN3_HEAD(5, p5) KNN3_HEAD(6, p6) KNN3_HEAD(7, p7)
#undef KNN3_HEAD
            rd[r] = bestd; ri[r] = besti;
            p0 += (bestq == 0); p1 += (bestq == 1); p2 += (bestq == 2); p3 += (bestq == 3);
            p4 += (bestq == 4); p5 += (bestq == 5); p6 += (bestq == 6); p7 += (bestq == 7);
        }
        float mxd = fmaxf(rd[0], fmaxf(rd[1], rd[2]));
        float e0 = expf(rd[0] - mxd), e1 = expf(rd[1] - mxd), e2 = expf(rd[2] - mxd);
        float inv = 1.f / (e0 + e1 + e2);
        long base = ((long)b * NPTS + pbase + t) * 3;
        k3i[base] = ri[0]; k3i[base + 1] = ri[1]; k3i[base + 2] = ri[2];
        k3w[base] = e0 * inv; k3w[base + 1] = e1 * inv; k3w[base + 2] = e2 * inv;
    }
}

__global__ __launch_bounds__(256) void k_unpool(const float* __restrict__ s7,
                                                const int* __restrict__ k3i,
                                                const float* __restrict__ k3w,
                                                float* __restrict__ sup) {
    int t = blockIdx.x * 256 + threadIdx.x;
    int n = t & 8191, c = (t >> 13) & 127, b = t >> 20;
    long base = ((long)b * NPTS + n) * 3;
    const float* spp = s7 + ((long)b * 128 + c) * MNODE;
    float a = k3w[base] * spp[k3i[base]] + k3w[base + 1] * spp[k3i[base + 1]] +
              k3w[base + 2] * spp[k3i[base + 2]];
    sup[((long)b * 128 + c) * NPTS + n] = a;
}

extern "C" void kernel_launch(void* const* d_in, const int* in_sizes, int n_in,
                              void* d_out, int out_size, void* d_ws, size_t ws_size,
                              hipStream_t stream) {
    const float* x     = (const float*)d_in[0];
    const float* c1w   = (const float*)d_in[1];
    const float* c2w   = (const float*)d_in[2];
    const float* c2mw  = (const float*)d_in[3];
    const float* c3w   = (const float*)d_in[4];
    const float* c4w   = (const float*)d_in[5];
    const float* c5w   = (const float*)d_in[6];
    const float* c6w   = (const float*)d_in[7];
    const float* c7w   = (const float*)d_in[8];
    const float* c8w   = (const float*)d_in[9];
    const float* c9w   = (const float*)d_in[10];
    const float* c10w  = (const float*)d_in[11];
    const float* bn1s  = (const float*)d_in[12]; const float* bn1b  = (const float*)d_in[13];
    const float* bn2s  = (const float*)d_in[14]; const float* bn2b  = (const float*)d_in[15];
    const float* bn2ms = (const float*)d_in[16]; const float* bn2mb = (const float*)d_in[17];
    const float* bn3s  = (const float*)d_in[18]; const float* bn3b  = (const float*)d_in[19];
    const float* bn4s  = (const float*)d_in[20]; const float* bn4b  = (const float*)d_in[21];
    const float* bn5s  = (const float*)d_in[22]; const float* bn5b  = (const float*)d_in[23];
    const float* bn6cs = (const float*)d_in[24]; const float* bn6cb = (const float*)d_in[25];
    const float* bn7cs = (const float*)d_in[26]; const float* bn7cb = (const float*)d_in[27];
    const float* bn8s  = (const float*)d_in[28]; const float* bn8b  = (const float*)d_in[29];
    const float* bn9s  = (const float*)d_in[30]; const float* bn9b  = (const float*)d_in[31];
    const float* bn6hs = (const float*)d_in[32]; const float* bn6hb = (const float*)d_in[33];
    const float* bn7hs = (const float*)d_in[34]; const float* bn7hb = (const float*)d_in[35];
    const float* poolw = (const float*)d_in[36]; const float* poolb = (const float*)d_in[37];
    const float* l1w   = (const float*)d_in[38];
    const float* l2w   = (const float*)d_in[39]; const float* l2b   = (const float*)d_in[40];
    const float* l3w   = (const float*)d_in[41]; const float* l3b   = (const float*)d_in[42];

    float* ws   = (float*)d_ws;
    float* xt1  = ws + WS_XT1;
    float* x34  = ws + WS_A;
    float* s8   = ws + WS_A;                 // LATE alias: x34 dead after conv7
    float* scor = ws + WS_B;
    float* hbuf = ws + WS_C;
    float* s6   = ws + WS_C;
    float* s7   = ws + WS_C + 1048576L;
    float* sup  = ws + WS_D;
    float* s9   = ws + WS_D;                 // LATE alias: sup dead after sp8 pack
    float* topv = ws + WS_TOPV;
    int*   topi = (int*)(ws + WS_TOPI);
    float* node = ws + WS_NODE;
    float* maxp = ws + WS_MAXP;
    float* vec  = ws + WS_VEC;
    float* c1b  = ws + WS_C1;
    float* c2b_ = ws + WS_C2;
    float* b6   = ws + WS_B6;
    int*   k20  = (int*)(ws + WS_K20);
    float* pmax1 = ws + WS_K20;              // 32*4*1024 = 131072 floats
    float* pmax2 = ws + WS_K20 + 131072;     // + 32768 -> total 163840 = k20 size
    int*   k3i  = (int*)(ws + WS_K3I);
    float* k3w  = ws + WS_K3W;
    unsigned int*   sskeys = (unsigned int*)(ws + WS_A);
    unsigned short* ssidx  = (unsigned short*)(ws + WS_A + 65536);
    // bf16 staging (lifetime-aliased):
    u16* xtb   = (u16*)(ws + WS_C);                 // [4][8192][128] (before hbuf)
    u16* c2mwb = (u16*)(ws + WS_D);                 // [1024][128] (early)
    u16* x34b  = (u16*)(ws + WS_B);                 // [4][2048][512] (after scores; dead at sp8)
    u16* c5wb  = (u16*)(ws + WS_B + 2097152);       // [1024][512]
    u16* hb    = (u16*)(ws + WS_D);                 // [4][2048][256] (mid)
    u16* x3p   = (u16*)(ws + WS_D + 1048576);       // [4][2048][256]
    u16* c3wb  = (u16*)(ws + WS_D + 2097152);       // [256][256]
    u16* c4wb  = (u16*)(ws + WS_D + 2129920);       // [256][256]
    u16* s6p   = (u16*)(ws + WS_D);                 // [4][2048][128] (conv7 in1; hb dead)
    u16* c6wb  = (u16*)(ws + WS_D + 524288);        // [128][256]
    u16* c7wb  = (u16*)(ws + WS_D + 540672);        // [128][384]
    u16* sp8   = (u16*)(ws + WS_B);                 // [4][8192][192] (late)
    u16* cc8wb = (u16*)(ws + WS_B + 3145728);       // [128][192]
    u16* sp9   = (u16*)(ws + WS_B);                 // reuse after conv8
    u16* cc9wb = (u16*)(ws + WS_B + 3145728);       // reuse after conv8

    float* out       = (float*)d_out;
    float* out_cls   = out;
    float* out_seg   = out + 60;
    float* out_node  = out + 60 + 65536;
    float* out_nstat = out_node + 24576;

    // x1 -> xt1_ ch0-63; x2 via fp32 k_conv (feeds rank-sensitive pool/scores: stays fp32)
    k_conv1<<<dim3(8192), dim3(256), 0, stream>>>(x, c1w, bn1s, bn1b, xt1);
    k_conv<<<dim3(8, 8, 4), dim3(256), 0, stream>>>(xt1, 64, 128L * NPTS, nullptr, 0, 0,
                                                    c2w, 64, nullptr, bn2s, bn2b, 1,
                                                    xt1 + 64L * NPTS, 128L * NPTS, 64, NPTS);
    // conv2m via bf16-MFMA
    k_packT2<<<dim3(256, 4, 4), dim3(256), 0, stream>>>(xt1, 128L * NPTS, 128, NPTS, xtb, 128, 0);
    k_packw<<<dim3(512), dim3(256), 0, stream>>>(c2mw, 128, 128, 1024, c2mwb);
    k_cvmx_bf<<<dim3(32, 16, 4), dim3(256), 0, stream>>>(xtb, c2mwb, 128,
                                                         bn2ms, bn2mb, 1, pmax1, 1024, NPTS);
    // pool-proj stays fp32 (top-k rank-sensitive)
    k_convmax<<<dim3(8, 64, 4), dim3(256), 16 * 257 * 4, stream>>>(
        xt1, 128, 128L * NPTS,
        poolw, poolb, nullptr, nullptr, 0, pmax2,
        nullptr, nullptr, nullptr, nullptr, 0, nullptr,
        128, 1024, NPTS);
    k_maxred2<<<dim3(32), dim3(256), 0, stream>>>(pmax1, 32, 1024, vec, 2048,
                                                  pmax2, 8, 1024, maxp, 1024, 16);
    // scores
    k_scores<<<dim3(32, 1, 4), dim3(256), 0, stream>>>(xt1, maxp, scor);
    // exact top-256 per (b,e)
    k_sorta<<<dim3(256), dim3(256), 0, stream>>>(scor, sskeys, ssidx);
    k_sortb<<<dim3(32), dim3(512), 0, stream>>>(sskeys, ssidx, topv, topi);
    // node / node_static / nf1
    k_poolgather<<<dim3(32), dim3(256), 0, stream>>>(x, topv, topi, node, out_node, out_nstat);
    k_nf1<<<dim3(4096), dim3(256), 0, stream>>>(xt1, topv, topi, hbuf);
    // aggregate
    k_knn20<<<dim3(8192), dim3(256), 0, stream>>>(x, node, k20);
    k_agg<<<dim3(4096), dim3(256), 0, stream>>>(xt1, k20, hbuf);
    // conv3 via bf16-MFMA
    k_packT2<<<dim3(64, 8, 4), dim3(256), 0, stream>>>(hbuf, 256L * MNODE, 256, MNODE, hb, 256, 0);
    k_packw<<<dim3(256), dim3(256), 0, stream>>>(c3w, 256, 256, 256, c3wb);
    k_conv_bf<<<dim3(8, 4, 4), dim3(256), 0, stream>>>(hb, 256, c3wb, bn3s, bn3b, 1,
                                                       x34, 512L * MNODE, MNODE);
    // conv4 via bf16-MFMA
    k_packT2<<<dim3(64, 8, 4), dim3(256), 0, stream>>>(x34, 512L * MNODE, 256, MNODE, x3p, 256, 0);
    k_packw<<<dim3(256), dim3(256), 0, stream>>>(c4w, 256, 256, 256, c4wb);
    k_conv_bf<<<dim3(8, 4, 4), dim3(256), 0, stream>>>(x3p, 256, c4wb, bn4s, bn4b, 1,
                                                       x34 + 256L * MNODE, 512L * MNODE, MNODE);
    // conv5 via bf16-MFMA (x34b reused below by conv6/conv7)
    k_packT2<<<dim3(64, 16, 4), dim3(256), 0, stream>>>(x34, 512L * MNODE, 512, MNODE, x34b, 512, 0);
    k_packw<<<dim3(2048), dim3(256), 0, stream>>>(c5w, 512, 512, 1024, c5wb);
    k_cvmx_bf<<<dim3(8, 16, 4), dim3(256), 0, stream>>>(x34b, c5wb, 512,
                                                        bn5s, bn5b, 1, pmax1, 1024, MNODE);
    k_maxred<<<dim3(16), dim3(256), 0, stream>>>(pmax1, 8, 1024, vec + 1024, 2048);
    // classification head
    k_gemv<<<dim3(512), dim3(256), 0, stream>>>(vec, 2048, l1w, 2048, nullptr, bn6hs, bn6hb, 1, c1b, 512);
    k_gemv<<<dim3(256), dim3(256), 0, stream>>>(c1b, 512, l2w, 512, l2b, bn7hs, bn7hb, 1, c2b_, 256);
    k_gemv<<<dim3(15), dim3(256), 0, stream>>>(c2b_, 256, l3w, 256, l3b, nullptr, nullptr, 0, out_cls, 15);
    // conv6 via bf16-MFMA: x4 part = x34b columns 256-511 (pointer offset, 32-aligned);
    // vrep part = b6 (fp32 gemv) added as 'extra' in epilogue
    k_gemv<<<dim3(128), dim3(256), 0, stream>>>(vec, 2048, c6w, 2304, nullptr, nullptr, nullptr, 0, b6, 128);
    k_packw<<<dim3(128), dim3(256), 0, stream>>>(c6w + 2048, 2304, 256, 128, c6wb);
    k_conv_bf2<<<dim3(8, 2, 4), dim3(256), 0, stream>>>(x34b + 256, 512, 256,
                                                        nullptr, 0, 0, c6wb, b6,
                                                        bn6cs, bn6cb, 1,
                                                        s6, 128L * MNODE, 128, MNODE);
    // conv7 via bf16-MFMA: in1 = packed s6, in2 = x34b columns 0-255 (x3)
    k_packT2<<<dim3(64, 4, 4), dim3(256), 0, stream>>>(s6, 128L * MNODE, 128, MNODE, s6p, 128, 0);
    k_packw<<<dim3(192), dim3(256), 0, stream>>>(c7w, 384, 384, 128, c7wb);
    k_conv_bf2<<<dim3(8, 2, 4), dim3(256), 0, stream>>>(s6p, 128, 128,
                                                        x34b, 512, 256, c7wb, nullptr,
                                                        bn7cs, bn7cb, 1,
                                                        s7, 128L * MNODE, 128, MNODE);
    // unpool
    k_knn3<<<dim3(1024), dim3(256), 0, stream>>>(x, node, k3i, k3w);
    k_unpool<<<dim3(16384), dim3(256), 0, stream>>>(s7, k3i, k3w, sup);
    // conv8 via bf16-MFMA
    k_packT2<<<dim3(256, 4, 4), dim3(256), 0, stream>>>(sup, 128L * NPTS, 128, NPTS, sp8, 192, 0);
    k_packT2<<<dim3(256, 2, 4), dim3(256), 0, stream>>>(xt1 + 64L * NPTS, 128L * NPTS, 64, NPTS,
                                                        sp8, 192, 128);
    k_packw<<<dim3(96), dim3(256), 0, stream>>>(c8w, 192, 192, 128, cc8wb);
    k_conv_bf<<<dim3(32, 2, 4), dim3(256), 0, stream>>>(sp8, 192, cc8wb, bn8s, bn8b, 1,
                                                        s8, 128L * NPTS, NPTS);
    // conv9 via bf16-MFMA
    k_packT2<<<dim3(256, 4, 4), dim3(256), 0, stream>>>(s8, 128L * NPTS, 128, NPTS, sp9, 192, 0);
    k_packT2<<<dim3(256, 2, 4), dim3(256), 0, stream>>>(xt1, 128L * NPTS, 64, NPTS, sp9, 192, 128);
    k_packw<<<dim3(96), dim3(256), 0, stream>>>(c9w, 192, 192, 128, cc9wb);
    k_conv_bf<<<dim3(32, 2, 4), dim3(256), 0, stream>>>(sp9, 192, cc9wb, bn9s, bn9b, 1,
                                                        s9, 128L * NPTS, NPTS);
    // conv10 (fp32, tiny)
    k_conv<<<dim3(8, 1, 4), dim3(256), 0, stream>>>(s9, 128, 128L * NPTS, nullptr, 0, 0,
                                                    c10w, 128, nullptr, nullptr, nullptr, 0,
                                                    out_seg, 2L * NPTS, 2, NPTS);
    (void)in_sizes; (void)n_in; (void)out_size; (void)ws_size;
}

// Round 19
// 806.360 us; speedup vs baseline: 7.3016x; 1.0237x over previous
//
#include <hip/hip_runtime.h>
#include <math.h>

typedef unsigned short u16;
typedef short bf8 __attribute__((ext_vector_type(8)));   // 8 bf16 (4 VGPRs)
typedef float f4 __attribute__((ext_vector_type(4)));    // 4 fp32

// Problem constants
#define NPTS 8192
#define MNODE 2048

// ---------------- ws layout (float element offsets) ----------------
#define WS_XT1  0L          // xt1_ [4][128][8192] — live whole pass
#define WS_A    4194304L    // sort scratch EARLY; x34 mid; s8 LATE (x34 dead)
#define WS_B    8388608L    // scores early; x34b+c5wb mid; sp8/sp9 late; cc8wb/cc9wb @+3145728/+3158016
#define WS_C    12582912L   // xtb early; h [4][256][2048]; s6/s7 later
#define WS_D    14680064L   // c2mwb@0; hb/x3p@0..2097152; c3wb/c4wb@2097152; c6wb/c7wb@2162688; s6p@0 late; sup/s9 last
#define WS_TOPV 18874368L
#define WS_TOPI 18882560L
#define WS_NODE 18890752L
#define WS_MAXP 18915328L
#define WS_VEC  18919424L
#define WS_C1   18927616L
#define WS_C2   18929664L
#define WS_B6   18930688L
#define WS_K20  18931200L   // int [4][2048][20]; ALSO pmax scratch (disjoint lifetime)
#define WS_K3I  19095040L
#define WS_K3W  19193344L
// end = 19291648 floats = 73.6 MB

__device__ __forceinline__ u16 bf16rne(float f) {
    unsigned u = __float_as_uint(f);
    unsigned r = u + 0x7FFFu + ((u >> 16) & 1u);
    return (u16)(r >> 16);
}

// ---------------- conv1: x[4,3,8192] -> xt1_ ch0-63 ----------------
__global__ __launch_bounds__(256) void k_conv1(const float* __restrict__ x,
                                               const float* __restrict__ W,
                                               const float* __restrict__ sc,
                                               const float* __restrict__ bi,
                                               float* __restrict__ out) {
    int t = blockIdx.x * 256 + threadIdx.x;
    int n = t & 8191, o = (t >> 13) & 63, b = t >> 19;
    const float* xb = x + (long)b * 3 * NPTS;
    float a = W[o * 3 + 0] * xb[n] + W[o * 3 + 1] * xb[NPTS + n] + W[o * 3 + 2] * xb[2 * NPTS + n];
    a = fmaxf(a * sc[o] + bi[o], 0.f);
    out[((long)b * 128 + o) * NPTS + n] = a;
}

// ---------------- bf16 packing ----------------
// MFMA 16x16x32 bf16 A/B frag k-layout: element j of lane l covers
// k = (l>>4)*4 + (j&3) + 16*(j>>2). Pre-permute k inside each 32-block so a
// lane's 8 frag elements are 8 CONTIGUOUS packed entries at offset (l>>4)*8.

// ALL weight packs in one launch. Segments hardcoded (shapes fixed).
__global__ __launch_bounds__(256) void k_packall(
        const float* __restrict__ c2mw, const float* __restrict__ c3w,
        const float* __restrict__ c4w,  const float* __restrict__ c5w,
        const float* __restrict__ c6w,  const float* __restrict__ c7w,
        const float* __restrict__ c8w,  const float* __restrict__ c9w,
        u16* __restrict__ d2m, u16* __restrict__ d3, u16* __restrict__ d4,
        u16* __restrict__ d5,  u16* __restrict__ d6, u16* __restrict__ d7,
        u16* __restrict__ d8,  u16* __restrict__ d9) {
    int t = blockIdx.x * 256 + threadIdx.x;
    const float* W; u16* dst; int C, wp, base;
    if (t < 131072)      { W = c2mw;       dst = d2m; C = 128; wp = 128;  base = 0; }
    else if (t < 196608) { W = c3w;        dst = d3;  C = 256; wp = 256;  base = 131072; }
    else if (t < 262144) { W = c4w;        dst = d4;  C = 256; wp = 256;  base = 196608; }
    else if (t < 786432) { W = c5w;        dst = d5;  C = 512; wp = 512;  base = 262144; }
    else if (t < 819200) { W = c6w + 2048; dst = d6;  C = 256; wp = 2304; base = 786432; }
    else if (t < 868352) { W = c7w;        dst = d7;  C = 384; wp = 384;  base = 819200; }
    else if (t < 892928) { W = c8w;        dst = d8;  C = 192; wp = 192;  base = 868352; }
    else if (t < 917504) { W = c9w;        dst = d9;  C = 192; wp = 192;  base = 892928; }
    else return;
    int u = t - base;
    int o = u / C, p = u - o * C;
    int blk = p >> 5, pj = p & 31;
    int g = pj >> 3, j = pj & 7;
    int k = (blk << 5) + g * 4 + (j & 3) + 16 * (j >> 2);
    dst[u] = bf16rne(W[(long)o * wp + k]);
}

// input: in f32 (batch stride ibs, row stride Nn) C channels -> out bf16 [B][Nn][opitch]
// at column offset coff (transpose + k-permute), LDS-tiled. C, coff multiples of 32.
__global__ __launch_bounds__(256) void k_packT2(const float* __restrict__ in, long ibs,
                                                int C, int Nn, u16* __restrict__ out,
                                                int opitch, int coff) {
    __shared__ float tile[32][33];
    int b = blockIdx.z;
    int k0 = blockIdx.y * 32, n0 = blockIdx.x * 32;
    int tx = threadIdx.x & 31, ty = threadIdx.x >> 5;   // 32 x 8
    for (int r = 0; r < 32; r += 8)
        tile[ty + r][tx] = in[(long)b * ibs + (long)(k0 + ty + r) * Nn + n0 + tx];
    __syncthreads();
    for (int r = 0; r < 32; r += 8) {
        int n = n0 + ty + r;
        int p = tx;
        int g = p >> 3, j = p & 7;
        int kin = g * 4 + (j & 3) + 16 * (j >> 2);
        out[((long)b * Nn + n) * opitch + coff + k0 + p] = bf16rne(tile[kin][ty + r]);
    }
}

// dual-source concat pack: src1 -> cols [0,C1), src2 -> cols [C1,C1+C2).
// grid.y = C1/32 + C2/32 (segment select).
__global__ __launch_bounds__(256) void k_packT2d(const float* __restrict__ in1, long ibs1, int C1,
                                                 const float* __restrict__ in2, long ibs2, int C2,
                                                 int Nn, u16* __restrict__ out, int opitch) {
    __shared__ float tile[32][33];
    int b = blockIdx.z;
    int y1 = C1 >> 5;
    const float* in; int k0, coff;
    if ((int)blockIdx.y < y1) { in = in1 + (long)b * ibs1; k0 = blockIdx.y * 32; coff = 0; }
    else { in = in2 + (long)b * ibs2; k0 = ((int)blockIdx.y - y1) * 32; coff = C1; }
    int n0 = blockIdx.x * 32;
    int tx = threadIdx.x & 31, ty = threadIdx.x >> 5;
    for (int r = 0; r < 32; r += 8)
        tile[ty + r][tx] = in[(long)(k0 + ty + r) * Nn + n0 + tx];
    __syncthreads();
    for (int r = 0; r < 32; r += 8) {
        int n = n0 + ty + r;
        int p = tx, g = p >> 3, j = p & 7;
        int kin = g * 4 + (j & 3) + 16 * (j >> 2);
        out[((long)b * Nn + n) * opitch + coff + k0 + p] = bf16rne(tile[kin][ty + r]);
    }
}

// ---------------- bf16-MFMA conv + bn/relu + partial max over n ----------------
__global__ __launch_bounds__(256) void k_cvmx_bf(const u16* __restrict__ in,
                                                 const u16* __restrict__ wpk, int C,
                                                 const float* __restrict__ sc,
                                                 const float* __restrict__ bi, int do_relu,
                                                 float* __restrict__ pmax, int O, int Nn) {
    __shared__ float red[4][16][17];
    int b = blockIdx.z, nc = blockIdx.x;
    int lane = threadIdx.x & 63, w = threadIdx.x >> 6;
    int o0 = (blockIdx.y * 4 + w) * 16;
    const u16* wp = wpk + (long)(o0 + (lane & 15)) * C + ((lane >> 4) << 3);
    const u16* ip = in + ((long)b * Nn + nc * 256 + (lane & 15)) * C + ((lane >> 4) << 3);
    long nstride = 16L * C;
    f4 acc[16];
#pragma unroll
    for (int t = 0; t < 16; ++t) acc[t] = (f4)(0.f);
    for (int kk = 0; kk < C; kk += 32) {
        bf8 a = *(const bf8*)(wp + kk);
#pragma unroll
        for (int t = 0; t < 16; ++t) {
            bf8 bb = *(const bf8*)(ip + t * nstride + kk);
            acc[t] = __builtin_amdgcn_mfma_f32_16x16x32_bf16(a, bb, acc[t], 0, 0, 0);
        }
    }
#pragma unroll
    for (int j = 0; j < 4; ++j) {
        int ol = (lane >> 4) * 4 + j;
        int o = o0 + ol;
        float scv = sc ? sc[o] : 1.f;
        float biv = bi ? bi[o] : 0.f;
        float mm = -3.0e38f;
#pragma unroll
        for (int t = 0; t < 16; ++t) {
            float v = acc[t][j] * scv + biv;
            if (do_relu) v = fmaxf(v, 0.f);
            mm = fmaxf(mm, v);
        }
        red[w][ol][lane & 15] = mm;
    }
    __syncthreads();
    if (threadIdx.x < 64) {
        int ww = threadIdx.x >> 4, oo = threadIdx.x & 15;
        float mm = red[ww][oo][0];
#pragma unroll
        for (int i = 1; i < 16; ++i) mm = fmaxf(mm, red[ww][oo][i]);
        int og = (blockIdx.y * 4 + ww) * 16 + oo;
        pmax[((long)nc * 4 + b) * O + og] = mm;
    }
}

// ---------------- bf16-MFMA conv + bn/relu, FULL output [B][O][Nn] ----------------
__global__ __launch_bounds__(256) void k_conv_bf(const u16* __restrict__ in,
                                                 int C,   // packed pitch
                                                 const u16* __restrict__ wpk,
                                                 const float* __restrict__ sc,
                                                 const float* __restrict__ bi, int do_relu,
                                                 float* __restrict__ out, long obs, int Nn) {
    int b = blockIdx.z, nc = blockIdx.x;
    int lane = threadIdx.x & 63, w = threadIdx.x >> 6;
    int o0 = (blockIdx.y * 4 + w) * 16;
    const u16* wp = wpk + (long)(o0 + (lane & 15)) * C + ((lane >> 4) << 3);
    const u16* ip = in + ((long)b * Nn + nc * 256 + (lane & 15)) * C + ((lane >> 4) << 3);
    long nstride = 16L * C;
    f4 acc[16];
#pragma unroll
    for (int t = 0; t < 16; ++t) acc[t] = (f4)(0.f);
    for (int kk = 0; kk < C; kk += 32) {
        bf8 a = *(const bf8*)(wp + kk);
#pragma unroll
        for (int t = 0; t < 16; ++t) {
            bf8 bb = *(const bf8*)(ip + t * nstride + kk);
            acc[t] = __builtin_amdgcn_mfma_f32_16x16x32_bf16(a, bb, acc[t], 0, 0, 0);
        }
    }
#pragma unroll
    for (int j = 0; j < 4; ++j) {
        int o = o0 + (lane >> 4) * 4 + j;
        float scv = sc ? sc[o] : 1.f;
        float biv = bi ? bi[o] : 0.f;
        float* op = out + (long)b * obs + (long)o * Nn + nc * 256 + (lane & 15);
#pragma unroll
        for (int t = 0; t < 16; ++t) {
            float v = acc[t][j] * scv + biv;
            if (do_relu) v = fmaxf(v, 0.f);
            op[t * 16] = v;
        }
    }
}

// ---------------- bf16-MFMA conv, TWO packed inputs + per-(b,o) extra ----------------
__global__ __launch_bounds__(256) void k_conv_bf2(
        const u16* __restrict__ in1, int p1, int C1,
        const u16* __restrict__ in2, int p2, int C2,
        const u16* __restrict__ wpk,
        const float* __restrict__ extra,
        const float* __restrict__ sc, const float* __restrict__ bi, int do_relu,
        float* __restrict__ out, long obs, int O, int Nn) {
    int b = blockIdx.z, nc = blockIdx.x;
    int lane = threadIdx.x & 63, w = threadIdx.x >> 6;
    int o0 = (blockIdx.y * 4 + w) * 16;
    int Ct = C1 + C2;
    const u16* wp = wpk + (long)(o0 + (lane & 15)) * Ct + ((lane >> 4) << 3);
    f4 acc[16];
#pragma unroll
    for (int t = 0; t < 16; ++t) acc[t] = (f4)(0.f);
    {
        const u16* ip1 = in1 + ((long)b * Nn + nc * 256 + (lane & 15)) * p1 + ((lane >> 4) << 3);
        long ns1 = 16L * p1;
        for (int kk = 0; kk < C1; kk += 32) {
            bf8 a = *(const bf8*)(wp + kk);
#pragma unroll
            for (int t = 0; t < 16; ++t) {
                bf8 bb = *(const bf8*)(ip1 + t * ns1 + kk);
                acc[t] = __builtin_amdgcn_mfma_f32_16x16x32_bf16(a, bb, acc[t], 0, 0, 0);
            }
        }
    }
    if (in2) {
        const u16* ip2 = in2 + ((long)b * Nn + nc * 256 + (lane & 15)) * p2 + ((lane >> 4) << 3);
        long ns2 = 16L * p2;
        for (int kk = 0; kk < C2; kk += 32) {
            bf8 a = *(const bf8*)(wp + C1 + kk);
#pragma unroll
            for (int t = 0; t < 16; ++t) {
                bf8 bb = *(const bf8*)(ip2 + t * ns2 + kk);
                acc[t] = __builtin_amdgcn_mfma_f32_16x16x32_bf16(a, bb, acc[t], 0, 0, 0);
            }
        }
    }
#pragma unroll
    for (int j = 0; j < 4; ++j) {
        int o = o0 + (lane >> 4) * 4 + j;
        float e = extra ? extra[(long)b * O + o] : 0.f;
        float scv = sc ? sc[o] : 1.f;
        float biv = bi ? bi[o] : 0.f;
        float* op = out + (long)b * obs + (long)o * Nn + nc * 256 + (lane & 15);
#pragma unroll
        for (int t = 0; t < 16; ++t) {
            float v = (acc[t][j] + e) * scv + biv;
            if (do_relu) v = fmaxf(v, 0.f);
            op[t * 16] = v;
        }
    }
}

// 16-output-tile FMA block (fp32 path)
#define CMAX_FMA16()                                                        \
    {                                                                       \
        const float4* wp4 = reinterpret_cast<const float4*>(Wl + c16);      \
        _Pragma("unroll")                                                   \
        for (int g = 0; g < 4; ++g) {                                       \
            float4 w = wp4[g];                                              \
            acc[4 * g + 0].x = fmaf(w.x, v.x, acc[4 * g + 0].x);            \
            acc[4 * g + 0].y = fmaf(w.x, v.y, acc[4 * g + 0].y);            \
            acc[4 * g + 0].z = fmaf(w.x, v.z, acc[4 * g + 0].z);            \
            acc[4 * g + 0].w = fmaf(w.x, v.w, acc[4 * g + 0].w);            \
            acc[4 * g + 1].x = fmaf(w.y, v.x, acc[4 * g + 1].x);            \
            acc[4 * g + 1].y = fmaf(w.y, v.y, acc[4 * g + 1].y);            \
            acc[4 * g + 1].z = fmaf(w.y, v.z, acc[4 * g + 1].z);            \
            acc[4 * g + 1].w = fmaf(w.y, v.w, acc[4 * g + 1].w);            \
            acc[4 * g + 2].x = fmaf(w.z, v.x, acc[4 * g + 2].x);            \
            acc[4 * g + 2].y = fmaf(w.z, v.y, acc[4 * g + 2].y);            \
            acc[4 * g + 2].z = fmaf(w.z, v.z, acc[4 * g + 2].z);            \
            acc[4 * g + 2].w = fmaf(w.z, v.w, acc[4 * g + 2].w);            \
            acc[4 * g + 3].x = fmaf(w.w, v.x, acc[4 * g + 3].x);            \
            acc[4 * g + 3].y = fmaf(w.w, v.y, acc[4 * g + 3].y);            \
            acc[4 * g + 3].z = fmaf(w.w, v.z, acc[4 * g + 3].z);            \
            acc[4 * g + 3].w = fmaf(w.w, v.w, acc[4 * g + 3].w);            \
        }                                                                   \
    }

// ---------------- fp32 convmax (pool-proj only; rank-sensitive path) ----------------
// NOTE: no min-waves bound (R13: (256,8) forced VGPR 52->32 spill, 5.9x slowdown).
__global__ __launch_bounds__(256) void k_convmax(
        const float* __restrict__ in, int C, long ibs,
        const float* __restrict__ W1, const float* __restrict__ cb1,
        const float* __restrict__ sc1, const float* __restrict__ bi1, int relu1,
        float* __restrict__ pmax1,
        const float* __restrict__ W2, const float* __restrict__ cb2,
        const float* __restrict__ sc2, const float* __restrict__ bi2, int relu2,
        float* __restrict__ pmax2,
        int wpitch, int O, int Nn) {
    extern __shared__ float sm_[];
    float* Wl = sm_;              // [C][16]
    float* red = sm_;             // [16][257] — aliases Wl (disjoint lifetime)
    int b = blockIdx.z;
    int ns = blockIdx.x;
    int oblocks = O >> 4;
    int setid = (int)blockIdx.y / oblocks;
    int og0 = ((int)blockIdx.y - setid * oblocks) * 16;
    const float* W  = setid ? W2 : W1;
    const float* cb = setid ? cb2 : cb1;
    const float* sc = setid ? sc2 : sc1;
    const float* bi = setid ? bi2 : bi1;
    int do_relu     = setid ? relu2 : relu1;
    float* pmax     = setid ? pmax2 : pmax1;
    for (int t = threadIdx.x; t < 16 * C; t += 256) {
        int c = t >> 4, o = t & 15;
        Wl[t] = W[(long)(og0 + o) * wpitch + c];
    }
    __syncthreads();
    int n0 = ns * 1024 + threadIdx.x * 4;
    float4 acc[16];
#pragma unroll
    for (int o = 0; o < 16; ++o) acc[o] = make_float4(0.f, 0.f, 0.f, 0.f);
    const float* p = in + (long)b * ibs + n0;
    float4 v = *reinterpret_cast<const float4*>(p);
    for (int c = 0; c < C - 1; ++c) {
        float4 vn = *reinterpret_cast<const float4*>(p + (long)(c + 1) * Nn);
        int c16 = c * 16;
        CMAX_FMA16();
        v = vn;
    }
    {
        int c16 = (C - 1) * 16;
        CMAX_FMA16();
    }
    float h2[16];
#pragma unroll
    for (int o = 0; o < 16; ++o) {
        float cbv = cb ? cb[og0 + o] : 0.f;
        float scv = sc ? sc[og0 + o] : 1.f;
        float biv = bi ? bi[og0 + o] : 0.f;
        float4 a = acc[o];
        float vx = (a.x + cbv) * scv + biv;
        float vy = (a.y + cbv) * scv + biv;
        float vz = (a.z + cbv) * scv + biv;
        float vw = (a.w + cbv) * scv + biv;
        if (do_relu) {
            vx = fmaxf(vx, 0.f); vy = fmaxf(vy, 0.f);
            vz = fmaxf(vz, 0.f); vw = fmaxf(vw, 0.f);
        }
        h2[o] = fmaxf(fmaxf(vx, vy), fmaxf(vz, vw));
    }
    __syncthreads();
#pragma unroll
    for (int o = 0; o < 16; ++o) red[o * 257 + threadIdx.x] = h2[o];
    __syncthreads();
    for (int ls = 7; ls >= 0; --ls) {
        int s = 1 << ls;
        for (int w = threadIdx.x; w < 16 * s; w += 256) {
            int o = w >> ls, i = w & (s - 1);
            float* r = red + o * 257;
            r[i] = fmaxf(r[i], r[i + s]);
        }
        __syncthreads();
    }
    if (threadIdx.x < 16)
        pmax[((long)ns * 4 + b) * O + og0 + threadIdx.x] = red[threadIdx.x * 257];
}

// finalize: out[b*obs + o] = max over nsplit partials. Dual-set variant.
__global__ __launch_bounds__(256) void k_maxred2(const float* __restrict__ pA, int nsA, int OA,
                                                 float* __restrict__ outA, long obsA,
                                                 const float* __restrict__ pB, int nsB, int OB,
                                                 float* __restrict__ outB, long obsB,
                                                 int blocksA) {
    const float* pm; int ns, O; float* out; long obs; int bid = blockIdx.x;
    if (bid < blocksA) { pm = pA; ns = nsA; O = OA; out = outA; obs = obsA; }
    else { pm = pB; ns = nsB; O = OB; out = outB; obs = obsB; bid -= blocksA; }
    int t = bid * 256 + threadIdx.x;
    if (t >= 4 * O) return;
    int o = t % O, b = t / O;
    float m = -3.0e38f;
    for (int s = 0; s < ns; ++s) m = fmaxf(m, pm[((long)s * 4 + b) * O + o]);
    out[(long)b * obs + o] = m;
}

__global__ __launch_bounds__(256) void k_maxred(const float* __restrict__ pmax, int nsplit,
                                                int O, float* __restrict__ out, long obs) {
    int t = blockIdx.x * 256 + threadIdx.x;
    if (t >= 4 * O) return;
    int o = t % O, b = t / O;
    float m = -3.0e38f;
    for (int s = 0; s < nsplit; ++s) m = fmaxf(m, pmax[((long)s * 4 + b) * O + o]);
    out[(long)b * obs + o] = m;
}

// ---------------- generic fp32 conv(+extra)(+bn)(+relu), up to 2 concat inputs ----------------
#define CONV_FMA8()                                                         \
    {                                                                       \
        const float4* wp4 = reinterpret_cast<const float4*>(Wl + c8);       \
        _Pragma("unroll")                                                   \
        for (int g = 0; g < 2; ++g) {                                       \
            float4 w = wp4[g];                                              \
            acc[4 * g + 0].x = fmaf(w.x, v.x, acc[4 * g + 0].x);            \
            acc[4 * g + 0].y = fmaf(w.x, v.y, acc[4 * g + 0].y);            \
            acc[4 * g + 0].z = fmaf(w.x, v.z, acc[4 * g + 0].z);            \
            acc[4 * g + 0].w = fmaf(w.x, v.w, acc[4 * g + 0].w);            \
            acc[4 * g + 1].x = fmaf(w.y, v.x, acc[4 * g + 1].x);            \
            acc[4 * g + 1].y = fmaf(w.y, v.y, acc[4 * g + 1].y);            \
            acc[4 * g + 1].z = fmaf(w.y, v.z, acc[4 * g + 1].z);            \
            acc[4 * g + 1].w = fmaf(w.y, v.w, acc[4 * g + 1].w);            \
            acc[4 * g + 2].x = fmaf(w.z, v.x, acc[4 * g + 2].x);            \
            acc[4 * g + 2].y = fmaf(w.z, v.y, acc[4 * g + 2].y);            \
            acc[4 * g + 2].z = fmaf(w.z, v.z, acc[4 * g + 2].z);            \
            acc[4 * g + 2].w = fmaf(w.z, v.w, acc[4 * g + 2].w);            \
            acc[4 * g + 3].x = fmaf(w.w, v.x, acc[4 * g + 3].x);            \
            acc[4 * g + 3].y = fmaf(w.w, v.y, acc[4 * g + 3].y);            \
            acc[4 * g + 3].z = fmaf(w.w, v.z, acc[4 * g + 3].z);            \
            acc[4 * g + 3].w = fmaf(w.w, v.w, acc[4 * g + 3].w);            \
        }                                                                   \
    }

__global__ __launch_bounds__(256) void k_conv(const float* __restrict__ in1, int C1, long ibs1,
                                              const float* __restrict__ in2, int C2, long ibs2,
                                              const float* __restrict__ W, int wpitch,
                                              const float* __restrict__ extra,
                                              const float* __restrict__ sc,
                                              const float* __restrict__ bi, int do_relu,
                                              float* __restrict__ out, long obs, int O, int Nn) {
    __shared__ float Wl[384 * 8];
    int b = blockIdx.z;
    int og0 = blockIdx.y * 8;
    int on = O - og0; if (on > 8) on = 8;
    int Ct = C1 + C2;
    for (int t = threadIdx.x; t < Ct * 8; t += 256) {
        int c = t >> 3, o = t & 7;
        Wl[t] = (o < on) ? W[(long)(og0 + o) * wpitch + c] : 0.f;
    }
    __syncthreads();
    int n0 = blockIdx.x * 1024 + threadIdx.x * 4;
    float4 acc[8];
#pragma unroll
    for (int o = 0; o < 8; ++o) acc[o] = make_float4(0.f, 0.f, 0.f, 0.f);
    const float* p1 = in1 + (long)b * ibs1 + n0;
    {
        float4 v = *reinterpret_cast<const float4*>(p1);
        for (int c = 0; c < C1 - 1; ++c) {
            float4 vn = *reinterpret_cast<const float4*>(p1 + (long)(c + 1) * Nn);
            int c8 = c * 8;
            CONV_FMA8();
            v = vn;
        }
        int c8 = (C1 - 1) * 8;
        CONV_FMA8();
    }
    if (in2) {
        const float* p2 = in2 + (long)b * ibs2 + n0;
        float4 v = *reinterpret_cast<const float4*>(p2);
        for (int c = 0; c < C2 - 1; ++c) {
            float4 vn = *reinterpret_cast<const float4*>(p2 + (long)(c + 1) * Nn);
            int c8 = (C1 + c) * 8;
            CONV_FMA8();
            v = vn;
        }
        int c8 = (Ct - 1) * 8;
        CONV_FMA8();
    }
#pragma unroll
    for (int o = 0; o < 8; ++o) {
        if (o < on) {
            float e = extra ? extra[(long)b * O + og0 + o] : 0.f;
            float s = sc ? sc[og0 + o] : 1.f;
            float bv = bi ? bi[og0 + o] : 0.f;
            float4 a = acc[o];
            a.x = (a.x + e) * s + bv;
            a.y = (a.y + e) * s + bv;
            a.z = (a.z + e) * s + bv;
            a.w = (a.w + e) * s + bv;
            if (do_relu) {
                a.x = fmaxf(a.x, 0.f); a.y = fmaxf(a.y, 0.f);
                a.z = fmaxf(a.z, 0.f); a.w = fmaxf(a.w, 0.f);
            }
            *reinterpret_cast<float4*>(out + (long)b * obs + (long)(og0 + o) * Nn + n0) = a;
        }
    }
}

// ---------------- scores: one n per thread, all 8 e; grid (32,1,4)=128 blocks ----------------
__global__ __launch_bounds__(256) void k_scores(const float* __restrict__ feat,
                                                const float* __restrict__ maxp,
                                                float* __restrict__ scores) {
    __shared__ float vl[1024];
    int b = blockIdx.z;
    for (int t = threadIdx.x; t < 1024; t += 256) vl[t] = maxp[b * 1024 + t];
    __syncthreads();
    int n = blockIdx.x * 256 + threadIdx.x;
    float acc[8];
#pragma unroll
    for (int e = 0; e < 8; ++e) acc[e] = 0.f;
    const float* p = feat + (long)b * 128 * NPTS + n;
    float v = p[0];
    for (int c = 0; c < 127; ++c) {
        float vn = p[(long)(c + 1) * NPTS];
#pragma unroll
        for (int e = 0; e < 8; ++e) acc[e] = fmaf(vl[c * 8 + e], v, acc[e]);
        v = vn;
    }
#pragma unroll
    for (int e = 0; e < 8; ++e) acc[e] = fmaf(vl[127 * 8 + e], v, acc[e]);
#pragma unroll
    for (int e = 0; e < 8; ++e)
        scores[((long)b * 8 + e) * NPTS + n] = 1.f / (1.f + expf(-acc[e]));
}

// ---------------- hierarchical exact sorted top-256 per (b,e) ----------------
__global__ __launch_bounds__(256) void k_sorta(const float* __restrict__ scores,
                                               unsigned int* __restrict__ kout,
                                               unsigned short* __restrict__ iout) {
    __shared__ unsigned int kv[1024];
    __shared__ unsigned short ki[1024];
    int ch = blockIdx.x & 7;
    const float* sp = scores + (long)(blockIdx.x >> 3) * NPTS + ch * 1024;
    for (int t = threadIdx.x; t < 1024; t += 256) {
        kv[t] = __float_as_uint(sp[t]) ^ 0xFFFFFFFFu;
        ki[t] = (unsigned short)(ch * 1024 + t);
    }
    __syncthreads();
    for (int k = 2; k <= 1024; k <<= 1) {
        for (int j = k >> 1; j > 0; j >>= 1) {
            for (int t = threadIdx.x; t < 1024; t += 256) {
                int ixj = t ^ j;
                if (ixj > t) {
                    unsigned int va = kv[t], vb = kv[ixj];
                    unsigned short ia = ki[t], ib = ki[ixj];
                    bool up = ((t & k) == 0);
                    bool gt = (va > vb) || (va == vb && ia > ib);
                    if (gt == up) { kv[t] = vb; kv[ixj] = va; ki[t] = ib; ki[ixj] = ia; }
                }
            }
            __syncthreads();
        }
    }
    if (threadIdx.x < 256) {
        kout[blockIdx.x * 256 + threadIdx.x] = kv[threadIdx.x];
        iout[blockIdx.x * 256 + threadIdx.x] = ki[threadIdx.x];
    }
}

__global__ __launch_bounds__(512) void k_sortb(const unsigned int* __restrict__ kin,
                                               const unsigned short* __restrict__ iin,
                                               float* __restrict__ topv,
                                               int* __restrict__ topi) {
    __shared__ unsigned int kv[2048];
    __shared__ unsigned short ki[2048];
    int be = blockIdx.x, b = be >> 3, e = be & 7;
    for (int t = threadIdx.x; t < 2048; t += 512) {
        kv[t] = kin[be * 2048 + t];
        ki[t] = iin[be * 2048 + t];
    }
    __syncthreads();
    for (int k = 2; k <= 2048; k <<= 1) {
        for (int j = k >> 1; j > 0; j >>= 1) {
            for (int t = threadIdx.x; t < 2048; t += 512) {
                int ixj = t ^ j;
                if (ixj > t) {
                    unsigned int va = kv[t], vb = kv[ixj];
                    unsigned short ia = ki[t], ib = ki[ixj];
                    bool up = ((t & k) == 0);
                    bool gt = (va > vb) || (va == vb && ia > ib);
                    if (gt == up) { kv[t] = vb; kv[ixj] = va; ki[t] = ib; ki[ixj] = ia; }
                }
            }
            __syncthreads();
        }
    }
    for (int r = threadIdx.x; r < 256; r += 512) {
        int j = r * 8 + e;  // torch-order reshape: values[b, r*8+e] = v[b,e,r]
        topv[b * 2048 + j] = __uint_as_float(kv[r] ^ 0xFFFFFFFFu);
        topi[b * 2048 + j] = (int)ki[r];
    }
}

// ---------------- merged gather: nf1 (blocks 0..4095) + poolgather (4096..4127) ----------------
__global__ __launch_bounds__(256) void k_gather(const float* __restrict__ feat,
                                                const float* __restrict__ xyz,
                                                const float* __restrict__ topv,
                                                const int* __restrict__ topi,
                                                float* __restrict__ h,
                                                float* __restrict__ node_ws,
                                                float* __restrict__ out_node,
                                                float* __restrict__ out_nstat) {
    int bid = blockIdx.x;
    if (bid < 4096) {
        int t = bid * 256 + threadIdx.x;
        int j = t & 2047, c = (t >> 11) & 127, b = t >> 18;
        int i = topi[b * 2048 + j];
        float v = topv[b * 2048 + j];
        h[((long)b * 256 + c) * MNODE + j] = feat[((long)b * 128 + c) * NPTS + i] * v;
    } else {
        int t = (bid - 4096) * 256 + threadIdx.x;  // 0..8191
        int j = t & 2047, b = t >> 11;
        int i = topi[b * 2048 + j];
        float v = topv[b * 2048 + j];
#pragma unroll
        for (int k = 0; k < 3; ++k) {
            float sx = xyz[((long)b * 3 + k) * NPTS + i];
            float nd = sx * v;
            out_nstat[((long)b * 3 + k) * MNODE + j] = sx;
            out_node[((long)b * 3 + k) * MNODE + j] = nd;
            node_ws[((long)b * 3 + k) * MNODE + j] = nd;
        }
    }
}

// ---------------- knn20 (block-per-node): exact stable top-20 ----------------
__device__ __forceinline__ unsigned int fsortbits(float f) {
    unsigned int u = __float_as_uint(f);
    return u ^ ((unsigned int)((int)u >> 31) | 0x80000000u);
}

__global__ __launch_bounds__(256) void k_knn20(const float* __restrict__ xyz,
                                               const float* __restrict__ node,
                                               int* __restrict__ k20) {
    __shared__ unsigned int s1[256];
    __shared__ int s2[256];
    __shared__ int lcnt;
    int m = blockIdx.x & 2047, b = blockIdx.x >> 11;
    int t = threadIdx.x;
    float nx = node[((long)b * 3 + 0) * MNODE + m];
    float ny = node[((long)b * 3 + 1) * MNODE + m];
    float nz = node[((long)b * 3 + 2) * MNODE + m];
    float sm = nx * nx + ny * ny + nz * nz;
    const float* xb = xyz + (long)b * 3 * NPTS;
    unsigned int kmin = 0xFFFFFFFFu;
    for (int i = 0; i < 32; ++i) {
        int n = i * 256 + t;
        float px = xb[n], py = xb[NPTS + n], pz = xb[2 * NPTS + n];
        float d = (px * px + py * py + pz * pz) + sm - 2.f * (px * nx + py * ny + pz * nz);
        unsigned int key = fsortbits(d);
        kmin = key < kmin ? key : kmin;
    }
    s1[t] = kmin;
    if (t == 0) lcnt = 0;
    __syncthreads();
    for (int k = 2; k <= 256; k <<= 1) {
        for (int j = k >> 1; j > 0; j >>= 1) {
            int ixj = t ^ j;
            if (ixj > t) {
                unsigned int va = s1[t], vb = s1[ixj];
                bool up = ((t & k) == 0);
                if ((va > vb) == up) { s1[t] = vb; s1[ixj] = va; }
            }
            __syncthreads();
        }
    }
    unsigned int keyT = s1[19];
    __syncthreads();
    for (int i = 0; i < 32; ++i) {
        int n = i * 256 + t;
        float px = xb[n], py = xb[NPTS + n], pz = xb[2 * NPTS + n];
        float d = (px * px + py * py + pz * pz) + sm - 2.f * (px * nx + py * ny + pz * nz);
        unsigned int key = fsortbits(d);
        if (key <= keyT) {
            int p = atomicAdd(&lcnt, 1);
            if (p < 128) { s1[p] = key; s2[p] = n; }
        }
    }
    __syncthreads();
    int cnt = lcnt;
    if (cnt <= 128) {
        if (t >= cnt && t < 128) { s1[t] = 0xFFFFFFFFu; s2[t] = 0x7FFFFFFF; }
        __syncthreads();
        for (int k = 2; k <= 128; k <<= 1) {
            for (int j = k >> 1; j > 0; j >>= 1) {
                if (t < 128) {
                    int ixj = t ^ j;
                    if (ixj > t) {
                        unsigned int va = s1[t], vb = s1[ixj];
                        int ia = s2[t], ib = s2[ixj];
                        bool up = ((t & k) == 0);
                        bool gt = (va > vb) || (va == vb && ia > ib);
                        if (gt == up) { s1[t] = vb; s1[ixj] = va; s2[t] = ib; s2[ixj] = ia; }
                    }
                }
                __syncthreads();
            }
        }
        if (t < 20) k20[((long)b * 2048 + m) * 20 + t] = s2[t];
    } else {
        unsigned int lastk = 0u; int lasti = -1;
        for (int r = 0; r < 20; ++r) {
            unsigned int bk = 0xFFFFFFFFu; int bi = 0x7FFFFFFF;
            for (int i = 0; i < 32; ++i) {
                int n = i * 256 + t;
                float px = xb[n], py = xb[NPTS + n], pz = xb[2 * NPTS + n];
                float d = (px * px + py * py + pz * pz) + sm - 2.f * (px * nx + py * ny + pz * nz);
                unsigned int key = fsortbits(d);
                bool gtlast = (key > lastk) || (key == lastk && n > lasti);
                bool ltbest = (key < bk) || (key == bk && n < bi);
                if (gtlast && ltbest) { bk = key; bi = n; }
            }
            s1[t] = bk; s2[t] = bi;
            __syncthreads();
            for (int s = 128; s > 0; s >>= 1) {
                if (t < s) {
                    unsigned int vo = s1[t + s]; int io = s2[t + s];
                    unsigned int vm = s1[t]; int im = s2[t];
                    if (vo < vm || (vo == vm && io < im)) { s1[t] = vo; s2[t] = io; }
                }
                __syncthreads();
            }
            if (t == 0) k20[((long)b * 2048 + m) * 20 + r] = s2[0];
            lastk = s1[0]; lasti = s2[0];
            __syncthreads();
        }
    }
}

// ---------------- aggregate: h ch128-255 = max over 20 gathered feats ----------------
__global__ __launch_bounds__(256) void k_agg(const float* __restrict__ feat,
                                             const int* __restrict__ k20,
                                             float* __restrict__ h) {
    int t = blockIdx.x * 256 + threadIdx.x;
    int m = t & 2047, c = (t >> 11) & 127, b = t >> 18;
    const int* ip = k20 + ((long)b * 2048 + m) * 20;
    const float* fb = feat + ((long)b * 128 + c) * NPTS;
    float mx = -3.0e38f;
#pragma unroll
    for (int q = 0; q < 20; ++q) mx = fmaxf(mx, fb[ip[q] & 8191]);
    h[((long)b * 256 + 128 + c) * MNODE + m] = mx;
}

// ---------------- gemv: block per output o, all 4 batches; coalesced row read ----------------
__global__ __launch_bounds__(256) void k_gemv(const float* __restrict__ in, int C,
                                              const float* __restrict__ W, int wpitch,
                                              const float* __restrict__ lb,
                                              const float* __restrict__ sc,
                                              const float* __restrict__ bi, int do_relu,
                                              float* __restrict__ out, int O) {
    __shared__ float red[256];
    int o = blockIdx.x;
    int t = threadIdx.x;
    const float* wp = W + (long)o * wpitch;
    float a0 = 0.f, a1 = 0.f, a2 = 0.f, a3 = 0.f;
    for (int c = t * 4; c < C; c += 1024) {
        float4 w = *reinterpret_cast<const float4*>(wp + c);
        float4 v0 = *reinterpret_cast<const float4*>(in + 0L * C + c);
        float4 v1 = *reinterpret_cast<const float4*>(in + 1L * C + c);
        float4 v2 = *reinterpret_cast<const float4*>(in + 2L * C + c);
        float4 v3 = *reinterpret_cast<const float4*>(in + 3L * C + c);
        a0 += w.x * v0.x + w.y * v0.y + w.z * v0.z + w.w * v0.w;
        a1 += w.x * v1.x + w.y * v1.y + w.z * v1.z + w.w * v1.w;
        a2 += w.x * v2.x + w.y * v2.y + w.z * v2.z + w.w * v2.w;
        a3 += w.x * v3.x + w.y * v3.y + w.z * v3.z + w.w * v3.w;
    }
    float lbv = lb ? lb[o] : 0.f;
    float scv = sc ? sc[o] : 1.f;
    float biv = bi ? bi[o] : 0.f;
#pragma unroll
    for (int b = 0; b < 4; ++b) {
        float a = (b == 0) ? a0 : (b == 1) ? a1 : (b == 2) ? a2 : a3;
        __syncthreads();
        red[t] = a;
        __syncthreads();
        for (int s2 = 128; s2 > 0; s2 >>= 1) {
            if (t < s2) red[t] += red[t + s2];
            __syncthreads();
        }
        if (t == 0) {
            float r = (red[0] + lbv) * scv + biv;
            if (do_relu) r = fmaxf(r, 0.f);
            out[(long)b * O + o] = r;
        }
    }
}

// ---------------- unpool knn3 ----------------
__global__ __launch_bounds__(256) void k_knn3(const float* __restrict__ xyz,
                                              const float* __restrict__ node,
                                              int* __restrict__ k3i, float* __restrict__ k3w) {
    __shared__ float sx[2048], sy[2048], sz[2048], sn[2048];
    __shared__ float md[256][3];
    __shared__ int   mi[256][3];
    int b = blockIdx.x >> 8;
    int pbase = (blockIdx.x & 255) * 32;
    int t = threadIdx.x;
    const float* nb = node + (long)b * 3 * MNODE;
    for (int j = t; j < 2048; j += 256) {
        float qx = nb[j], qy = nb[MNODE + j], qz = nb[2 * MNODE + j];
        sx[j] = qx; sy[j] = qy; sz[j] = qz;
        sn[j] = qx * qx + qy * qy + qz * qz;
    }
    __syncthreads();
    int i = t & 31, q = t >> 5;
    int n = pbase + i;
    float px = xyz[((long)b * 3 + 0) * NPTS + n];
    float py = xyz[((long)b * 3 + 1) * NPTS + n];
    float pz = xyz[((long)b * 3 + 2) * NPTS + n];
    float sp = px * px + py * py + pz * pz;
    float d0 = 3.0e38f, d1 = 3.0e38f, d2 = 3.0e38f;
    int i0 = 0, i1 = 0, i2 = 0;
    int m0 = q * 256;
#pragma unroll 4
    for (int k = 0; k < 256; ++k) {
        int m = m0 + k;
        float d = (sp + sn[m]) - 2.f * (px * sx[m] + py * sy[m] + pz * sz[m]);
        if (d < d2) {
            d2 = d; i2 = m;
            if (d2 < d1) { float td = d1; d1 = d2; d2 = td; int ti = i1; i1 = i2; i2 = ti; }
            if (d1 < d0) { float td = d0; d0 = d1; d1 = td; int ti = i0; i0 = i1; i1 = ti; }
        }
    }
    md[t][0] = d0; md[t][1] = d1; md[t][2] = d2;
    mi[t][0] = i0; mi[t][1] = i1; mi[t][2] = i2;
    __syncthreads();
    if (t < 32) {
        int p0 = 0, p1 = 0, p2 = 0, p3 = 0, p4 = 0, p5 = 0, p6 = 0, p7 = 0;
        float rd[3]; int ri[3];
#pragma unroll
        for (int r = 0; r < 3; ++r) {
            float bestd = 3.0e38f; int besti = 0x7FFFFFFF; int bestq = -1;
#define KNN3_HEAD(QQ, PV)                                                              \
            {                                                                          \
                float dd = md[(QQ) * 32 + t][PV]; int ii = mi[(QQ) * 32 + t][PV];      \
                if (dd < bestd || (dd == bestd && ii < besti)) {                       \
                    bestd = dd; besti = ii; bestq = (QQ);                              \
                }                                                                      \
            }
            KNN3_HEAD(0, p0) KNN3_HEAD(1, p1) KNN3_HEAD(2, p2) KNN3_HEAD(3, p3)
            KNN3_HEAD(4, p4) KNN3_HEAD(5, p5) KNN3_HEAD(6, p6) KNN3_HEAD(7, p7)
#undef KNN3_HEAD
            rd[r] = bestd; ri[r] = besti;
            p0 += (bestq == 0); p1 += (bestq == 1); p2 += (bestq == 2); p3 += (bestq == 3);
            p4 += (bestq == 4); p5 += (bestq == 5); p6 += (bestq == 6); p7 += (bestq == 7);
        }
        float mxd = fmaxf(rd[0], fmaxf(rd[1], rd[2]));
        float e0 = expf(rd[0] - mxd), e1 = expf(rd[1] - mxd), e2 = expf(rd[2] - mxd);
        float inv = 1.f / (e0 + e1 + e2);
        long base = ((long)b * NPTS + pbase + t) * 3;
        k3i[base] = ri[0]; k3i[base + 1] = ri[1]; k3i[base + 2] = ri[2];
        k3w[base] = e0 * inv; k3w[base + 1] = e1 * inv; k3w[base + 2] = e2 * inv;
    }
}

__global__ __launch_bounds__(256) void k_unpool(const float* __restrict__ s7,
                                                const int* __restrict__ k3i,
                                                const float* __restrict__ k3w,
                                                float* __restrict__ sup) {
    int t = blockIdx.x * 256 + threadIdx.x;
    int n = t & 8191, c = (t >> 13) & 127, b = t >> 20;
    long base = ((long)b * NPTS + n) * 3;
    const float* spp = s7 + ((long)b * 128 + c) * MNODE;
    float a = k3w[base] * spp[k3i[base]] + k3w[base + 1] * spp[k3i[base + 1]] +
              k3w[base + 2] * spp[k3i[base + 2]];
    sup[((long)b * 128 + c) * NPTS + n] = a;
}

extern "C" void kernel_launch(void* const* d_in, const int* in_sizes, int n_in,
                              void* d_out, int out_size, void* d_ws, size_t ws_size,
                              hipStream_t stream) {
    const float* x     = (const float*)d_in[0];
    const float* c1w   = (const float*)d_in[1];
    const float* c2w   = (const float*)d_in[2];
    const float* c2mw  = (const float*)d_in[3];
    const float* c3w   = (const float*)d_in[4];
    const float* c4w   = (const float*)d_in[5];
    const float* c5w   = (const float*)d_in[6];
    const float* c6w   = (const float*)d_in[7];
    const float* c7w   = (const float*)d_in[8];
    const float* c8w   = (const float*)d_in[9];
    const float* c9w   = (const float*)d_in[10];
    const float* c10w  = (const float*)d_in[11];
    const float* bn1s  = (const float*)d_in[12]; const float* bn1b  = (const float*)d_in[13];
    const float* bn2s  = (const float*)d_in[14]; const float* bn2b  = (const float*)d_in[15];
    const float* bn2ms = (const float*)d_in[16]; const float* bn2mb = (const float*)d_in[17];
    const float* bn3s  = (const float*)d_in[18]; const float* bn3b  = (const float*)d_in[19];
    const float* bn4s  = (const float*)d_in[20]; const float* bn4b  = (const float*)d_in[21];
    const float* bn5s  = (const float*)d_in[22]; const float* bn5b  = (const float*)d_in[23];
    const float* bn6cs = (const float*)d_in[24]; const float* bn6cb = (const float*)d_in[25];
    const float* bn7cs = (const float*)d_in[26]; const float* bn7cb = (const float*)d_in[27];
    const float* bn8s  = (const float*)d_in[28]; const float* bn8b  = (const float*)d_in[29];
    const float* bn9s  = (const float*)d_in[30]; const float* bn9b  = (const float*)d_in[31];
    const float* bn6hs = (const float*)d_in[32]; const float* bn6hb = (const float*)d_in[33];
    const float* bn7hs = (const float*)d_in[34]; const float* bn7hb = (const float*)d_in[35];
    const float* poolw = (const float*)d_in[36]; const float* poolb = (const float*)d_in[37];
    const float* l1w   = (const float*)d_in[38];
    const float* l2w   = (const float*)d_in[39]; const float* l2b   = (const float*)d_in[40];
    const float* l3w   = (const float*)d_in[41]; const float* l3b   = (const float*)d_in[42];

    float* ws   = (float*)d_ws;
    float* xt1  = ws + WS_XT1;
    float* x34  = ws + WS_A;
    float* s8   = ws + WS_A;                 // LATE alias: x34 dead after conv7
    float* scor = ws + WS_B;
    float* hbuf = ws + WS_C;
    float* s6   = ws + WS_C;
    float* s7   = ws + WS_C + 1048576L;
    float* sup  = ws + WS_D;
    float* s9   = ws + WS_D;                 // LATE alias: sup dead after sp8 pack
    float* topv = ws + WS_TOPV;
    int*   topi = (int*)(ws + WS_TOPI);
    float* node = ws + WS_NODE;
    float* maxp = ws + WS_MAXP;
    float* vec  = ws + WS_VEC;
    float* c1b  = ws + WS_C1;
    float* c2b_ = ws + WS_C2;
    float* b6   = ws + WS_B6;
    int*   k20  = (int*)(ws + WS_K20);
    float* pmax1 = ws + WS_K20;              // 32*4*1024 = 131072 floats
    float* pmax2 = ws + WS_K20 + 131072;     // + 32768 -> total 163840 = k20 size
    int*   k3i  = (int*)(ws + WS_K3I);
    float* k3w  = ws + WS_K3W;
    unsigned int*   sskeys = (unsigned int*)(ws + WS_A);
    unsigned short* ssidx  = (unsigned short*)(ws + WS_A + 65536);
    // bf16 staging (lifetime-aliased; weight packs hoisted to stream head):
    u16* xtb   = (u16*)(ws + WS_C);                 // [4][8192][128] (before hbuf)
    u16* c2mwb = (u16*)(ws + WS_D);                 // [0..65536) fl; hb overwrites after conv2m
    u16* x34b  = (u16*)(ws + WS_B);                 // [0..2097152) fl (after scores)
    u16* c5wb  = (u16*)(ws + WS_B + 2097152);       // [2097152..2359296) fl
    u16* hb    = (u16*)(ws + WS_D);                 // [0..1048576) fl (after conv2m)
    u16* x3p   = (u16*)(ws + WS_D + 1048576);       // [1048576..2097152) fl
    u16* c3wb  = (u16*)(ws + WS_D + 2097152);       // [..2129920) fl
    u16* c4wb  = (u16*)(ws + WS_D + 2129920);       // [..2162688) fl
    u16* c6wb  = (u16*)(ws + WS_D + 2162688);       // [..2179072) fl — survives hb/x3p/s6p
    u16* c7wb  = (u16*)(ws + WS_D + 2179072);       // [..2203648) fl
    u16* s6p   = (u16*)(ws + WS_D);                 // [0..524288) fl (conv7 in1; hb dead)
    u16* sp8   = (u16*)(ws + WS_B);                 // [0..3145728) fl (late)
    u16* cc8wb = (u16*)(ws + WS_B + 3145728);       // [..3158016) fl
    u16* cc9wb = (u16*)(ws + WS_B + 3158016);       // [..3170304) fl (de-aliased from cc8wb)
    u16* sp9   = (u16*)(ws + WS_B);                 // reuse after conv8

    float* out       = (float*)d_out;
    float* out_cls   = out;
    float* out_seg   = out + 60;
    float* out_node  = out + 60 + 65536;
    float* out_nstat = out_node + 24576;

    // ALL weight packs in one upfront launch (depend only on inputs)
    k_packall<<<dim3(3584), dim3(256), 0, stream>>>(c2mw, c3w, c4w, c5w, c6w, c7w, c8w, c9w,
                                                    c2mwb, c3wb, c4wb, c5wb, c6wb, c7wb,
                                                    cc8wb, cc9wb);
    // x1 -> xt1_ ch0-63; x2 via fp32 k_conv (feeds rank-sensitive pool/scores: stays fp32)
    k_conv1<<<dim3(8192), dim3(256), 0, stream>>>(x, c1w, bn1s, bn1b, xt1);
    k_conv<<<dim3(8, 8, 4), dim3(256), 0, stream>>>(xt1, 64, 128L * NPTS, nullptr, 0, 0,
                                                    c2w, 64, nullptr, bn2s, bn2b, 1,
                                                    xt1 + 64L * NPTS, 128L * NPTS, 64, NPTS);
    // conv2m via bf16-MFMA
    k_packT2<<<dim3(256, 4, 4), dim3(256), 0, stream>>>(xt1, 128L * NPTS, 128, NPTS, xtb, 128, 0);
    k_cvmx_bf<<<dim3(32, 16, 4), dim3(256), 0, stream>>>(xtb, c2mwb, 128,
                                                         bn2ms, bn2mb, 1, pmax1, 1024, NPTS);
    // pool-proj stays fp32 (top-k rank-sensitive)
    k_convmax<<<dim3(8, 64, 4), dim3(256), 16 * 257 * 4, stream>>>(
        xt1, 128, 128L * NPTS,
        poolw, poolb, nullptr, nullptr, 0, pmax2,
        nullptr, nullptr, nullptr, nullptr, 0, nullptr,
        128, 1024, NPTS);
    k_maxred2<<<dim3(32), dim3(256), 0, stream>>>(pmax1, 32, 1024, vec, 2048,
                                                  pmax2, 8, 1024, maxp, 1024, 16);
    // scores
    k_scores<<<dim3(32, 1, 4), dim3(256), 0, stream>>>(xt1, maxp, scor);
    // exact top-256 per (b,e)
    k_sorta<<<dim3(256), dim3(256), 0, stream>>>(scor, sskeys, ssidx);
    k_sortb<<<dim3(32), dim3(512), 0, stream>>>(sskeys, ssidx, topv, topi);
    // merged nf1 + poolgather
    k_gather<<<dim3(4128), dim3(256), 0, stream>>>(xt1, x, topv, topi, hbuf,
                                                   node, out_node, out_nstat);
    // aggregate
    k_knn20<<<dim3(8192), dim3(256), 0, stream>>>(x, node, k20);
    k_agg<<<dim3(4096), dim3(256), 0, stream>>>(xt1, k20, hbuf);
    // conv3 via bf16-MFMA
    k_packT2<<<dim3(64, 8, 4), dim3(256), 0, stream>>>(hbuf, 256L * MNODE, 256, MNODE, hb, 256, 0);
    k_conv_bf<<<dim3(8, 4, 4), dim3(256), 0, stream>>>(hb, 256, c3wb, bn3s, bn3b, 1,
                                                       x34, 512L * MNODE, MNODE);
    // conv4 via bf16-MFMA
    k_packT2<<<dim3(64, 8, 4), dim3(256), 0, stream>>>(x34, 512L * MNODE, 256, MNODE, x3p, 256, 0);
    k_conv_bf<<<dim3(8, 4, 4), dim3(256), 0, stream>>>(x3p, 256, c4wb, bn4s, bn4b, 1,
                                                       x34 + 256L * MNODE, 512L * MNODE, MNODE);
    // conv5 via bf16-MFMA (x34b reused by conv6/conv7)
    k_packT2<<<dim3(64, 16, 4), dim3(256), 0, stream>>>(x34, 512L * MNODE, 512, MNODE, x34b, 512, 0);
    k_cvmx_bf<<<dim3(8, 16, 4), dim3(256), 0, stream>>>(x34b, c5wb, 512,
                                                        bn5s, bn5b, 1, pmax1, 1024, MNODE);
    k_maxred<<<dim3(16), dim3(256), 0, stream>>>(pmax1, 8, 1024, vec + 1024, 2048);
    // classification head
    k_gemv<<<dim3(512), dim3(256), 0, stream>>>(vec, 2048, l1w, 2048, nullptr, bn6hs, bn6hb, 1, c1b, 512);
    k_gemv<<<dim3(256), dim3(256), 0, stream>>>(c1b, 512, l2w, 512, l2b, bn7hs, bn7hb, 1, c2b_, 256);
    k_gemv<<<dim3(15), dim3(256), 0, stream>>>(c2b_, 256, l3w, 256, l3b, nullptr, nullptr, 0, out_cls, 15);
    // conv6 via bf16-MFMA: x4 = x34b cols 256-511 (ptr offset); vrep term = b6 as 'extra'
    k_gemv<<<dim3(128), dim3(256), 0, stream>>>(vec, 2048, c6w, 2304, nullptr, nullptr, nullptr, 0, b6, 128);
    k_conv_bf2<<<dim3(8, 2, 4), dim3(256), 0, stream>>>(x34b + 256, 512, 256,
                                                        nullptr, 0, 0, c6wb, b6,
                                                        bn6cs, bn6cb, 1,
                                                        s6, 128L * MNODE, 128, MNODE);
    // conv7 via bf16-MFMA: in1 = packed s6, in2 = x34b cols 0-255 (x3)
    k_packT2<<<dim3(64, 4, 4), dim3(256), 0, stream>>>(s6, 128L * MNODE, 128, MNODE, s6p, 128, 0);
    k_conv_bf2<<<dim3(8, 2, 4), dim3(256), 0, stream>>>(s6p, 128, 128,
                                                        x34b, 512, 256, c7wb, nullptr,
                                                        bn7cs, bn7cb, 1,
                                                        s7, 128L * MNODE, 128, MNODE);
    // unpool
    k_knn3<<<dim3(1024), dim3(256), 0, stream>>>(x, node, k3i, k3w);
    k_unpool<<<dim3(16384), dim3(256), 0, stream>>>(s7, k3i, k3w, sup);
    // conv8 via bf16-MFMA: dual-source pack (sup + xt1 ch64-127) in ONE launch
    k_packT2d<<<dim3(256, 6, 4), dim3(256), 0, stream>>>(sup, 128L * NPTS, 128,
                                                         xt1 + 64L * NPTS, 128L * NPTS, 64,
                                                         NPTS, sp8, 192);
    k_conv_bf<<<dim3(32, 2, 4), dim3(256), 0, stream>>>(sp8, 192, cc8wb, bn8s, bn8b, 1,
                                                        s8, 128L * NPTS, NPTS);
    // conv9 via bf16-MFMA: dual-source pack (s8 + xt1 ch0-63) in ONE launch
    k_packT2d<<<dim3(256, 6, 4), dim3(256), 0, stream>>>(s8, 128L * NPTS, 128,
                                                         xt1, 128L * NPTS, 64,
                                                         NPTS, sp9, 192);
    k_conv_bf<<<dim3(32, 2, 4), dim3(256), 0, stream>>>(sp9, 192, cc9wb, bn9s, bn9b, 1,
                                                        s9, 128L * NPTS, NPTS);
    // conv10 (fp32, tiny)
    k_conv<<<dim3(8, 1, 4), dim3(256), 0, stream>>>(s9, 128, 128L * NPTS, nullptr, 0, 0,
                                                    c10w, 128, nullptr, nullptr, nullptr, 0,
                                                    out_seg, 2L * NPTS, 2, NPTS);
    (void)in_sizes; (void)n_in; (void)out_size; (void)ws_size;
}